// Round 2
// baseline (3505.999 us; speedup 1.0000x reference)
//
#include <hip/hip_runtime.h>
#include <math.h>

#define TOK 4096      // B*L
#define DMODEL 512
#define LSEQ 1024
#define BATCH 4
#define NLAYER 2
#define NEXP 8
#define TOPK 4
#define HDIM 2048
#define NBLK 136      // max 128-row blocks across all experts (sum counts = 16384)
#define ROWCAP 17408  // padded compact-row capacity

// Set to 0 to fall back to legacy (non-partitionable) threefry counter scheme.
#define THREEFRY_PARTITIONABLE 1

// ---------------------------------------------------------------- reductions
__device__ __forceinline__ float waveAllSum(float v) {
#pragma unroll
  for (int off = 1; off < 64; off <<= 1) v += __shfl_xor(v, off, 64);
  return v;
}
__device__ __forceinline__ float waveAllMax(float v) {
#pragma unroll
  for (int off = 1; off < 64; off <<= 1) v = fmaxf(v, __shfl_xor(v, off, 64));
  return v;
}

// ---------------------------------------------------------------- threefry
__device__ __forceinline__ unsigned rotl32(unsigned x, int r) {
  return (x << r) | (x >> (32 - r));
}
__device__ __forceinline__ void tf2x32(unsigned k0, unsigned k1,
                                       unsigned& x0, unsigned& x1) {
  const unsigned ks0 = k0, ks1 = k1, ks2 = k0 ^ k1 ^ 0x1BD11BDAu;
  x0 += ks0; x1 += ks1;
#define TF_R4(a, b, c, d)                                   \
  x0 += x1; x1 = rotl32(x1, a); x1 ^= x0;                   \
  x0 += x1; x1 = rotl32(x1, b); x1 ^= x0;                   \
  x0 += x1; x1 = rotl32(x1, c); x1 ^= x0;                   \
  x0 += x1; x1 = rotl32(x1, d); x1 ^= x0;
  TF_R4(13, 15, 26, 6)  x0 += ks1; x1 += ks2 + 1u;
  TF_R4(17, 29, 16, 24) x0 += ks2; x1 += ks0 + 2u;
  TF_R4(13, 15, 26, 6)  x0 += ks0; x1 += ks1 + 3u;
  TF_R4(17, 29, 16, 24) x0 += ks1; x1 += ks2 + 4u;
  TF_R4(13, 15, 26, 6)  x0 += ks2; x1 += ks0 + 5u;
#undef TF_R4
}

// XLA f32 ErfInv (Giles polynomial), with unfused mul/add to match XLA.
__device__ __forceinline__ float xla_erfinv(float u) {
  float w = -log1pf(-__fmul_rn(u, u));
  float p;
  if (w < 5.0f) {
    w = __fadd_rn(w, -2.5f);
    p = 2.81022636e-08f;
    p = __fadd_rn(3.43273939e-07f, __fmul_rn(p, w));
    p = __fadd_rn(-3.5233877e-06f, __fmul_rn(p, w));
    p = __fadd_rn(-4.39150654e-06f, __fmul_rn(p, w));
    p = __fadd_rn(0.00021858087f, __fmul_rn(p, w));
    p = __fadd_rn(-0.00125372503f, __fmul_rn(p, w));
    p = __fadd_rn(-0.00417768164f, __fmul_rn(p, w));
    p = __fadd_rn(0.246640727f, __fmul_rn(p, w));
    p = __fadd_rn(1.50140941f, __fmul_rn(p, w));
  } else {
    w = __fadd_rn(sqrtf(w), -3.0f);
    p = -0.000200214257f;
    p = __fadd_rn(0.000100950558f, __fmul_rn(p, w));
    p = __fadd_rn(0.00134934322f, __fmul_rn(p, w));
    p = __fadd_rn(-0.00367342844f, __fmul_rn(p, w));
    p = __fadd_rn(0.00573950773f, __fmul_rn(p, w));
    p = __fadd_rn(-0.0076224613f, __fmul_rn(p, w));
    p = __fadd_rn(0.00943887047f, __fmul_rn(p, w));
    p = __fadd_rn(1.00167406f, __fmul_rn(p, w));
    p = __fadd_rn(2.83297682f, __fmul_rn(p, w));
  }
  return __fmul_rn(p, u);
}

__device__ __forceinline__ float bits_to_normal(unsigned bits) {
  const unsigned fb = (bits >> 9) | 0x3f800000u;
  const float u01 = __fadd_rn(__uint_as_float(fb), -1.0f);
  const float lo = -0.99999994f;  // nextafter(-1,0) in f32
  float u = __fadd_rn(__fmul_rn(u01, 2.0f), lo);
  u = fmaxf(u, lo);
  return __fmul_rn(1.41421356237309515f, xla_erfinv(u));
}

// eps = jax.random.normal(fold_in(key(42), layer), (B,L,E)) element i (row-major)
__device__ __forceinline__ float eps_normal(unsigned i, unsigned layer) {
  unsigned f0 = 0u, f1 = layer;   // fold_in: cipher((0,42), (0,layer))
  tf2x32(0u, 42u, f0, f1);
#if THREEFRY_PARTITIONABLE
  unsigned x0 = 0u, x1 = i;  // 64-bit iota split (hi, lo)
  tf2x32(f0, f1, x0, x1);
  return bits_to_normal(x0 ^ x1);
#else
  const unsigned HALF = (TOK * NEXP) / 2;  // 16384
  unsigned x0, x1; bool hi;
  if (i < HALF) { x0 = i; x1 = i + HALF; hi = false; }
  else          { x0 = i - HALF; x1 = i; hi = true; }
  tf2x32(f0, f1, x0, x1);
  return bits_to_normal(hi ? x1 : x0);
#endif
}

// ---------------------------------------------------------------- GEMM core
// 128x128 tile, BK=8, 256 thr, 8x8 acc/thread.
// Thread columns: {tx*4..+3} and {64+tx*4..+3}  (2-way LDS aliasing = free;
// the old tx*8 mapping was a 4-way bank conflict, 1.58x on that read).
template <bool TRANSB, bool RELU, bool GATED, bool ACCUM>
__global__ __launch_bounds__(256) void gemm_f32(
    const float* __restrict__ Ag, const float* __restrict__ Bg,
    const float* __restrict__ bias, const float* __restrict__ gate,
    float* __restrict__ Cg, int M, int N, int K, float alpha,
    long long sA, long long sB, long long sC) {
  __shared__ float As[8][132];
  __shared__ float Bs[8][132];
  const float* A = Ag + (long long)blockIdx.z * sA;
  const float* B = Bg + (long long)blockIdx.z * sB;
  float* C = Cg + (long long)blockIdx.z * sC;
  const int m0 = blockIdx.y * 128, n0 = blockIdx.x * 128;
  const int t = threadIdx.x;
  const int tx = t & 15, ty = t >> 4;
  const int ar = t >> 1, ac = (t & 1) * 4;   // A (and B^T) tile coords
  const int br = t >> 5, bc = (t & 31) * 4;  // B (NN) tile coords

  float acc[8][8];
#pragma unroll
  for (int i = 0; i < 8; ++i)
#pragma unroll
    for (int j = 0; j < 8; ++j) acc[i][j] = 0.f;

  for (int k0 = 0; k0 < K; k0 += 8) {
    const float4 av = *(const float4*)(A + (long long)(m0 + ar) * K + (k0 + ac));
    float4 bv;
    if (TRANSB) bv = *(const float4*)(B + (long long)(n0 + ar) * K + (k0 + ac));
    else        bv = *(const float4*)(B + (long long)(k0 + br) * N + (n0 + bc));
    As[ac + 0][ar] = av.x; As[ac + 1][ar] = av.y;
    As[ac + 2][ar] = av.z; As[ac + 3][ar] = av.w;
    if (TRANSB) {
      Bs[ac + 0][ar] = bv.x; Bs[ac + 1][ar] = bv.y;
      Bs[ac + 2][ar] = bv.z; Bs[ac + 3][ar] = bv.w;
    } else {
      *(float4*)&Bs[br][bc] = bv;
    }
    __syncthreads();
#pragma unroll
    for (int kk = 0; kk < 8; ++kk) {
      float a0[8], b0[8];
      *(float4*)&a0[0] = *(const float4*)&As[kk][ty * 8];
      *(float4*)&a0[4] = *(const float4*)&As[kk][ty * 8 + 4];
      *(float4*)&b0[0] = *(const float4*)&Bs[kk][tx * 4];
      *(float4*)&b0[4] = *(const float4*)&Bs[kk][64 + tx * 4];
#pragma unroll
      for (int i = 0; i < 8; ++i)
#pragma unroll
        for (int j = 0; j < 8; ++j) acc[i][j] = fmaf(a0[i], b0[j], acc[i][j]);
    }
    __syncthreads();
  }

#pragma unroll
  for (int i = 0; i < 8; ++i) {
    const int m = m0 + ty * 8 + i;
    float gv = 1.f;
    if (GATED) gv = gate[(long long)m * NEXP];
#pragma unroll
    for (int h = 0; h < 2; ++h) {
      const int n = n0 + h * 64 + tx * 4;
      const long long idx = (long long)m * N + n;
      float4 cv;
      float* cp = (float*)&cv;
#pragma unroll
      for (int jj = 0; jj < 4; ++jj) {
        float c = acc[i][h * 4 + jj] * alpha;
        if (bias) c += bias[n + jj];
        if (RELU) c = fmaxf(c, 0.f);
        if (GATED) c *= gv;
        cp[jj] = c;
      }
      if (ACCUM) {
        const float4 old = *(const float4*)(C + idx);
        cv.x += old.x; cv.y += old.y; cv.z += old.z; cv.w += old.w;
      }
      *(float4*)(C + idx) = cv;
    }
  }
}

// ------------------------------------------------- fused Q/K/V projection
// grid.x: 12 = 3 matrices x 4 n-blocks; grid.y: TOK/128
__global__ __launch_bounds__(256) void gemm_qkv(
    const float* __restrict__ X,
    const float* __restrict__ wqp, const float* __restrict__ wkp,
    const float* __restrict__ wvp,
    const float* __restrict__ bqp, const float* __restrict__ bkp,
    const float* __restrict__ bvp,
    float* __restrict__ qo, float* __restrict__ ko, float* __restrict__ vo) {
  __shared__ float As[8][132];
  __shared__ float Bs[8][132];
  const int mat = blockIdx.x >> 2;
  const float* B = (mat == 0) ? wqp : (mat == 1) ? wkp : wvp;
  const float* bias = (mat == 0) ? bqp : (mat == 1) ? bkp : bvp;
  float* C = (mat == 0) ? qo : (mat == 1) ? ko : vo;
  const int m0 = blockIdx.y * 128, n0 = (blockIdx.x & 3) * 128;
  const int t = threadIdx.x;
  const int tx = t & 15, ty = t >> 4;
  const int ar = t >> 1, ac = (t & 1) * 4;
  const int br = t >> 5, bc = (t & 31) * 4;

  float acc[8][8];
#pragma unroll
  for (int i = 0; i < 8; ++i)
#pragma unroll
    for (int j = 0; j < 8; ++j) acc[i][j] = 0.f;

  for (int k0 = 0; k0 < DMODEL; k0 += 8) {
    const float4 av = *(const float4*)(X + (long long)(m0 + ar) * DMODEL + (k0 + ac));
    const float4 bv = *(const float4*)(B + (long long)(k0 + br) * DMODEL + (n0 + bc));
    As[ac + 0][ar] = av.x; As[ac + 1][ar] = av.y;
    As[ac + 2][ar] = av.z; As[ac + 3][ar] = av.w;
    *(float4*)&Bs[br][bc] = bv;
    __syncthreads();
#pragma unroll
    for (int kk = 0; kk < 8; ++kk) {
      float a0[8], b0[8];
      *(float4*)&a0[0] = *(const float4*)&As[kk][ty * 8];
      *(float4*)&a0[4] = *(const float4*)&As[kk][ty * 8 + 4];
      *(float4*)&b0[0] = *(const float4*)&Bs[kk][tx * 4];
      *(float4*)&b0[4] = *(const float4*)&Bs[kk][64 + tx * 4];
#pragma unroll
      for (int i = 0; i < 8; ++i)
#pragma unroll
        for (int j = 0; j < 8; ++j) acc[i][j] = fmaf(a0[i], b0[j], acc[i][j]);
    }
    __syncthreads();
  }
#pragma unroll
  for (int i = 0; i < 8; ++i) {
    const int m = m0 + ty * 8 + i;
#pragma unroll
    for (int h = 0; h < 2; ++h) {
      const int n = n0 + h * 64 + tx * 4;
      float4 cv;
      float* cp = (float*)&cv;
#pragma unroll
      for (int jj = 0; jj < 4; ++jj) cp[jj] = acc[i][h * 4 + jj] + bias[n + jj];
      *(float4*)(C + (long long)m * DMODEL + n) = cv;
    }
  }
}

// ------------------------------------------------- grouped expert GEMM 1
// H[row] = relu(X[list[row]] @ W1[e] + b1[e]) over compact rows
__global__ __launch_bounds__(256) void gemm_moe1(
    const float* __restrict__ X, const float* __restrict__ W1l,
    const float* __restrict__ b1l, const int* __restrict__ list,
    const int* __restrict__ blockExp, const int* __restrict__ blockBase,
    const int* __restrict__ blockValid, float* __restrict__ H) {
  const int by = blockIdx.y;
  const int e = blockExp[by];
  if (e < 0) return;
  const int row0 = blockBase[by], valid = blockValid[by];
  const float* B = W1l + (long long)e * DMODEL * HDIM;
  const float* bias = b1l + e * HDIM;
  __shared__ float As[8][132];
  __shared__ float Bs[8][132];
  const int n0 = blockIdx.x * 128;
  const int t = threadIdx.x;
  const int tx = t & 15, ty = t >> 4;
  const int ar = t >> 1, ac = (t & 1) * 4;
  const int br = t >> 5, bc = (t & 31) * 4;
  const int atok = list[row0 + ((ar < valid) ? ar : 0)];
  const float* Arow = X + (long long)atok * DMODEL;

  float acc[8][8];
#pragma unroll
  for (int i = 0; i < 8; ++i)
#pragma unroll
    for (int j = 0; j < 8; ++j) acc[i][j] = 0.f;

  for (int k0 = 0; k0 < DMODEL; k0 += 8) {
    const float4 av = *(const float4*)(Arow + k0 + ac);
    const float4 bv = *(const float4*)(B + (long long)(k0 + br) * HDIM + (n0 + bc));
    As[ac + 0][ar] = av.x; As[ac + 1][ar] = av.y;
    As[ac + 2][ar] = av.z; As[ac + 3][ar] = av.w;
    *(float4*)&Bs[br][bc] = bv;
    __syncthreads();
#pragma unroll
    for (int kk = 0; kk < 8; ++kk) {
      float a0[8], b0[8];
      *(float4*)&a0[0] = *(const float4*)&As[kk][ty * 8];
      *(float4*)&a0[4] = *(const float4*)&As[kk][ty * 8 + 4];
      *(float4*)&b0[0] = *(const float4*)&Bs[kk][tx * 4];
      *(float4*)&b0[4] = *(const float4*)&Bs[kk][64 + tx * 4];
#pragma unroll
      for (int i = 0; i < 8; ++i)
#pragma unroll
        for (int j = 0; j < 8; ++j) acc[i][j] = fmaf(a0[i], b0[j], acc[i][j]);
    }
    __syncthreads();
  }
#pragma unroll
  for (int i = 0; i < 8; ++i) {
    const int m = ty * 8 + i;
    if (m >= valid) continue;
#pragma unroll
    for (int h = 0; h < 2; ++h) {
      const int n = n0 + h * 64 + tx * 4;
      float4 cv;
      float* cp = (float*)&cv;
#pragma unroll
      for (int jj = 0; jj < 4; ++jj)
        cp[jj] = fmaxf(acc[i][h * 4 + jj] + bias[n + jj], 0.f);
      *(float4*)(H + (long long)(row0 + m) * HDIM + n) = cv;
    }
  }
}

// ------------------------------------------------- grouped expert GEMM 2
// moe[list[row]] += (H[row] @ W2[e] + b2[e]) * gate[list[row], e]
__global__ __launch_bounds__(256) void gemm_moe2(
    const float* __restrict__ H, const float* __restrict__ W2l,
    const float* __restrict__ b2l, const int* __restrict__ list,
    const int* __restrict__ blockExp, const int* __restrict__ blockBase,
    const int* __restrict__ blockValid, const float* __restrict__ gate,
    float* __restrict__ moe) {
  const int by = blockIdx.y;
  const int e = blockExp[by];
  if (e < 0) return;
  const int row0 = blockBase[by], valid = blockValid[by];
  const float* B = W2l + (long long)e * HDIM * DMODEL;
  const float* bias = b2l + e * DMODEL;
  __shared__ float As[8][132];
  __shared__ float Bs[8][132];
  const int n0 = blockIdx.x * 128;
  const int t = threadIdx.x;
  const int tx = t & 15, ty = t >> 4;
  const int ar = t >> 1, ac = (t & 1) * 4;
  const int br = t >> 5, bc = (t & 31) * 4;

  float acc[8][8];
#pragma unroll
  for (int i = 0; i < 8; ++i)
#pragma unroll
    for (int j = 0; j < 8; ++j) acc[i][j] = 0.f;

  for (int k0 = 0; k0 < HDIM; k0 += 8) {
    const float4 av = *(const float4*)(H + (long long)(row0 + ar) * HDIM + (k0 + ac));
    const float4 bv = *(const float4*)(B + (long long)(k0 + br) * DMODEL + (n0 + bc));
    As[ac + 0][ar] = av.x; As[ac + 1][ar] = av.y;
    As[ac + 2][ar] = av.z; As[ac + 3][ar] = av.w;
    *(float4*)&Bs[br][bc] = bv;
    __syncthreads();
#pragma unroll
    for (int kk = 0; kk < 8; ++kk) {
      float a0[8], b0[8];
      *(float4*)&a0[0] = *(const float4*)&As[kk][ty * 8];
      *(float4*)&a0[4] = *(const float4*)&As[kk][ty * 8 + 4];
      *(float4*)&b0[0] = *(const float4*)&Bs[kk][tx * 4];
      *(float4*)&b0[4] = *(const float4*)&Bs[kk][64 + tx * 4];
#pragma unroll
      for (int i = 0; i < 8; ++i)
#pragma unroll
        for (int j = 0; j < 8; ++j) acc[i][j] = fmaf(a0[i], b0[j], acc[i][j]);
    }
    __syncthreads();
  }
#pragma unroll
  for (int i = 0; i < 8; ++i) {
    const int m = ty * 8 + i;
    if (m >= valid) continue;
    const int tok = list[row0 + m];
    const float gv = gate[(long long)tok * NEXP + e];
    float* orow = moe + (long long)tok * DMODEL;
#pragma unroll
    for (int h = 0; h < 2; ++h) {
      const int n = n0 + h * 64 + tx * 4;
#pragma unroll
      for (int jj = 0; jj < 4; ++jj)
        atomicAdd(orow + n + jj, (acc[i][h * 4 + jj] + bias[n + jj]) * gv);
    }
  }
}

// ---------------------------------------------------------------- RoPE
__global__ __launch_bounds__(256) void rope_rot(
    float* __restrict__ q, float* __restrict__ k,
    const float* __restrict__ nc, const float* __restrict__ wr) {
  const int tok = blockIdx.x, j = threadIdx.x;  // j < 256
  const float c0 = nc[tok * 2 + 0], c1 = nc[tok * 2 + 1];
  const float f = c0 * wr[j] + c1 * wr[256 + j];
  const float cf = cosf(f), sf = sinf(f);
  float2* q2 = (float2*)(q + (long long)tok * DMODEL);
  float2* k2 = (float2*)(k + (long long)tok * DMODEL);
  const float2 qq = q2[j];
  const float2 kk = k2[j];
  q2[j] = make_float2(qq.x * cf - qq.y * sf, qq.x * sf + qq.y * cf);
  k2[j] = make_float2(kk.x * cf - kk.y * sf, kk.x * sf + kk.y * cf);
}

// ---------------------------------------------------------------- softmax
__global__ __launch_bounds__(256) void attn_softmax(
    float* __restrict__ S, const unsigned char* __restrict__ pad) {
  const int q = blockIdx.x & (LSEQ - 1);
  const int b = blockIdx.x >> 10;
  float* row = S + (long long)blockIdx.x * LSEQ;
  const int t = threadIdx.x;
  const float4 v = ((const float4*)row)[t];
  float vals[4] = {v.x, v.y, v.z, v.w};
  const int k0 = t * 4;
#pragma unroll
  for (int j = 0; j < 4; ++j) {
    const int k = k0 + j;
    if (k > q || pad[b * LSEQ + k]) vals[j] = -INFINITY;
  }
  __shared__ float red[4];
  const int wid = t >> 6, lane = t & 63;
  float m = waveAllMax(fmaxf(fmaxf(vals[0], vals[1]), fmaxf(vals[2], vals[3])));
  if (lane == 0) red[wid] = m;
  __syncthreads();
  m = fmaxf(fmaxf(red[0], red[1]), fmaxf(red[2], red[3]));
  const float e0 = expf(vals[0] - m), e1 = expf(vals[1] - m);
  const float e2 = expf(vals[2] - m), e3 = expf(vals[3] - m);
  const float ps = waveAllSum(e0 + e1 + e2 + e3);
  __syncthreads();
  if (lane == 0) red[wid] = ps;
  __syncthreads();
  const float tot = red[0] + red[1] + red[2] + red[3];
  float4 o;
  o.x = e0 / tot; o.y = e1 / tot; o.z = e2 / tot; o.w = e3 / tot;
  ((float4*)row)[t] = o;
}

// ---------------------------------------------------------------- add + LN
__global__ __launch_bounds__(128) void ln_add(
    const float* __restrict__ Aa, const float* __restrict__ Bb,
    const float* __restrict__ gg, const float* __restrict__ bb,
    float* __restrict__ out) {
  const int row = blockIdx.x, t = threadIdx.x;
  const float4 va = ((const float4*)(Aa + (long long)row * DMODEL))[t];
  const float4 vb = ((const float4*)(Bb + (long long)row * DMODEL))[t];
  const float x0 = va.x + vb.x, x1 = va.y + vb.y;
  const float x2 = va.z + vb.z, x3 = va.w + vb.w;
  __shared__ float r1[2], r2[2];
  const int wid = t >> 6, lane = t & 63;
  const float s = waveAllSum(x0 + x1 + x2 + x3);
  if (lane == 0) r1[wid] = s;
  __syncthreads();
  const float mean = (r1[0] + r1[1]) * (1.0f / DMODEL);
  const float d0 = x0 - mean, d1 = x1 - mean, d2 = x2 - mean, d3 = x3 - mean;
  const float vs = waveAllSum(d0 * d0 + d1 * d1 + d2 * d2 + d3 * d3);
  if (lane == 0) r2[wid] = vs;
  __syncthreads();
  const float var = (r2[0] + r2[1]) * (1.0f / DMODEL);
  const float rs = rsqrtf(var + 1e-5f);
  const float4 g4 = ((const float4*)gg)[t];
  const float4 b4 = ((const float4*)bb)[t];
  float4 o;
  o.x = d0 * rs * g4.x + b4.x;
  o.y = d1 * rs * g4.y + b4.y;
  o.z = d2 * rs * g4.z + b4.z;
  o.w = d3 * rs * g4.w + b4.w;
  ((float4*)(out + (long long)row * DMODEL))[t] = o;
}

// ------------------------------------------------- router + noise + topk + gate
__global__ __launch_bounds__(64) void router_topk(
    const float* __restrict__ x, const float* __restrict__ rtw,
    const float* __restrict__ rtb, const float* __restrict__ nzw,
    const float* __restrict__ nzb, float* __restrict__ gate,
    int* __restrict__ counts, unsigned char* __restrict__ selmask, int layer) {
  __shared__ float xs[DMODEL];
  __shared__ float red[16];
  __shared__ float noisy[8];
  const int tok = blockIdx.x, t = threadIdx.x;
  const float4* x4 = (const float4*)(x + (long long)tok * DMODEL);
  ((float4*)xs)[t] = x4[t];
  ((float4*)xs)[64 + t] = x4[64 + t];
  __syncthreads();
  const int o = t >> 2, p = t & 3, e = o & 7;
  const float* W = (o < 8) ? rtw : nzw;
  float s = 0.f;
  const int d0 = p * 128;
  for (int d = 0; d < 128; ++d) s = fmaf(xs[d0 + d], W[(d0 + d) * NEXP + e], s);
  s += __shfl_xor(s, 1, 64);
  s += __shfl_xor(s, 2, 64);
  if (p == 0) red[o] = s;
  __syncthreads();
  if (t < 8) {
    const float logit = red[t] + rtb[t];
    const float nl = red[8 + t] + nzb[t];
    const float eps = eps_normal((unsigned)(tok * NEXP + t), (unsigned)layer);
    const float sp = fmaxf(nl, 0.f) + log1pf(expf(-fabsf(nl)));  // logaddexp(x,0)
    noisy[t] = logit + eps * sp;
  }
  __syncthreads();
  if (t == 0) {
    float v[8]; bool sel[8];
#pragma unroll
    for (int i = 0; i < 8; ++i) { v[i] = noisy[i]; sel[i] = false; }
    for (int r = 0; r < TOPK; ++r) {  // strict '>' => lowest index wins ties
      int bi = 0; float best = -INFINITY;
      for (int i = 0; i < 8; ++i)
        if (!sel[i] && v[i] > best) { best = v[i]; bi = i; }
      sel[bi] = true;
    }
    float m = -INFINITY;
    for (int i = 0; i < 8; ++i) if (sel[i]) m = fmaxf(m, v[i]);
    float ex[8]; float den = 0.f;
    unsigned char mbits = 0;
    for (int i = 0; i < 8; ++i) {
      ex[i] = sel[i] ? expf(v[i] - m) : 0.f;
      den += ex[i];
      if (sel[i]) { mbits |= (unsigned char)(1u << i); atomicAdd(&counts[i], 1); }
    }
    for (int i = 0; i < 8; ++i) gate[tok * NEXP + i] = ex[i] / den;
    selmask[tok] = mbits;
  }
}

// ------------------------------------------------- dispatch plan/build/zero
__global__ void moe_plan(const int* __restrict__ counts, int* __restrict__ start,
                         int* __restrict__ blockExp, int* __restrict__ blockBase,
                         int* __restrict__ blockValid) {
  if (threadIdx.x != 0) return;
  int s = 0, by = 0;
  for (int e = 0; e < NEXP; ++e) {
    start[e] = s;
    const int c = counts[e];
    const int nb = (c + 127) >> 7;
    for (int b = 0; b < nb; ++b) {
      blockExp[by] = e;
      blockBase[by] = s + b * 128;
      blockValid[by] = min(128, c - b * 128);
      ++by;
    }
    s += nb * 128;
  }
  for (; by < NBLK; ++by) blockExp[by] = -1;
}

__global__ __launch_bounds__(256) void moe_build(
    const unsigned char* __restrict__ selmask, const int* __restrict__ start,
    int* __restrict__ cursor, int* __restrict__ list) {
  const int tok = blockIdx.x * 256 + threadIdx.x;
  if (tok >= TOK) return;
  unsigned m = selmask[tok];
  while (m) {
    const int e = __ffs(m) - 1;
    m &= m - 1;
    const int slot = atomicAdd(&cursor[e], 1);
    list[start[e] + slot] = tok;
  }
}

__global__ __launch_bounds__(256) void zero_f32(float* __restrict__ p, int n4) {
  const int i = blockIdx.x * 256 + threadIdx.x;
  if (i < n4) ((float4*)p)[i] = make_float4(0.f, 0.f, 0.f, 0.f);
}
__global__ void zero_i32(int* __restrict__ p, int n) {
  const int i = threadIdx.x;
  if (i < n) p[i] = 0;
}

// ---------------------------------------------------------------- launch
extern "C" void kernel_launch(void* const* d_in, const int* in_sizes, int n_in,
                              void* d_out, int out_size, void* d_ws,
                              size_t ws_size, hipStream_t stream) {
  const float* x_in = (const float*)d_in[0];
  const float* nc = (const float*)d_in[1];
  const unsigned char* pad = (const unsigned char*)d_in[3];
  const float* wq = (const float*)d_in[4];
  const float* bq = (const float*)d_in[5];
  const float* wk = (const float*)d_in[6];
  const float* bk = (const float*)d_in[7];
  const float* wv = (const float*)d_in[8];
  const float* bv = (const float*)d_in[9];
  const float* wr = (const float*)d_in[10];
  const float* ln1g = (const float*)d_in[11];
  const float* ln1b = (const float*)d_in[12];
  const float* rtw = (const float*)d_in[13];
  const float* rtb = (const float*)d_in[14];
  const float* nzw = (const float*)d_in[15];
  const float* nzb = (const float*)d_in[16];
  const float* ew1 = (const float*)d_in[17];
  const float* eb1 = (const float*)d_in[18];
  const float* ew2 = (const float*)d_in[19];
  const float* eb2 = (const float*)d_in[20];
  const float* ln2g = (const float*)d_in[21];
  const float* ln2b = (const float*)d_in[22];

  float* ws = (float*)d_ws;
  const long long SZ = (long long)TOK * DMODEL;  // 2M floats
  float* qb = ws;
  float* kb = ws + SZ;
  float* vb2 = ws + 2 * SZ;
  float* xcur = ws + 3 * SZ;
  float* moe = ws + 4 * SZ;
  float* gate = ws + 5 * SZ;          // 32768 floats
  float* scores = gate + 32768;       // 4M floats (16 MB)
  int* meta = (int*)(scores + 4194304);
  // meta layout (ints): counts[8] cursor[8] start[8] blockExp[136]
  //                     blockBase[136] blockValid[136] list[17408] selmask(4096B)
  int* counts = meta;
  int* cursor = meta + 8;
  int* startE = meta + 16;
  int* blockExp = meta + 24;
  int* blockBase = meta + 160;
  int* blockValid = meta + 296;
  int* list = meta + 432;
  unsigned char* selmask = (unsigned char*)(meta + 17840);
  float* hidden = (float*)(meta + 19456);  // ROWCAP x HDIM

  const long long sparse_floats =
      5 * SZ + 32768 + 4194304 + 19456 + (long long)ROWCAP * HDIM;
  const bool use_sparse = (ws_size >= (size_t)(sparse_floats * 4));
  // dense fallback: "big" (scores OR dense hidden) right after gate
  float* big = gate + 65536;

  const float iscale = 1.0f / sqrtf((float)DMODEL);
  const dim3 blk(256);

  for (int l = 0; l < NLAYER; ++l) {
    const float* xl = (l == 0) ? x_in : xcur;
    const long long wOff = (long long)l * DMODEL * DMODEL;
    float* sc = use_sparse ? scores : big;

    gemm_qkv<<<dim3(12, TOK / 128), blk, 0, stream>>>(
        xl, wq + wOff, wk + wOff, wv + wOff, bq + l * DMODEL, bk + l * DMODEL,
        bv + l * DMODEL, qb, kb, vb2);

    rope_rot<<<TOK, 256, 0, stream>>>(qb, kb, nc, wr + (long long)l * DMODEL);

    gemm_f32<true, false, false, false><<<dim3(8, 8, BATCH), blk, 0, stream>>>(
        qb, kb, nullptr, nullptr, sc, LSEQ, LSEQ, DMODEL, iscale,
        (long long)LSEQ * DMODEL, (long long)LSEQ * DMODEL, (long long)LSEQ * LSEQ);

    attn_softmax<<<BATCH * LSEQ, 256, 0, stream>>>(sc, pad);

    gemm_f32<false, false, false, false><<<dim3(4, 8, BATCH), blk, 0, stream>>>(
        sc, vb2, nullptr, nullptr, qb, LSEQ, DMODEL, LSEQ, 1.f,
        (long long)LSEQ * LSEQ, (long long)LSEQ * DMODEL, (long long)LSEQ * DMODEL);

    ln_add<<<TOK, 128, 0, stream>>>(xl, qb, ln1g + l * DMODEL, ln1b + l * DMODEL, xcur);

    zero_i32<<<1, 64, 0, stream>>>(counts, 16);  // counts + cursor
    router_topk<<<TOK, 64, 0, stream>>>(xcur, rtw + l * DMODEL * NEXP,
                                        rtb + l * NEXP, nzw + l * DMODEL * NEXP,
                                        nzb + l * NEXP, gate, counts, selmask, l);

    if (use_sparse) {
      moe_plan<<<1, 64, 0, stream>>>(counts, startE, blockExp, blockBase, blockValid);
      moe_build<<<TOK / 256, 256, 0, stream>>>(selmask, startE, cursor, list);
      zero_f32<<<(int)(SZ / 4 / 256), 256, 0, stream>>>(moe, (int)(SZ / 4));

      gemm_moe1<<<dim3(HDIM / 128, NBLK), blk, 0, stream>>>(
          xcur, ew1 + (long long)l * NEXP * DMODEL * HDIM,
          eb1 + (long long)l * NEXP * HDIM, list, blockExp, blockBase,
          blockValid, hidden);

      gemm_moe2<<<dim3(DMODEL / 128, NBLK), blk, 0, stream>>>(
          hidden, ew2 + (long long)l * NEXP * HDIM * DMODEL,
          eb2 + (long long)l * NEXP * DMODEL, list, blockExp, blockBase,
          blockValid, gate, moe);
    } else {
      for (int e = 0; e < NEXP; ++e) {
        const long long we = (long long)(l * NEXP + e);
        gemm_f32<false, true, false, false><<<dim3(HDIM / 128, TOK / 128), blk, 0, stream>>>(
            xcur, ew1 + we * DMODEL * HDIM, eb1 + we * HDIM, nullptr, big,
            TOK, HDIM, DMODEL, 1.f, 0, 0, 0);
        if (e == 0)
          gemm_f32<false, false, true, false><<<dim3(DMODEL / 128, TOK / 128), blk, 0, stream>>>(
              big, ew2 + we * (long long)HDIM * DMODEL, eb2 + we * DMODEL,
              gate + e, moe, TOK, DMODEL, HDIM, 1.f, 0, 0, 0);
        else
          gemm_f32<false, false, true, true><<<dim3(DMODEL / 128, TOK / 128), blk, 0, stream>>>(
              big, ew2 + we * (long long)HDIM * DMODEL, eb2 + we * DMODEL,
              gate + e, moe, TOK, DMODEL, HDIM, 1.f, 0, 0, 0);
      }
    }

    float* outp = (l == NLAYER - 1) ? (float*)d_out : xcur;
    ln_add<<<TOK, 128, 0, stream>>>(xcur, moe, ln2g + l * DMODEL, ln2b + l * DMODEL, outp);
  }
}

// Round 6
// 2486.926 us; speedup vs baseline: 1.4098x; 1.4098x over previous
//
#include <hip/hip_runtime.h>
#include <math.h>

#define TOK 4096      // B*L
#define DMODEL 512
#define LSEQ 1024
#define BATCH 4
#define NLAYER 2
#define NEXP 8
#define TOPK 4
#define HDIM 2048
#define NBLK 136      // max 128-row blocks across all experts (sum counts = 16384)
#define CHBLK 68      // blocks per chunk (2 chunks)

typedef unsigned short u16;
typedef __attribute__((ext_vector_type(8))) short bf16x8;
typedef __attribute__((ext_vector_type(4))) float f32x4;

// ---------------------------------------------------------------- bf16 split
__device__ __forceinline__ u16 f2bf(float x) {
  const unsigned u = __float_as_uint(x);
  return (u16)((u + 0x7FFFu + ((u >> 16) & 1u)) >> 16);
}
__device__ __forceinline__ float bf2f(u16 h) {
  return __uint_as_float(((unsigned)h) << 16);
}

// ---------------------------------------------------------------- reductions
__device__ __forceinline__ float waveAllSum(float v) {
#pragma unroll
  for (int off = 1; off < 64; off <<= 1) v += __shfl_xor(v, off, 64);
  return v;
}
__device__ __forceinline__ float waveAllMax(float v) {
#pragma unroll
  for (int off = 1; off < 64; off <<= 1) v = fmaxf(v, __shfl_xor(v, off, 64));
  return v;
}

// ---------------------------------------------------------------- threefry
__device__ __forceinline__ unsigned rotl32(unsigned x, int r) {
  return (x << r) | (x >> (32 - r));
}
__device__ __forceinline__ void tf2x32(unsigned k0, unsigned k1,
                                       unsigned& x0, unsigned& x1) {
  const unsigned ks0 = k0, ks1 = k1, ks2 = k0 ^ k1 ^ 0x1BD11BDAu;
  x0 += ks0; x1 += ks1;
#define TF_R4(a, b, c, d)                                   \
  x0 += x1; x1 = rotl32(x1, a); x1 ^= x0;                   \
  x0 += x1; x1 = rotl32(x1, b); x1 ^= x0;                   \
  x0 += x1; x1 = rotl32(x1, c); x1 ^= x0;                   \
  x0 += x1; x1 = rotl32(x1, d); x1 ^= x0;
  TF_R4(13, 15, 26, 6)  x0 += ks1; x1 += ks2 + 1u;
  TF_R4(17, 29, 16, 24) x0 += ks2; x1 += ks0 + 2u;
  TF_R4(13, 15, 26, 6)  x0 += ks0; x1 += ks1 + 3u;
  TF_R4(17, 29, 16, 24) x0 += ks1; x1 += ks2 + 4u;
  TF_R4(13, 15, 26, 6)  x0 += ks2; x1 += ks0 + 5u;
#undef TF_R4
}

__device__ __forceinline__ float xla_erfinv(float u) {
  float w = -log1pf(-__fmul_rn(u, u));
  float p;
  if (w < 5.0f) {
    w = __fadd_rn(w, -2.5f);
    p = 2.81022636e-08f;
    p = __fadd_rn(3.43273939e-07f, __fmul_rn(p, w));
    p = __fadd_rn(-3.5233877e-06f, __fmul_rn(p, w));
    p = __fadd_rn(-4.39150654e-06f, __fmul_rn(p, w));
    p = __fadd_rn(0.00021858087f, __fmul_rn(p, w));
    p = __fadd_rn(-0.00125372503f, __fmul_rn(p, w));
    p = __fadd_rn(-0.00417768164f, __fmul_rn(p, w));
    p = __fadd_rn(0.246640727f, __fmul_rn(p, w));
    p = __fadd_rn(1.50140941f, __fmul_rn(p, w));
  } else {
    w = __fadd_rn(sqrtf(w), -3.0f);
    p = -0.000200214257f;
    p = __fadd_rn(0.000100950558f, __fmul_rn(p, w));
    p = __fadd_rn(0.00134934322f, __fmul_rn(p, w));
    p = __fadd_rn(-0.00367342844f, __fmul_rn(p, w));
    p = __fadd_rn(0.00573950773f, __fmul_rn(p, w));
    p = __fadd_rn(-0.0076224613f, __fmul_rn(p, w));
    p = __fadd_rn(0.00943887047f, __fmul_rn(p, w));
    p = __fadd_rn(1.00167406f, __fmul_rn(p, w));
    p = __fadd_rn(2.83297682f, __fmul_rn(p, w));
  }
  return __fmul_rn(p, u);
}

__device__ __forceinline__ float bits_to_normal(unsigned bits) {
  const unsigned fb = (bits >> 9) | 0x3f800000u;
  const float u01 = __fadd_rn(__uint_as_float(fb), -1.0f);
  const float lo = -0.99999994f;
  float u = __fadd_rn(__fmul_rn(u01, 2.0f), lo);
  u = fmaxf(u, lo);
  return __fmul_rn(1.41421356237309515f, xla_erfinv(u));
}

__device__ __forceinline__ float eps_normal(unsigned i, unsigned layer) {
  unsigned f0 = 0u, f1 = layer;
  tf2x32(0u, 42u, f0, f1);
  unsigned x0 = 0u, x1 = i;
  tf2x32(f0, f1, x0, x1);
  return bits_to_normal(x0 ^ x1);
}

// ---------------------------------------------------------------- fp32 GEMM
template <bool TRANSB>
__global__ __launch_bounds__(256) void gemm_f32(
    const float* __restrict__ Ag, const float* __restrict__ Bg,
    float* __restrict__ Cg, int M, int N, int K, float alpha,
    long long sA, long long sB, long long sC) {
  __shared__ float As[8][132];
  __shared__ float Bs[8][132];
  const float* A = Ag + (long long)blockIdx.z * sA;
  const float* B = Bg + (long long)blockIdx.z * sB;
  float* C = Cg + (long long)blockIdx.z * sC;
  const int m0 = blockIdx.y * 128, n0 = blockIdx.x * 128;
  const int t = threadIdx.x;
  const int tx = t & 15, ty = t >> 4;
  const int ar = t >> 1, ac = (t & 1) * 4;
  const int br = t >> 5, bc = (t & 31) * 4;

  float acc[8][8];
#pragma unroll
  for (int i = 0; i < 8; ++i)
#pragma unroll
    for (int j = 0; j < 8; ++j) acc[i][j] = 0.f;

  for (int k0 = 0; k0 < K; k0 += 8) {
    const float4 av = *(const float4*)(A + (long long)(m0 + ar) * K + (k0 + ac));
    float4 bv;
    if (TRANSB) bv = *(const float4*)(B + (long long)(n0 + ar) * K + (k0 + ac));
    else        bv = *(const float4*)(B + (long long)(k0 + br) * N + (n0 + bc));
    As[ac + 0][ar] = av.x; As[ac + 1][ar] = av.y;
    As[ac + 2][ar] = av.z; As[ac + 3][ar] = av.w;
    if (TRANSB) {
      Bs[ac + 0][ar] = bv.x; Bs[ac + 1][ar] = bv.y;
      Bs[ac + 2][ar] = bv.z; Bs[ac + 3][ar] = bv.w;
    } else {
      *(float4*)&Bs[br][bc] = bv;
    }
    __syncthreads();
#pragma unroll
    for (int kk = 0; kk < 8; ++kk) {
      float a0[8], b0[8];
      *(float4*)&a0[0] = *(const float4*)&As[kk][ty * 8];
      *(float4*)&a0[4] = *(const float4*)&As[kk][ty * 8 + 4];
      *(float4*)&b0[0] = *(const float4*)&Bs[kk][tx * 4];
      *(float4*)&b0[4] = *(const float4*)&Bs[kk][64 + tx * 4];
#pragma unroll
      for (int i = 0; i < 8; ++i)
#pragma unroll
        for (int j = 0; j < 8; ++j) acc[i][j] = fmaf(a0[i], b0[j], acc[i][j]);
    }
    __syncthreads();
  }

#pragma unroll
  for (int i = 0; i < 8; ++i) {
    const int m = m0 + ty * 8 + i;
#pragma unroll
    for (int h = 0; h < 2; ++h) {
      const int n = n0 + h * 64 + tx * 4;
      float4 cv;
      float* cp = (float*)&cv;
#pragma unroll
      for (int jj = 0; jj < 4; ++jj) cp[jj] = acc[i][h * 4 + jj] * alpha;
      *(float4*)(C + (long long)m * N + n) = cv;
    }
  }
}

// ------------------------------------------------- fused Q/K/V projection
__global__ __launch_bounds__(256) void gemm_qkv(
    const float* __restrict__ X,
    const float* __restrict__ wqp, const float* __restrict__ wkp,
    const float* __restrict__ wvp,
    const float* __restrict__ bqp, const float* __restrict__ bkp,
    const float* __restrict__ bvp,
    float* __restrict__ qo, float* __restrict__ ko, float* __restrict__ vo) {
  __shared__ float As[8][132];
  __shared__ float Bs[8][132];
  const int mat = blockIdx.x >> 2;
  const float* B = (mat == 0) ? wqp : (mat == 1) ? wkp : wvp;
  const float* bias = (mat == 0) ? bqp : (mat == 1) ? bkp : bvp;
  float* C = (mat == 0) ? qo : (mat == 1) ? ko : vo;
  const int m0 = blockIdx.y * 128, n0 = (blockIdx.x & 3) * 128;
  const int t = threadIdx.x;
  const int tx = t & 15, ty = t >> 4;
  const int ar = t >> 1, ac = (t & 1) * 4;
  const int br = t >> 5, bc = (t & 31) * 4;

  float acc[8][8];
#pragma unroll
  for (int i = 0; i < 8; ++i)
#pragma unroll
    for (int j = 0; j < 8; ++j) acc[i][j] = 0.f;

  for (int k0 = 0; k0 < DMODEL; k0 += 8) {
    const float4 av = *(const float4*)(X + (long long)(m0 + ar) * DMODEL + (k0 + ac));
    const float4 bv = *(const float4*)(B + (long long)(k0 + br) * DMODEL + (n0 + bc));
    As[ac + 0][ar] = av.x; As[ac + 1][ar] = av.y;
    As[ac + 2][ar] = av.z; As[ac + 3][ar] = av.w;
    *(float4*)&Bs[br][bc] = bv;
    __syncthreads();
#pragma unroll
    for (int kk = 0; kk < 8; ++kk) {
      float a0[8], b0[8];
      *(float4*)&a0[0] = *(const float4*)&As[kk][ty * 8];
      *(float4*)&a0[4] = *(const float4*)&As[kk][ty * 8 + 4];
      *(float4*)&b0[0] = *(const float4*)&Bs[kk][tx * 4];
      *(float4*)&b0[4] = *(const float4*)&Bs[kk][64 + tx * 4];
#pragma unroll
      for (int i = 0; i < 8; ++i)
#pragma unroll
        for (int j = 0; j < 8; ++j) acc[i][j] = fmaf(a0[i], b0[j], acc[i][j]);
    }
    __syncthreads();
  }
#pragma unroll
  for (int i = 0; i < 8; ++i) {
    const int m = m0 + ty * 8 + i;
#pragma unroll
    for (int h = 0; h < 2; ++h) {
      const int n = n0 + h * 64 + tx * 4;
      float4 cv;
      float* cp = (float*)&cv;
#pragma unroll
      for (int jj = 0; jj < 4; ++jj) cp[jj] = acc[i][h * 4 + jj] + bias[n + jj];
      *(float4*)(C + (long long)m * DMODEL + n) = cv;
    }
  }
}

// ------------------------------------------------- split / transpose-split
__global__ __launch_bounds__(256) void split_f32_bf16(
    const float* __restrict__ in, u16* __restrict__ hi, u16* __restrict__ lo,
    int n) {
  const int i = (blockIdx.x * 256 + threadIdx.x) * 4;
  if (i >= n) return;
  const float4 v = *(const float4*)(in + i);
  ushort4 h, l;
  h.x = f2bf(v.x); l.x = f2bf(v.x - bf2f(h.x));
  h.y = f2bf(v.y); l.y = f2bf(v.y - bf2f(h.y));
  h.z = f2bf(v.z); l.z = f2bf(v.z - bf2f(h.z));
  h.w = f2bf(v.w); l.w = f2bf(v.w - bf2f(h.w));
  *(ushort4*)(hi + i) = h;
  *(ushort4*)(lo + i) = l;
}

// in [E][R][C] f32 -> hi/lo [E][C][R] bf16
__global__ __launch_bounds__(256) void transpose_split(
    const float* __restrict__ in, u16* __restrict__ hi, u16* __restrict__ lo,
    int R, int C) {
  __shared__ float tile[32][33];
  const size_t eoff = (size_t)blockIdx.z * R * C;
  const float* src = in + eoff;
  const int r0 = blockIdx.y * 32, c0 = blockIdx.x * 32;
  const int tx = threadIdx.x & 31, ty = threadIdx.x >> 5;
#pragma unroll
  for (int j = 0; j < 4; ++j)
    tile[ty + 8 * j][tx] = src[(size_t)(r0 + ty + 8 * j) * C + c0 + tx];
  __syncthreads();
  u16* dh = hi + eoff;
  u16* dl = lo + eoff;
#pragma unroll
  for (int j = 0; j < 4; ++j) {
    const float v = tile[tx][ty + 8 * j];
    const u16 h = f2bf(v);
    const size_t idx = (size_t)(c0 + ty + 8 * j) * R + r0 + tx;
    dh[idx] = h;
    dl[idx] = f2bf(v - bf2f(h));
  }
}

// ------------------------------------------------- MFMA expert GEMM 1
// H[row] = relu(Xbf[list[row]] @ W1T[e]^T + b1[e]); split-bf16 (3-pass)
#define SWZC(lane) ((((lane) >> 4) ^ ((lane) & 3)) * 8)

template <int PASSES>
__global__ __launch_bounds__(256) void mfma_moe1(
    const u16* __restrict__ Ahi, const u16* __restrict__ Alo,
    const u16* __restrict__ Bhi, const u16* __restrict__ Blo,
    const float* __restrict__ b1l, const int* __restrict__ list,
    const int* __restrict__ blockExp, const int* __restrict__ blockBase,
    const int* __restrict__ blockValid, int byOff,
    u16* __restrict__ Hhi, u16* __restrict__ Hlo) {
  constexpr int K = DMODEL;
  constexpr int NT = 128 * 40;
  __shared__ u16 lds[(PASSES == 3 ? 4 : 2) * NT];
  u16(*As)[40] = (u16(*)[40])lds;
  u16(*Bs)[40] = (u16(*)[40])(lds + NT);
  u16(*Als)[40] = (u16(*)[40])(lds + 2 * NT);
  u16(*Bls)[40] = (u16(*)[40])(lds + 3 * NT);
  const int by = byOff + blockIdx.y;
  const int e = blockExp[by];
  if (e < 0) return;
  const int row0 = blockBase[by], valid = blockValid[by];
  const int hbase = blockBase[byOff];
  const int n0 = blockIdx.x * 128;
  const int t = threadIdx.x;
  const int sr = t >> 1, c0 = (t & 1) * 2;
  const int w0 = ((c0) ^ (sr & 3)) * 8, w1 = ((c0 + 1) ^ (sr & 3)) * 8;
  const int atok = list[row0 + ((sr < valid) ? sr : 0)];
  const u16* aH = Ahi + (size_t)atok * K;
  const u16* aL = Alo + (size_t)atok * K;
  const u16* bH = Bhi + ((size_t)e * HDIM + n0 + sr) * K;
  const u16* bL = Blo + ((size_t)e * HDIM + n0 + sr) * K;
  const int lane = t & 63, w = t >> 6;
  const int wm = (w >> 1) * 64, wn = (w & 1) * 64;
  const int lr = lane & 15;
  const int kcol = SWZC(lane);

  f32x4 acc[4][4] = {};
  for (int k0 = 0; k0 < K; k0 += 32) {
    __syncthreads();
    *(uint4*)&As[sr][w0] = *(const uint4*)(aH + k0 + c0 * 8);
    *(uint4*)&As[sr][w1] = *(const uint4*)(aH + k0 + c0 * 8 + 8);
    *(uint4*)&Bs[sr][w0] = *(const uint4*)(bH + k0 + c0 * 8);
    *(uint4*)&Bs[sr][w1] = *(const uint4*)(bH + k0 + c0 * 8 + 8);
    if constexpr (PASSES == 3) {
      *(uint4*)&Als[sr][w0] = *(const uint4*)(aL + k0 + c0 * 8);
      *(uint4*)&Als[sr][w1] = *(const uint4*)(aL + k0 + c0 * 8 + 8);
      *(uint4*)&Bls[sr][w0] = *(const uint4*)(bL + k0 + c0 * 8);
      *(uint4*)&Bls[sr][w1] = *(const uint4*)(bL + k0 + c0 * 8 + 8);
    }
    __syncthreads();
    bf16x8 ah[4], bh[4];
#pragma unroll
    for (int i = 0; i < 4; ++i) {
      ah[i] = *(const bf16x8*)&As[wm + i * 16 + lr][kcol];
      bh[i] = *(const bf16x8*)&Bs[wn + i * 16 + lr][kcol];
    }
    if constexpr (PASSES == 3) {
      bf16x8 al[4], bl[4];
#pragma unroll
      for (int i = 0; i < 4; ++i) {
        al[i] = *(const bf16x8*)&Als[wm + i * 16 + lr][kcol];
        bl[i] = *(const bf16x8*)&Bls[wn + i * 16 + lr][kcol];
      }
#pragma unroll
      for (int i = 0; i < 4; ++i)
#pragma unroll
        for (int j = 0; j < 4; ++j) {
          acc[i][j] = __builtin_amdgcn_mfma_f32_16x16x32_bf16(ah[i], bh[j], acc[i][j], 0, 0, 0);
          acc[i][j] = __builtin_amdgcn_mfma_f32_16x16x32_bf16(al[i], bh[j], acc[i][j], 0, 0, 0);
          acc[i][j] = __builtin_amdgcn_mfma_f32_16x16x32_bf16(ah[i], bl[j], acc[i][j], 0, 0, 0);
        }
    } else {
#pragma unroll
      for (int i = 0; i < 4; ++i)
#pragma unroll
        for (int j = 0; j < 4; ++j)
          acc[i][j] = __builtin_amdgcn_mfma_f32_16x16x32_bf16(ah[i], bh[j], acc[i][j], 0, 0, 0);
    }
  }
#pragma unroll
  for (int i = 0; i < 4; ++i) {
#pragma unroll
    for (int j = 0; j < 4; ++j) {
      const int n = n0 + wn + j * 16 + lr;
      const float bv = b1l[(size_t)e * HDIM + n];
#pragma unroll
      for (int r = 0; r < 4; ++r) {
        const int m = wm + i * 16 + (lane >> 4) * 4 + r;
        if (m < valid) {
          const float h = fmaxf(acc[i][j][r] + bv, 0.f);
          const u16 hh = f2bf(h);
          const size_t idx = (size_t)(row0 + m - hbase) * HDIM + n;
          Hhi[idx] = hh;
          if constexpr (PASSES == 3) Hlo[idx] = f2bf(h - bf2f(hh));
        }
      }
    }
  }
}

// ------------------------------------------------- MFMA expert GEMM 2
// moe[list[row]] += (H[row] @ W2T[e]^T + b2[e]) * rowGate[row]
template <int PASSES>
__global__ __launch_bounds__(256) void mfma_moe2(
    const u16* __restrict__ Hhi, const u16* __restrict__ Hlo,
    const u16* __restrict__ Bhi, const u16* __restrict__ Blo,
    const float* __restrict__ b2l, const int* __restrict__ list,
    const int* __restrict__ blockExp, const int* __restrict__ blockBase,
    const int* __restrict__ blockValid, int byOff,
    const float* __restrict__ rowGate, float* __restrict__ moe) {
  constexpr int K = HDIM;
  constexpr int NT = 128 * 40;
  __shared__ u16 lds[(PASSES == 3 ? 4 : 2) * NT];
  u16(*As)[40] = (u16(*)[40])lds;
  u16(*Bs)[40] = (u16(*)[40])(lds + NT);
  u16(*Als)[40] = (u16(*)[40])(lds + 2 * NT);
  u16(*Bls)[40] = (u16(*)[40])(lds + 3 * NT);
  const int by = byOff + blockIdx.y;
  const int e = blockExp[by];
  if (e < 0) return;
  const int row0 = blockBase[by], valid = blockValid[by];
  const int hbase = blockBase[byOff];
  const int n0 = blockIdx.x * 128;
  const int t = threadIdx.x;
  const int sr = t >> 1, c0 = (t & 1) * 2;
  const int w0 = ((c0) ^ (sr & 3)) * 8, w1 = ((c0 + 1) ^ (sr & 3)) * 8;
  const u16* aH = Hhi + (size_t)(row0 + sr - hbase) * K;
  const u16* aL = Hlo + (size_t)(row0 + sr - hbase) * K;
  const u16* bH = Bhi + ((size_t)e * DMODEL + n0 + sr) * K;
  const u16* bL = Blo + ((size_t)e * DMODEL + n0 + sr) * K;
  const int lane = t & 63, w = t >> 6;
  const int wm = (w >> 1) * 64, wn = (w & 1) * 64;
  const int lr = lane & 15;
  const int kcol = SWZC(lane);

  f32x4 acc[4][4] = {};
  for (int k0 = 0; k0 < K; k0 += 32) {
    __syncthreads();
    *(uint4*)&As[sr][w0] = *(const uint4*)(aH + k0 + c0 * 8);
    *(uint4*)&As[sr][w1] = *(const uint4*)(aH + k0 + c0 * 8 + 8);
    *(uint4*)&Bs[sr][w0] = *(const uint4*)(bH + k0 + c0 * 8);
    *(uint4*)&Bs[sr][w1] = *(const uint4*)(bH + k0 + c0 * 8 + 8);
    if constexpr (PASSES == 3) {
      *(uint4*)&Als[sr][w0] = *(const uint4*)(aL + k0 + c0 * 8);
      *(uint4*)&Als[sr][w1] = *(const uint4*)(aL + k0 + c0 * 8 + 8);
      *(uint4*)&Bls[sr][w0] = *(const uint4*)(bL + k0 + c0 * 8);
      *(uint4*)&Bls[sr][w1] = *(const uint4*)(bL + k0 + c0 * 8 + 8);
    }
    __syncthreads();
    bf16x8 ah[4], bh[4];
#pragma unroll
    for (int i = 0; i < 4; ++i) {
      ah[i] = *(const bf16x8*)&As[wm + i * 16 + lr][kcol];
      bh[i] = *(const bf16x8*)&Bs[wn + i * 16 + lr][kcol];
    }
    if constexpr (PASSES == 3) {
      bf16x8 al[4], bl[4];
#pragma unroll
      for (int i = 0; i < 4; ++i) {
        al[i] = *(const bf16x8*)&Als[wm + i * 16 + lr][kcol];
        bl[i] = *(const bf16x8*)&Bls[wn + i * 16 + lr][kcol];
      }
#pragma unroll
      for (int i = 0; i < 4; ++i)
#pragma unroll
        for (int j = 0; j < 4; ++j) {
          acc[i][j] = __builtin_amdgcn_mfma_f32_16x16x32_bf16(ah[i], bh[j], acc[i][j], 0, 0, 0);
          acc[i][j] = __builtin_amdgcn_mfma_f32_16x16x32_bf16(al[i], bh[j], acc[i][j], 0, 0, 0);
          acc[i][j] = __builtin_amdgcn_mfma_f32_16x16x32_bf16(ah[i], bl[j], acc[i][j], 0, 0, 0);
        }
    } else {
#pragma unroll
      for (int i = 0; i < 4; ++i)
#pragma unroll
        for (int j = 0; j < 4; ++j)
          acc[i][j] = __builtin_amdgcn_mfma_f32_16x16x32_bf16(ah[i], bh[j], acc[i][j], 0, 0, 0);
    }
  }
#pragma unroll
  for (int i = 0; i < 4; ++i) {
#pragma unroll
    for (int r = 0; r < 4; ++r) {
      const int m = wm + i * 16 + (lane >> 4) * 4 + r;
      if (m >= valid) continue;
      const int tok = list[row0 + m];
      const float g = rowGate[row0 + m];
      float* orow = moe + (size_t)tok * DMODEL;
#pragma unroll
      for (int j = 0; j < 4; ++j) {
        const int n = n0 + wn + j * 16 + lr;
        atomicAdd(orow + n, (acc[i][j][r] + b2l[(size_t)e * DMODEL + n]) * g);
      }
    }
  }
}

// ---------------------------------------------------------------- RoPE
__global__ __launch_bounds__(256) void rope_rot(
    float* __restrict__ q, float* __restrict__ k,
    const float* __restrict__ nc, const float* __restrict__ wr) {
  const int tok = blockIdx.x, j = threadIdx.x;
  const float c0 = nc[tok * 2 + 0], c1 = nc[tok * 2 + 1];
  const float f = c0 * wr[j] + c1 * wr[256 + j];
  const float cf = cosf(f), sf = sinf(f);
  float2* q2 = (float2*)(q + (long long)tok * DMODEL);
  float2* k2 = (float2*)(k + (long long)tok * DMODEL);
  const float2 qq = q2[j];
  const float2 kk = k2[j];
  q2[j] = make_float2(qq.x * cf - qq.y * sf, qq.x * sf + qq.y * cf);
  k2[j] = make_float2(kk.x * cf - kk.y * sf, kk.x * sf + kk.y * cf);
}

// ---------------------------------------------------------------- softmax
__global__ __launch_bounds__(256) void attn_softmax(
    float* __restrict__ S, const unsigned char* __restrict__ pad) {
  const int q = blockIdx.x & (LSEQ - 1);
  const int b = blockIdx.x >> 10;
  float* row = S + (long long)blockIdx.x * LSEQ;
  const int t = threadIdx.x;
  const float4 v = ((const float4*)row)[t];
  float vals[4] = {v.x, v.y, v.z, v.w};
  const int k0 = t * 4;
#pragma unroll
  for (int j = 0; j < 4; ++j) {
    const int k = k0 + j;
    if (k > q || pad[b * LSEQ + k]) vals[j] = -INFINITY;
  }
  __shared__ float red[4];
  const int wid = t >> 6, lane = t & 63;
  float m = waveAllMax(fmaxf(fmaxf(vals[0], vals[1]), fmaxf(vals[2], vals[3])));
  if (lane == 0) red[wid] = m;
  __syncthreads();
  m = fmaxf(fmaxf(red[0], red[1]), fmaxf(red[2], red[3]));
  const float e0 = expf(vals[0] - m), e1 = expf(vals[1] - m);
  const float e2 = expf(vals[2] - m), e3 = expf(vals[3] - m);
  const float ps = waveAllSum(e0 + e1 + e2 + e3);
  __syncthreads();
  if (lane == 0) red[wid] = ps;
  __syncthreads();
  const float tot = red[0] + red[1] + red[2] + red[3];
  float4 o;
  o.x = e0 / tot; o.y = e1 / tot; o.z = e2 / tot; o.w = e3 / tot;
  ((float4*)row)[t] = o;
}

// ---------------------------------------------------------------- add + LN
__global__ __launch_bounds__(128) void ln_add(
    const float* __restrict__ Aa, const float* __restrict__ Bb,
    const float* __restrict__ gg, const float* __restrict__ bb,
    float* __restrict__ out) {
  const int row = blockIdx.x, t = threadIdx.x;
  const float4 va = ((const float4*)(Aa + (long long)row * DMODEL))[t];
  const float4 vb = ((const float4*)(Bb + (long long)row * DMODEL))[t];
  const float x0 = va.x + vb.x, x1 = va.y + vb.y;
  const float x2 = va.z + vb.z, x3 = va.w + vb.w;
  __shared__ float r1[2], r2[2];
  const int wid = t >> 6, lane = t & 63;
  const float s = waveAllSum(x0 + x1 + x2 + x3);
  if (lane == 0) r1[wid] = s;
  __syncthreads();
  const float mean = (r1[0] + r1[1]) * (1.0f / DMODEL);
  const float d0 = x0 - mean, d1 = x1 - mean, d2 = x2 - mean, d3 = x3 - mean;
  const float vs = waveAllSum(d0 * d0 + d1 * d1 + d2 * d2 + d3 * d3);
  if (lane == 0) r2[wid] = vs;
  __syncthreads();
  const float var = (r2[0] + r2[1]) * (1.0f / DMODEL);
  const float rs = rsqrtf(var + 1e-5f);
  const float4 g4 = ((const float4*)gg)[t];
  const float4 b4 = ((const float4*)bb)[t];
  float4 o;
  o.x = d0 * rs * g4.x + b4.x;
  o.y = d1 * rs * g4.y + b4.y;
  o.z = d2 * rs * g4.z + b4.z;
  o.w = d3 * rs * g4.w + b4.w;
  ((float4*)(out + (long long)row * DMODEL))[t] = o;
}

// ------------------------------------------------- router + topk + gate
__global__ __launch_bounds__(64) void router_topk(
    const float* __restrict__ x, const float* __restrict__ rtw,
    const float* __restrict__ rtb, const float* __restrict__ nzw,
    const float* __restrict__ nzb, float* __restrict__ gate,
    int* __restrict__ counts, unsigned char* __restrict__ selmask, int layer) {
  __shared__ float xs[DMODEL];
  __shared__ float red[16];
  __shared__ float noisy[8];
  const int tok = blockIdx.x, t = threadIdx.x;
  const float4* x4 = (const float4*)(x + (long long)tok * DMODEL);
  ((float4*)xs)[t] = x4[t];
  ((float4*)xs)[64 + t] = x4[64 + t];
  __syncthreads();
  const int o = t >> 2, p = t & 3, e = o & 7;
  const float* W = (o < 8) ? rtw : nzw;
  float s = 0.f;
  const int d0 = p * 128;
  for (int d = 0; d < 128; ++d) s = fmaf(xs[d0 + d], W[(d0 + d) * NEXP + e], s);
  s += __shfl_xor(s, 1, 64);
  s += __shfl_xor(s, 2, 64);
  if (p == 0) red[o] = s;
  __syncthreads();
  if (t < 8) {
    const float logit = red[t] + rtb[t];
    const float nl = red[8 + t] + nzb[t];
    const float eps = eps_normal((unsigned)(tok * NEXP + t), (unsigned)layer);
    const float sp = fmaxf(nl, 0.f) + log1pf(expf(-fabsf(nl)));
    noisy[t] = logit + eps * sp;
  }
  __syncthreads();
  if (t == 0) {
    float v[8]; bool sel[8];
#pragma unroll
    for (int i = 0; i < 8; ++i) { v[i] = noisy[i]; sel[i] = false; }
    for (int r = 0; r < TOPK; ++r) {
      int bi = 0; float best = -INFINITY;
      for (int i = 0; i < 8; ++i)
        if (!sel[i] && v[i] > best) { best = v[i]; bi = i; }
      sel[bi] = true;
    }
    float m = -INFINITY;
    for (int i = 0; i < 8; ++i) if (sel[i]) m = fmaxf(m, v[i]);
    float ex[8]; float den = 0.f;
    unsigned char mbits = 0;
    for (int i = 0; i < 8; ++i) {
      ex[i] = sel[i] ? expf(v[i] - m) : 0.f;
      den += ex[i];
      if (sel[i]) { mbits |= (unsigned char)(1u << i); atomicAdd(&counts[i], 1); }
    }
    for (int i = 0; i < 8; ++i) gate[tok * NEXP + i] = ex[i] / den;
    selmask[tok] = mbits;
  }
}

// ------------------------------------------------- dispatch plan/build/zero
__global__ void moe_plan(const int* __restrict__ counts, int* __restrict__ start,
                         int* __restrict__ blockExp, int* __restrict__ blockBase,
                         int* __restrict__ blockValid) {
  if (threadIdx.x != 0) return;
  int s = 0, by = 0;
  for (int e = 0; e < NEXP; ++e) {
    start[e] = s;
    const int c = counts[e];
    const int nb = (c + 127) >> 7;
    for (int b = 0; b < nb; ++b) {
      blockExp[by] = e;
      blockBase[by] = s + b * 128;
      blockValid[by] = min(128, c - b * 128);
      ++by;
    }
    s += nb * 128;
  }
  for (; by < NBLK; ++by) { blockExp[by] = -1; blockBase[by] = s; blockValid[by] = 0; }
}

__global__ __launch_bounds__(256) void moe_build(
    const unsigned char* __restrict__ selmask, const int* __restrict__ start,
    int* __restrict__ cursor, int* __restrict__ list,
    const float* __restrict__ gate, float* __restrict__ rowGate) {
  const int tok = blockIdx.x * 256 + threadIdx.x;
  if (tok >= TOK) return;
  unsigned m = selmask[tok];
  while (m) {
    const int e = __ffs(m) - 1;
    m &= m - 1;
    const int slot = atomicAdd(&cursor[e], 1);
    list[start[e] + slot] = tok;
    rowGate[start[e] + slot] = gate[tok * NEXP + e];
  }
}

__global__ __launch_bounds__(256) void zero_f32(float* __restrict__ p, int n4) {
  const int i = blockIdx.x * 256 + threadIdx.x;
  if (i < n4) ((float4*)p)[i] = make_float4(0.f, 0.f, 0.f, 0.f);
}
__global__ void zero_i32(int* __restrict__ p, int n) {
  const int i = threadIdx.x;
  if (i < n) p[i] = 0;
}

// ---------------------------------------------------------------- launch
extern "C" void kernel_launch(void* const* d_in, const int* in_sizes, int n_in,
                              void* d_out, int out_size, void* d_ws,
                              size_t ws_size, hipStream_t stream) {
  const float* x_in = (const float*)d_in[0];
  const float* nc = (const float*)d_in[1];
  const unsigned char* pad = (const unsigned char*)d_in[3];
  const float* wq = (const float*)d_in[4];
  const float* bq = (const float*)d_in[5];
  const float* wk = (const float*)d_in[6];
  const float* bk = (const float*)d_in[7];
  const float* wv = (const float*)d_in[8];
  const float* bv = (const float*)d_in[9];
  const float* wr = (const float*)d_in[10];
  const float* ln1g = (const float*)d_in[11];
  const float* ln1b = (const float*)d_in[12];
  const float* rtw = (const float*)d_in[13];
  const float* rtb = (const float*)d_in[14];
  const float* nzw = (const float*)d_in[15];
  const float* nzb = (const float*)d_in[16];
  const float* ew1 = (const float*)d_in[17];
  const float* eb1 = (const float*)d_in[18];
  const float* ew2 = (const float*)d_in[19];
  const float* eb2 = (const float*)d_in[20];
  const float* ln2g = (const float*)d_in[21];
  const float* ln2b = (const float*)d_in[22];

  float* ws = (float*)d_ws;
  const long long SZ = (long long)TOK * DMODEL;  // 2,097,152
  float* qb = ws;
  float* kb = ws + SZ;
  float* vb2 = ws + 2 * SZ;
  float* xcur = ws + 3 * SZ;
  float* moe = ws + 4 * SZ;
  float* gate = ws + 5 * SZ;                         // 10,485,760 (+32768)
  int* meta = (int*)(ws + 10518528);
  int* counts = meta;
  int* cursor = meta + 8;
  int* startE = meta + 16;
  int* blockExp = meta + 24;
  int* blockBase = meta + 160;
  int* blockValid = meta + 296;
  int* list = meta + 432;                            // 17408 ints
  unsigned char* selmask = (unsigned char*)(meta + 17840);  // 4096 B
  float* rowGate = ws + 10537408;                    // 17408 floats
  u16* Xhi = (u16*)(ws + 10554816);
  u16* Xlo = (u16*)(ws + 11603392);
  float* scores = ws + 12651968;                     // aliases W1Thi
  u16* W1Thi = (u16*)(ws + 12651968);
  u16* W1Tlo = (u16*)(ws + 16846272);
  u16* W2Thi = (u16*)(ws + 21040576);
  u16* W2Tlo = (u16*)(ws + 25234880);
  u16* Hhi = (u16*)(ws + 29429184);                  // 8704 x 2048 bf16
  u16* Hlo = (u16*)(ws + 38342080);                  // total end 47,254,976 f

  const float iscale = 1.0f / sqrtf((float)DMODEL);
  const dim3 blk(256);

  for (int l = 0; l < NLAYER; ++l) {
    const float* xl = (l == 0) ? x_in : xcur;
    const long long wOff = (long long)l * DMODEL * DMODEL;

    gemm_qkv<<<dim3(12, TOK / 128), blk, 0, stream>>>(
        xl, wq + wOff, wk + wOff, wv + wOff, bq + l * DMODEL, bk + l * DMODEL,
        bv + l * DMODEL, qb, kb, vb2);

    rope_rot<<<TOK, 256, 0, stream>>>(qb, kb, nc, wr + (long long)l * DMODEL);

    gemm_f32<true><<<dim3(8, 8, BATCH), blk, 0, stream>>>(
        qb, kb, scores, LSEQ, LSEQ, DMODEL, iscale,
        (long long)LSEQ * DMODEL, (long long)LSEQ * DMODEL, (long long)LSEQ * LSEQ);

    attn_softmax<<<BATCH * LSEQ, 256, 0, stream>>>(scores, pad);

    gemm_f32<false><<<dim3(4, 8, BATCH), blk, 0, stream>>>(
        scores, vb2, qb, LSEQ, DMODEL, LSEQ, 1.f,
        (long long)LSEQ * LSEQ, (long long)LSEQ * DMODEL, (long long)LSEQ * DMODEL);

    ln_add<<<TOK, 128, 0, stream>>>(xl, qb, ln1g + l * DMODEL, ln1b + l * DMODEL, xcur);

    zero_i32<<<1, 64, 0, stream>>>(counts, 16);
    router_topk<<<TOK, 64, 0, stream>>>(xcur, rtw + l * DMODEL * NEXP,
                                        rtb + l * NEXP, nzw + l * DMODEL * NEXP,
                                        nzb + l * NEXP, gate, counts, selmask, l);
    moe_plan<<<1, 64, 0, stream>>>(counts, startE, blockExp, blockBase, blockValid);
    moe_build<<<TOK / 256, 256, 0, stream>>>(selmask, startE, cursor, list, gate, rowGate);
    zero_f32<<<(int)(SZ / 4 / 256), 256, 0, stream>>>(moe, (int)(SZ / 4));

    split_f32_bf16<<<(int)(SZ / 4 / 256), 256, 0, stream>>>(xcur, Xhi, Xlo, (int)SZ);
    transpose_split<<<dim3(64, 16, 8), blk, 0, stream>>>(
        ew1 + (long long)l * NEXP * DMODEL * HDIM, W1Thi, W1Tlo, DMODEL, HDIM);
    transpose_split<<<dim3(16, 64, 8), blk, 0, stream>>>(
        ew2 + (long long)l * NEXP * HDIM * DMODEL, W2Thi, W2Tlo, HDIM, DMODEL);

    const float* b1l = eb1 + (long long)l * NEXP * HDIM;
    const float* b2l = eb2 + (long long)l * NEXP * DMODEL;
    for (int ch = 0; ch < 2; ++ch) {
      const int byOff = ch * CHBLK;
      // 3-pass split-bf16 for BOTH layers this round (conservative while the
      // verification tolerance is unanchored for the MFMA path).
      mfma_moe1<3><<<dim3(HDIM / 128, CHBLK), blk, 0, stream>>>(
          Xhi, Xlo, W1Thi, W1Tlo, b1l, list, blockExp, blockBase, blockValid,
          byOff, Hhi, Hlo);
      mfma_moe2<3><<<dim3(DMODEL / 128, CHBLK), blk, 0, stream>>>(
          Hhi, Hlo, W2Thi, W2Tlo, b2l, list, blockExp, blockBase, blockValid,
          byOff, rowGate, moe);
    }

    float* outp = (l == NLAYER - 1) ? (float*)d_out : xcur;
    ln_add<<<TOK, 128, 0, stream>>>(xcur, moe, ln2g + l * DMODEL, ln2b + l * DMODEL, outp);
  }
}

// Round 8
// 1854.068 us; speedup vs baseline: 1.8910x; 1.3413x over previous
//
#include <hip/hip_runtime.h>
#include <math.h>

#define TOK 4096      // B*L
#define DMODEL 512
#define LSEQ 1024
#define BATCH 4
#define NLAYER 2
#define NEXP 8
#define TOPK 4
#define HDIM 2048
#define NBLK 136
#define CHBLK 68

typedef unsigned short u16;
typedef __attribute__((ext_vector_type(8))) short bf16x8;
typedef __attribute__((ext_vector_type(4))) float f32x4;

// ---------------------------------------------------------------- bf16 split
__device__ __forceinline__ u16 f2bf(float x) {
  const unsigned u = __float_as_uint(x);
  return (u16)((u + 0x7FFFu + ((u >> 16) & 1u)) >> 16);
}
__device__ __forceinline__ float bf2f(u16 h) {
  return __uint_as_float(((unsigned)h) << 16);
}

// ---------------------------------------------------------------- reductions
__device__ __forceinline__ float waveAllSum(float v) {
#pragma unroll
  for (int off = 1; off < 64; off <<= 1) v += __shfl_xor(v, off, 64);
  return v;
}
__device__ __forceinline__ float waveAllMax(float v) {
#pragma unroll
  for (int off = 1; off < 64; off <<= 1) v = fmaxf(v, __shfl_xor(v, off, 64));
  return v;
}

// ---------------------------------------------------------------- threefry
__device__ __forceinline__ unsigned rotl32(unsigned x, int r) {
  return (x << r) | (x >> (32 - r));
}
__device__ __forceinline__ void tf2x32(unsigned k0, unsigned k1,
                                       unsigned& x0, unsigned& x1) {
  const unsigned ks0 = k0, ks1 = k1, ks2 = k0 ^ k1 ^ 0x1BD11BDAu;
  x0 += ks0; x1 += ks1;
#define TF_R4(a, b, c, d)                                   \
  x0 += x1; x1 = rotl32(x1, a); x1 ^= x0;                   \
  x0 += x1; x1 = rotl32(x1, b); x1 ^= x0;                   \
  x0 += x1; x1 = rotl32(x1, c); x1 ^= x0;                   \
  x0 += x1; x1 = rotl32(x1, d); x1 ^= x0;
  TF_R4(13, 15, 26, 6)  x0 += ks1; x1 += ks2 + 1u;
  TF_R4(17, 29, 16, 24) x0 += ks2; x1 += ks0 + 2u;
  TF_R4(13, 15, 26, 6)  x0 += ks0; x1 += ks1 + 3u;
  TF_R4(17, 29, 16, 24) x0 += ks1; x1 += ks2 + 4u;
  TF_R4(13, 15, 26, 6)  x0 += ks2; x1 += ks0 + 5u;
#undef TF_R4
}

__device__ __forceinline__ float xla_erfinv(float u) {
  float w = -log1pf(-__fmul_rn(u, u));
  float p;
  if (w < 5.0f) {
    w = __fadd_rn(w, -2.5f);
    p = 2.81022636e-08f;
    p = __fadd_rn(3.43273939e-07f, __fmul_rn(p, w));
    p = __fadd_rn(-3.5233877e-06f, __fmul_rn(p, w));
    p = __fadd_rn(-4.39150654e-06f, __fmul_rn(p, w));
    p = __fadd_rn(0.00021858087f, __fmul_rn(p, w));
    p = __fadd_rn(-0.00125372503f, __fmul_rn(p, w));
    p = __fadd_rn(-0.00417768164f, __fmul_rn(p, w));
    p = __fadd_rn(0.246640727f, __fmul_rn(p, w));
    p = __fadd_rn(1.50140941f, __fmul_rn(p, w));
  } else {
    w = __fadd_rn(sqrtf(w), -3.0f);
    p = -0.000200214257f;
    p = __fadd_rn(0.000100950558f, __fmul_rn(p, w));
    p = __fadd_rn(0.00134934322f, __fmul_rn(p, w));
    p = __fadd_rn(-0.00367342844f, __fmul_rn(p, w));
    p = __fadd_rn(0.00573950773f, __fmul_rn(p, w));
    p = __fadd_rn(-0.0076224613f, __fmul_rn(p, w));
    p = __fadd_rn(0.00943887047f, __fmul_rn(p, w));
    p = __fadd_rn(1.00167406f, __fmul_rn(p, w));
    p = __fadd_rn(2.83297682f, __fmul_rn(p, w));
  }
  return __fmul_rn(p, u);
}

__device__ __forceinline__ float bits_to_normal(unsigned bits) {
  const unsigned fb = (bits >> 9) | 0x3f800000u;
  const float u01 = __fadd_rn(__uint_as_float(fb), -1.0f);
  const float lo = -0.99999994f;
  float u = __fadd_rn(__fmul_rn(u01, 2.0f), lo);
  u = fmaxf(u, lo);
  return __fmul_rn(1.41421356237309515f, xla_erfinv(u));
}

__device__ __forceinline__ float eps_normal(unsigned i, unsigned layer) {
  unsigned f0 = 0u, f1 = layer;
  tf2x32(0u, 42u, f0, f1);
  unsigned x0 = 0u, x1 = i;
  tf2x32(f0, f1, x0, x1);
  return bits_to_normal(x0 ^ x1);
}

// ------------------------------------------------- split / transpose-split
__global__ __launch_bounds__(256) void split_f32_bf16(
    const float* __restrict__ in, u16* __restrict__ hi, u16* __restrict__ lo,
    int n) {
  const int i = (blockIdx.x * 256 + threadIdx.x) * 4;
  if (i >= n) return;
  const float4 v = *(const float4*)(in + i);
  ushort4 h, l;
  h.x = f2bf(v.x); l.x = f2bf(v.x - bf2f(h.x));
  h.y = f2bf(v.y); l.y = f2bf(v.y - bf2f(h.y));
  h.z = f2bf(v.z); l.z = f2bf(v.z - bf2f(h.z));
  h.w = f2bf(v.w); l.w = f2bf(v.w - bf2f(h.w));
  *(ushort4*)(hi + i) = h;
  *(ushort4*)(lo + i) = l;
}

// in [Z][R][C] f32 -> hi/lo [Z][C][R] bf16
__global__ __launch_bounds__(256) void transpose_split(
    const float* __restrict__ in, u16* __restrict__ hi, u16* __restrict__ lo,
    int R, int C) {
  __shared__ float tile[32][33];
  const size_t eoff = (size_t)blockIdx.z * R * C;
  const float* src = in + eoff;
  const int r0 = blockIdx.y * 32, c0 = blockIdx.x * 32;
  const int tx = threadIdx.x & 31, ty = threadIdx.x >> 5;
#pragma unroll
  for (int j = 0; j < 4; ++j)
    tile[ty + 8 * j][tx] = src[(size_t)(r0 + ty + 8 * j) * C + c0 + tx];
  __syncthreads();
  u16* dh = hi + eoff;
  u16* dl = lo + eoff;
#pragma unroll
  for (int j = 0; j < 4; ++j) {
    const float v = tile[tx][ty + 8 * j];
    const u16 h = f2bf(v);
    const size_t idx = (size_t)(c0 + ty + 8 * j) * R + r0 + tx;
    dh[idx] = h;
    dl[idx] = f2bf(v - bf2f(h));
  }
}

#define SWZC(lane) ((((lane) >> 4) ^ ((lane) & 3)) * 8)

// ------------------------------------------------- generic 3-pass MFMA GEMM
// C[z][M][N] = alpha*(A[z] @ B[z]^T) + bias ; A MxK, B NxK row-major, split hi/lo.
// M, N multiples of 128; K multiple of 32.
template <int PASSES>
__global__ __launch_bounds__(256) void mfma_gemm3(
    const u16* __restrict__ Ahi, const u16* __restrict__ Alo,
    const u16* __restrict__ Bhi, const u16* __restrict__ Blo,
    const float* __restrict__ bias, float* __restrict__ Cg,
    int N, int K, float alpha,
    long long sA, long long sB, long long sC) {
  constexpr int NT = 128 * 40;
  __shared__ u16 lds[(PASSES == 3 ? 4 : 2) * NT];
  u16(*As)[40] = (u16(*)[40])lds;
  u16(*Bs)[40] = (u16(*)[40])(lds + NT);
  u16(*Als)[40] = (u16(*)[40])(lds + 2 * NT);
  u16(*Bls)[40] = (u16(*)[40])(lds + 3 * NT);
  const int m0 = blockIdx.y * 128, n0 = blockIdx.x * 128;
  const int t = threadIdx.x;
  const int sr = t >> 1, c0 = (t & 1) * 2;
  const int w0 = ((c0) ^ (sr & 3)) * 8, w1 = ((c0 + 1) ^ (sr & 3)) * 8;
  const u16* aH = Ahi + (long long)blockIdx.z * sA + (size_t)(m0 + sr) * K;
  const u16* aL = Alo + (long long)blockIdx.z * sA + (size_t)(m0 + sr) * K;
  const u16* bH = Bhi + (long long)blockIdx.z * sB + (size_t)(n0 + sr) * K;
  const u16* bL = Blo + (long long)blockIdx.z * sB + (size_t)(n0 + sr) * K;
  float* C = Cg + (long long)blockIdx.z * sC;
  const int lane = t & 63, w = t >> 6;
  const int wm = (w >> 1) * 64, wn = (w & 1) * 64;
  const int lr = lane & 15;
  const int kcol = SWZC(lane);

  f32x4 acc[4][4] = {};
  for (int k0 = 0; k0 < K; k0 += 32) {
    __syncthreads();
    *(uint4*)&As[sr][w0] = *(const uint4*)(aH + k0 + c0 * 8);
    *(uint4*)&As[sr][w1] = *(const uint4*)(aH + k0 + c0 * 8 + 8);
    *(uint4*)&Bs[sr][w0] = *(const uint4*)(bH + k0 + c0 * 8);
    *(uint4*)&Bs[sr][w1] = *(const uint4*)(bH + k0 + c0 * 8 + 8);
    if constexpr (PASSES == 3) {
      *(uint4*)&Als[sr][w0] = *(const uint4*)(aL + k0 + c0 * 8);
      *(uint4*)&Als[sr][w1] = *(const uint4*)(aL + k0 + c0 * 8 + 8);
      *(uint4*)&Bls[sr][w0] = *(const uint4*)(bL + k0 + c0 * 8);
      *(uint4*)&Bls[sr][w1] = *(const uint4*)(bL + k0 + c0 * 8 + 8);
    }
    __syncthreads();
    bf16x8 ah[4], bh[4];
#pragma unroll
    for (int i = 0; i < 4; ++i) {
      ah[i] = *(const bf16x8*)&As[wm + i * 16 + lr][kcol];
      bh[i] = *(const bf16x8*)&Bs[wn + i * 16 + lr][kcol];
    }
    if constexpr (PASSES == 3) {
      bf16x8 al[4], bl[4];
#pragma unroll
      for (int i = 0; i < 4; ++i) {
        al[i] = *(const bf16x8*)&Als[wm + i * 16 + lr][kcol];
        bl[i] = *(const bf16x8*)&Bls[wn + i * 16 + lr][kcol];
      }
#pragma unroll
      for (int i = 0; i < 4; ++i)
#pragma unroll
        for (int j = 0; j < 4; ++j) {
          acc[i][j] = __builtin_amdgcn_mfma_f32_16x16x32_bf16(ah[i], bh[j], acc[i][j], 0, 0, 0);
          acc[i][j] = __builtin_amdgcn_mfma_f32_16x16x32_bf16(al[i], bh[j], acc[i][j], 0, 0, 0);
          acc[i][j] = __builtin_amdgcn_mfma_f32_16x16x32_bf16(ah[i], bl[j], acc[i][j], 0, 0, 0);
        }
    } else {
#pragma unroll
      for (int i = 0; i < 4; ++i)
#pragma unroll
        for (int j = 0; j < 4; ++j)
          acc[i][j] = __builtin_amdgcn_mfma_f32_16x16x32_bf16(ah[i], bh[j], acc[i][j], 0, 0, 0);
    }
  }
#pragma unroll
  for (int i = 0; i < 4; ++i) {
#pragma unroll
    for (int j = 0; j < 4; ++j) {
      const int n = n0 + wn + j * 16 + lr;
      const float bv = bias ? bias[n] : 0.f;
#pragma unroll
      for (int r = 0; r < 4; ++r) {
        const int m = m0 + wm + i * 16 + (lane >> 4) * 4 + r;
        C[(size_t)m * N + n] = acc[i][j][r] * alpha + bv;
      }
    }
  }
}

// ------------------------------------------------- MFMA expert GEMM 1
template <int PASSES>
__global__ __launch_bounds__(256) void mfma_moe1(
    const u16* __restrict__ Ahi, const u16* __restrict__ Alo,
    const u16* __restrict__ Bhi, const u16* __restrict__ Blo,
    const float* __restrict__ b1l, const int* __restrict__ list,
    const int* __restrict__ blockExp, const int* __restrict__ blockBase,
    const int* __restrict__ blockValid, int byOff,
    u16* __restrict__ Hhi, u16* __restrict__ Hlo) {
  constexpr int K = DMODEL;
  constexpr int NT = 128 * 40;
  __shared__ u16 lds[(PASSES == 3 ? 4 : 2) * NT];
  u16(*As)[40] = (u16(*)[40])lds;
  u16(*Bs)[40] = (u16(*)[40])(lds + NT);
  u16(*Als)[40] = (u16(*)[40])(lds + 2 * NT);
  u16(*Bls)[40] = (u16(*)[40])(lds + 3 * NT);
  const int by = byOff + blockIdx.y;
  const int e = blockExp[by];
  if (e < 0) return;
  const int row0 = blockBase[by], valid = blockValid[by];
  const int hbase = blockBase[byOff];
  const int n0 = blockIdx.x * 128;
  const int t = threadIdx.x;
  const int sr = t >> 1, c0 = (t & 1) * 2;
  const int w0 = ((c0) ^ (sr & 3)) * 8, w1 = ((c0 + 1) ^ (sr & 3)) * 8;
  const int atok = list[row0 + ((sr < valid) ? sr : 0)];
  const u16* aH = Ahi + (size_t)atok * K;
  const u16* aL = Alo + (size_t)atok * K;
  const u16* bH = Bhi + ((size_t)e * HDIM + n0 + sr) * K;
  const u16* bL = Blo + ((size_t)e * HDIM + n0 + sr) * K;
  const int lane = t & 63, w = t >> 6;
  const int wm = (w >> 1) * 64, wn = (w & 1) * 64;
  const int lr = lane & 15;
  const int kcol = SWZC(lane);

  f32x4 acc[4][4] = {};
  for (int k0 = 0; k0 < K; k0 += 32) {
    __syncthreads();
    *(uint4*)&As[sr][w0] = *(const uint4*)(aH + k0 + c0 * 8);
    *(uint4*)&As[sr][w1] = *(const uint4*)(aH + k0 + c0 * 8 + 8);
    *(uint4*)&Bs[sr][w0] = *(const uint4*)(bH + k0 + c0 * 8);
    *(uint4*)&Bs[sr][w1] = *(const uint4*)(bH + k0 + c0 * 8 + 8);
    if constexpr (PASSES == 3) {
      *(uint4*)&Als[sr][w0] = *(const uint4*)(aL + k0 + c0 * 8);
      *(uint4*)&Als[sr][w1] = *(const uint4*)(aL + k0 + c0 * 8 + 8);
      *(uint4*)&Bls[sr][w0] = *(const uint4*)(bL + k0 + c0 * 8);
      *(uint4*)&Bls[sr][w1] = *(const uint4*)(bL + k0 + c0 * 8 + 8);
    }
    __syncthreads();
    bf16x8 ah[4], bh[4];
#pragma unroll
    for (int i = 0; i < 4; ++i) {
      ah[i] = *(const bf16x8*)&As[wm + i * 16 + lr][kcol];
      bh[i] = *(const bf16x8*)&Bs[wn + i * 16 + lr][kcol];
    }
    if constexpr (PASSES == 3) {
      bf16x8 al[4], bl[4];
#pragma unroll
      for (int i = 0; i < 4; ++i) {
        al[i] = *(const bf16x8*)&Als[wm + i * 16 + lr][kcol];
        bl[i] = *(const bf16x8*)&Bls[wn + i * 16 + lr][kcol];
      }
#pragma unroll
      for (int i = 0; i < 4; ++i)
#pragma unroll
        for (int j = 0; j < 4; ++j) {
          acc[i][j] = __builtin_amdgcn_mfma_f32_16x16x32_bf16(ah[i], bh[j], acc[i][j], 0, 0, 0);
          acc[i][j] = __builtin_amdgcn_mfma_f32_16x16x32_bf16(al[i], bh[j], acc[i][j], 0, 0, 0);
          acc[i][j] = __builtin_amdgcn_mfma_f32_16x16x32_bf16(ah[i], bl[j], acc[i][j], 0, 0, 0);
        }
    } else {
#pragma unroll
      for (int i = 0; i < 4; ++i)
#pragma unroll
        for (int j = 0; j < 4; ++j)
          acc[i][j] = __builtin_amdgcn_mfma_f32_16x16x32_bf16(ah[i], bh[j], acc[i][j], 0, 0, 0);
    }
  }
#pragma unroll
  for (int i = 0; i < 4; ++i) {
#pragma unroll
    for (int j = 0; j < 4; ++j) {
      const int n = n0 + wn + j * 16 + lr;
      const float bv = b1l[(size_t)e * HDIM + n];
#pragma unroll
      for (int r = 0; r < 4; ++r) {
        const int m = wm + i * 16 + (lane >> 4) * 4 + r;
        if (m < valid) {
          const float h = fmaxf(acc[i][j][r] + bv, 0.f);
          const u16 hh = f2bf(h);
          const size_t idx = (size_t)(row0 + m - hbase) * HDIM + n;
          Hhi[idx] = hh;
          if constexpr (PASSES == 3) Hlo[idx] = f2bf(h - bf2f(hh));
        }
      }
    }
  }
}

// ------------------------------------------------- MFMA expert GEMM 2
template <int PASSES>
__global__ __launch_bounds__(256) void mfma_moe2(
    const u16* __restrict__ Hhi, const u16* __restrict__ Hlo,
    const u16* __restrict__ Bhi, const u16* __restrict__ Blo,
    const float* __restrict__ b2l, const int* __restrict__ list,
    const int* __restrict__ blockExp, const int* __restrict__ blockBase,
    const int* __restrict__ blockValid, int byOff,
    const float* __restrict__ rowGate, float* __restrict__ moe) {
  constexpr int K = HDIM;
  constexpr int NT = 128 * 40;
  __shared__ u16 lds[(PASSES == 3 ? 4 : 2) * NT];
  u16(*As)[40] = (u16(*)[40])lds;
  u16(*Bs)[40] = (u16(*)[40])(lds + NT);
  u16(*Als)[40] = (u16(*)[40])(lds + 2 * NT);
  u16(*Bls)[40] = (u16(*)[40])(lds + 3 * NT);
  const int by = byOff + blockIdx.y;
  const int e = blockExp[by];
  if (e < 0) return;
  const int row0 = blockBase[by], valid = blockValid[by];
  const int hbase = blockBase[byOff];
  const int n0 = blockIdx.x * 128;
  const int t = threadIdx.x;
  const int sr = t >> 1, c0 = (t & 1) * 2;
  const int w0 = ((c0) ^ (sr & 3)) * 8, w1 = ((c0 + 1) ^ (sr & 3)) * 8;
  const u16* aH = Hhi + (size_t)(row0 + sr - hbase) * K;
  const u16* aL = Hlo + (size_t)(row0 + sr - hbase) * K;
  const u16* bH = Bhi + ((size_t)e * DMODEL + n0 + sr) * K;
  const u16* bL = Blo + ((size_t)e * DMODEL + n0 + sr) * K;
  const int lane = t & 63, w = t >> 6;
  const int wm = (w >> 1) * 64, wn = (w & 1) * 64;
  const int lr = lane & 15;
  const int kcol = SWZC(lane);

  f32x4 acc[4][4] = {};
  for (int k0 = 0; k0 < K; k0 += 32) {
    __syncthreads();
    *(uint4*)&As[sr][w0] = *(const uint4*)(aH + k0 + c0 * 8);
    *(uint4*)&As[sr][w1] = *(const uint4*)(aH + k0 + c0 * 8 + 8);
    *(uint4*)&Bs[sr][w0] = *(const uint4*)(bH + k0 + c0 * 8);
    *(uint4*)&Bs[sr][w1] = *(const uint4*)(bH + k0 + c0 * 8 + 8);
    if constexpr (PASSES == 3) {
      *(uint4*)&Als[sr][w0] = *(const uint4*)(aL + k0 + c0 * 8);
      *(uint4*)&Als[sr][w1] = *(const uint4*)(aL + k0 + c0 * 8 + 8);
      *(uint4*)&Bls[sr][w0] = *(const uint4*)(bL + k0 + c0 * 8);
      *(uint4*)&Bls[sr][w1] = *(const uint4*)(bL + k0 + c0 * 8 + 8);
    }
    __syncthreads();
    bf16x8 ah[4], bh[4];
#pragma unroll
    for (int i = 0; i < 4; ++i) {
      ah[i] = *(const bf16x8*)&As[wm + i * 16 + lr][kcol];
      bh[i] = *(const bf16x8*)&Bs[wn + i * 16 + lr][kcol];
    }
    if constexpr (PASSES == 3) {
      bf16x8 al[4], bl[4];
#pragma unroll
      for (int i = 0; i < 4; ++i) {
        al[i] = *(const bf16x8*)&Als[wm + i * 16 + lr][kcol];
        bl[i] = *(const bf16x8*)&Bls[wn + i * 16 + lr][kcol];
      }
#pragma unroll
      for (int i = 0; i < 4; ++i)
#pragma unroll
        for (int j = 0; j < 4; ++j) {
          acc[i][j] = __builtin_amdgcn_mfma_f32_16x16x32_bf16(ah[i], bh[j], acc[i][j], 0, 0, 0);
          acc[i][j] = __builtin_amdgcn_mfma_f32_16x16x32_bf16(al[i], bh[j], acc[i][j], 0, 0, 0);
          acc[i][j] = __builtin_amdgcn_mfma_f32_16x16x32_bf16(ah[i], bl[j], acc[i][j], 0, 0, 0);
        }
    } else {
#pragma unroll
      for (int i = 0; i < 4; ++i)
#pragma unroll
        for (int j = 0; j < 4; ++j)
          acc[i][j] = __builtin_amdgcn_mfma_f32_16x16x32_bf16(ah[i], bh[j], acc[i][j], 0, 0, 0);
    }
  }
#pragma unroll
  for (int i = 0; i < 4; ++i) {
#pragma unroll
    for (int r = 0; r < 4; ++r) {
      const int m = wm + i * 16 + (lane >> 4) * 4 + r;
      if (m >= valid) continue;
      const int tok = list[row0 + m];
      const float g = rowGate[row0 + m];
      float* orow = moe + (size_t)tok * DMODEL;
#pragma unroll
      for (int j = 0; j < 4; ++j) {
        const int n = n0 + wn + j * 16 + lr;
        atomicAdd(orow + n, (acc[i][j][r] + b2l[(size_t)e * DMODEL + n]) * g);
      }
    }
  }
}

// ---------------------------------------------------------------- RoPE
__global__ __launch_bounds__(256) void rope_rot(
    float* __restrict__ q, float* __restrict__ k,
    const float* __restrict__ nc, const float* __restrict__ wr) {
  const int tok = blockIdx.x, j = threadIdx.x;
  const float c0 = nc[tok * 2 + 0], c1 = nc[tok * 2 + 1];
  const float f = c0 * wr[j] + c1 * wr[256 + j];
  const float cf = cosf(f), sf = sinf(f);
  float2* q2 = (float2*)(q + (long long)tok * DMODEL);
  float2* k2 = (float2*)(k + (long long)tok * DMODEL);
  const float2 qq = q2[j];
  const float2 kk = k2[j];
  q2[j] = make_float2(qq.x * cf - qq.y * sf, qq.x * sf + qq.y * cf);
  k2[j] = make_float2(kk.x * cf - kk.y * sf, kk.x * sf + kk.y * cf);
}

// ---------------------------------------------------------------- softmax
__global__ __launch_bounds__(256) void attn_softmax(
    float* __restrict__ S, const unsigned char* __restrict__ pad) {
  const int q = blockIdx.x & (LSEQ - 1);
  const int b = blockIdx.x >> 10;
  float* row = S + (long long)blockIdx.x * LSEQ;
  const int t = threadIdx.x;
  const float4 v = ((const float4*)row)[t];
  float vals[4] = {v.x, v.y, v.z, v.w};
  const int k0 = t * 4;
#pragma unroll
  for (int j = 0; j < 4; ++j) {
    const int k = k0 + j;
    if (k > q || pad[b * LSEQ + k]) vals[j] = -INFINITY;
  }
  __shared__ float red[4];
  const int wid = t >> 6, lane = t & 63;
  float m = waveAllMax(fmaxf(fmaxf(vals[0], vals[1]), fmaxf(vals[2], vals[3])));
  if (lane == 0) red[wid] = m;
  __syncthreads();
  m = fmaxf(fmaxf(red[0], red[1]), fmaxf(red[2], red[3]));
  const float e0 = expf(vals[0] - m), e1 = expf(vals[1] - m);
  const float e2 = expf(vals[2] - m), e3 = expf(vals[3] - m);
  const float ps = waveAllSum(e0 + e1 + e2 + e3);
  __syncthreads();
  if (lane == 0) red[wid] = ps;
  __syncthreads();
  const float tot = red[0] + red[1] + red[2] + red[3];
  float4 o;
  o.x = e0 / tot; o.y = e1 / tot; o.z = e2 / tot; o.w = e3 / tot;
  ((float4*)row)[t] = o;
}

// ---------------------------------------------------------------- add + LN
__global__ __launch_bounds__(128) void ln_add(
    const float* __restrict__ Aa, const float* __restrict__ Bb,
    const float* __restrict__ gg, const float* __restrict__ bb,
    float* __restrict__ out) {
  const int row = blockIdx.x, t = threadIdx.x;
  const float4 va = ((const float4*)(Aa + (long long)row * DMODEL))[t];
  const float4 vb = ((const float4*)(Bb + (long long)row * DMODEL))[t];
  const float x0 = va.x + vb.x, x1 = va.y + vb.y;
  const float x2 = va.z + vb.z, x3 = va.w + vb.w;
  __shared__ float r1[2], r2[2];
  const int wid = t >> 6, lane = t & 63;
  const float s = waveAllSum(x0 + x1 + x2 + x3);
  if (lane == 0) r1[wid] = s;
  __syncthreads();
  const float mean = (r1[0] + r1[1]) * (1.0f / DMODEL);
  const float d0 = x0 - mean, d1 = x1 - mean, d2 = x2 - mean, d3 = x3 - mean;
  const float vs = waveAllSum(d0 * d0 + d1 * d1 + d2 * d2 + d3 * d3);
  if (lane == 0) r2[wid] = vs;
  __syncthreads();
  const float var = (r2[0] + r2[1]) * (1.0f / DMODEL);
  const float rs = rsqrtf(var + 1e-5f);
  const float4 g4 = ((const float4*)gg)[t];
  const float4 b4 = ((const float4*)bb)[t];
  float4 o;
  o.x = d0 * rs * g4.x + b4.x;
  o.y = d1 * rs * g4.y + b4.y;
  o.z = d2 * rs * g4.z + b4.z;
  o.w = d3 * rs * g4.w + b4.w;
  ((float4*)(out + (long long)row * DMODEL))[t] = o;
}

// ------------------------------------------------- router v2 (LDS-staged W)
// block = 256 thr = 16 tokens x 16 outputs; W [16][524] padded: float4 reads
// land 2-way bank aliased (free, m136). Old version: 204 us (latency-bound
// scalar W loads); this does the K=512 dot with float4 from L1 + LDS.
__global__ __launch_bounds__(256) void router_topk2(
    const float* __restrict__ x, const float* __restrict__ rtw,
    const float* __restrict__ rtb, const float* __restrict__ nzw,
    const float* __restrict__ nzb, float* __restrict__ gate,
    int* __restrict__ counts, unsigned char* __restrict__ selmask, int layer) {
  __shared__ float Wl[16][524];
  __shared__ float noisyS[16][8];
  const int t = threadIdx.x;
  for (int i = t; i < DMODEL * NEXP; i += 256) {
    const int d = i >> 3, e = i & 7;
    Wl[e][d] = rtw[i];
    Wl[8 + e][d] = nzw[i];
  }
  __syncthreads();
  const int tt = t >> 4, o = t & 15;
  const int tok = blockIdx.x * 16 + tt;
  const float4* x4 = (const float4*)(x + (size_t)tok * DMODEL);
  float s = 0.f;
#pragma unroll 4
  for (int dd = 0; dd < DMODEL / 4; ++dd) {
    const float4 xv = x4[dd];
    const float4 wv = *(const float4*)&Wl[o][dd * 4];
    s = fmaf(xv.x, wv.x, s);
    s = fmaf(xv.y, wv.y, s);
    s = fmaf(xv.z, wv.z, s);
    s = fmaf(xv.w, wv.w, s);
  }
  const float other = __shfl_xor(s, 8, 64);  // pair logit<->noise lanes
  if (o < 8) {
    const float logit = s + rtb[o];
    const float nl = other + nzb[o];
    const float eps = eps_normal((unsigned)(tok * NEXP + o), (unsigned)layer);
    const float sp = fmaxf(nl, 0.f) + log1pf(expf(-fabsf(nl)));  // logaddexp(x,0)
    noisyS[tt][o] = logit + eps * sp;
  }
  __syncthreads();
  if (t < 16) {
    const int tk = blockIdx.x * 16 + t;
    float v[8]; bool sel[8];
#pragma unroll
    for (int i = 0; i < 8; ++i) { v[i] = noisyS[t][i]; sel[i] = false; }
    for (int r = 0; r < TOPK; ++r) {  // strict '>' => lowest index wins ties
      int bi = 0; float best = -INFINITY;
      for (int i = 0; i < 8; ++i)
        if (!sel[i] && v[i] > best) { best = v[i]; bi = i; }
      sel[bi] = true;
    }
    float m = -INFINITY;
    for (int i = 0; i < 8; ++i) if (sel[i]) m = fmaxf(m, v[i]);
    float ex[8]; float den = 0.f;
    unsigned char mbits = 0;
    for (int i = 0; i < 8; ++i) {
      ex[i] = sel[i] ? expf(v[i] - m) : 0.f;
      den += ex[i];
      if (sel[i]) { mbits |= (unsigned char)(1u << i); atomicAdd(&counts[i], 1); }
    }
    for (int i = 0; i < 8; ++i) gate[tk * NEXP + i] = ex[i] / den;
    selmask[tk] = mbits;
  }
}

// ------------------------------------------------- dispatch plan/build/zero
__global__ void moe_plan(const int* __restrict__ counts, int* __restrict__ start,
                         int* __restrict__ blockExp, int* __restrict__ blockBase,
                         int* __restrict__ blockValid) {
  if (threadIdx.x != 0) return;
  int s = 0, by = 0;
  for (int e = 0; e < NEXP; ++e) {
    start[e] = s;
    const int c = counts[e];
    const int nb = (c + 127) >> 7;
    for (int b = 0; b < nb; ++b) {
      blockExp[by] = e;
      blockBase[by] = s + b * 128;
      blockValid[by] = min(128, c - b * 128);
      ++by;
    }
    s += nb * 128;
  }
  for (; by < NBLK; ++by) { blockExp[by] = -1; blockBase[by] = s; blockValid[by] = 0; }
}

__global__ __launch_bounds__(256) void moe_build(
    const unsigned char* __restrict__ selmask, const int* __restrict__ start,
    int* __restrict__ cursor, int* __restrict__ list,
    const float* __restrict__ gate, float* __restrict__ rowGate) {
  const int tok = blockIdx.x * 256 + threadIdx.x;
  if (tok >= TOK) return;
  unsigned m = selmask[tok];
  while (m) {
    const int e = __ffs(m) - 1;
    m &= m - 1;
    const int slot = atomicAdd(&cursor[e], 1);
    list[start[e] + slot] = tok;
    rowGate[start[e] + slot] = gate[tok * NEXP + e];
  }
}

__global__ __launch_bounds__(256) void zero_f32(float* __restrict__ p, int n4) {
  const int i = blockIdx.x * 256 + threadIdx.x;
  if (i < n4) ((float4*)p)[i] = make_float4(0.f, 0.f, 0.f, 0.f);
}
__global__ void zero_i32(int* __restrict__ p, int n) {
  const int i = threadIdx.x;
  if (i < n) p[i] = 0;
}

// ---------------------------------------------------------------- launch
extern "C" void kernel_launch(void* const* d_in, const int* in_sizes, int n_in,
                              void* d_out, int out_size, void* d_ws,
                              size_t ws_size, hipStream_t stream) {
  const float* x_in = (const float*)d_in[0];
  const float* nc = (const float*)d_in[1];
  const unsigned char* pad = (const unsigned char*)d_in[3];
  const float* wq = (const float*)d_in[4];
  const float* bq = (const float*)d_in[5];
  const float* wk = (const float*)d_in[6];
  const float* bk = (const float*)d_in[7];
  const float* wv = (const float*)d_in[8];
  const float* bv = (const float*)d_in[9];
  const float* wr = (const float*)d_in[10];
  const float* ln1g = (const float*)d_in[11];
  const float* ln1b = (const float*)d_in[12];
  const float* rtw = (const float*)d_in[13];
  const float* rtb = (const float*)d_in[14];
  const float* nzw = (const float*)d_in[15];
  const float* nzb = (const float*)d_in[16];
  const float* ew1 = (const float*)d_in[17];
  const float* eb1 = (const float*)d_in[18];
  const float* ew2 = (const float*)d_in[19];
  const float* eb2 = (const float*)d_in[20];
  const float* ln2g = (const float*)d_in[21];
  const float* ln2b = (const float*)d_in[22];

  float* ws = (float*)d_ws;
  const long long SZ = (long long)TOK * DMODEL;  // 2,097,152
  float* qb = ws;                        // also attn output
  float* kb = ws + SZ;
  float* vb2 = ws + 2 * SZ;
  float* xcur = ws + 3 * SZ;
  float* moe = ws + 4 * SZ;
  float* gate = ws + 5 * SZ;
  int* meta = (int*)(ws + 10518528);
  int* counts = meta;
  int* cursor = meta + 8;
  int* startE = meta + 16;
  int* blockExp = meta + 24;
  int* blockBase = meta + 160;
  int* blockValid = meta + 296;
  int* list = meta + 432;
  unsigned char* selmask = (unsigned char*)(meta + 17840);
  float* rowGate = ws + 10537408;
  u16* Xhi = (u16*)(ws + 10554816);      // expert split of xcur
  u16* Xlo = (u16*)(ws + 11603392);

  // ---- attention region (aliases expert W1T/W2T/H region; disjoint lifetime)
  float* scores = ws + 12651968;         // 4,194,304 f32
  u16* ub = (u16*)(ws + 16846272);
  u16* XAhi = ub;                        // 2,097,152 each
  u16* XAlo = ub + 2097152;
  u16* Qhi = ub + 4194304;
  u16* Qlo = ub + 6291456;
  u16* Khi = ub + 8388608;
  u16* Klo = ub + 10485760;
  u16* Phi = ub + 12582912;              // 4,194,304 each
  u16* Plo = ub + 16777216;
  u16* VThi = ub + 20971520;             // 2,097,152 each
  u16* VTlo = ub + 23068672;
  u16* WqThi = ub + 25165824;            // 262,144 each
  u16* WqTlo = ub + 25427968;
  u16* WkThi = ub + 25690112;
  u16* WkTlo = ub + 25952256;
  u16* WvThi = ub + 26214400;
  u16* WvTlo = ub + 26476544;            // region ends 30,215,616 floats

  // ---- expert region (written after attention each layer)
  u16* W1Thi = (u16*)(ws + 12651968);
  u16* W1Tlo = (u16*)(ws + 16846272);
  u16* W2Thi = (u16*)(ws + 21040576);
  u16* W2Tlo = (u16*)(ws + 25234880);
  u16* Hhi = (u16*)(ws + 29429184);
  u16* Hlo = (u16*)(ws + 38342080);      // high-water 47,254,976 f = 189 MB

  const float iscale = 1.0f / sqrtf((float)DMODEL);
  const dim3 blk(256);
  const long long sQ = (long long)LSEQ * DMODEL;   // per-batch q/k/v stride
  const long long sS = (long long)LSEQ * LSEQ;     // per-batch scores stride

  for (int l = 0; l < NLAYER; ++l) {
    const float* xl = (l == 0) ? x_in : xcur;
    const long long wOff = (long long)l * DMODEL * DMODEL;

    // ---- QKV via split-bf16 MFMA
    split_f32_bf16<<<2048, blk, 0, stream>>>(xl, XAhi, XAlo, (int)SZ);
    transpose_split<<<dim3(16, 16, 1), blk, 0, stream>>>(wq + wOff, WqThi, WqTlo, DMODEL, DMODEL);
    transpose_split<<<dim3(16, 16, 1), blk, 0, stream>>>(wk + wOff, WkThi, WkTlo, DMODEL, DMODEL);
    transpose_split<<<dim3(16, 16, 1), blk, 0, stream>>>(wv + wOff, WvThi, WvTlo, DMODEL, DMODEL);
    mfma_gemm3<3><<<dim3(4, 32, 1), blk, 0, stream>>>(
        XAhi, XAlo, WqThi, WqTlo, bq + l * DMODEL, qb, DMODEL, DMODEL, 1.f, 0, 0, 0);
    mfma_gemm3<3><<<dim3(4, 32, 1), blk, 0, stream>>>(
        XAhi, XAlo, WkThi, WkTlo, bk + l * DMODEL, kb, DMODEL, DMODEL, 1.f, 0, 0, 0);
    mfma_gemm3<3><<<dim3(4, 32, 1), blk, 0, stream>>>(
        XAhi, XAlo, WvThi, WvTlo, bv + l * DMODEL, vb2, DMODEL, DMODEL, 1.f, 0, 0, 0);

    rope_rot<<<TOK, 256, 0, stream>>>(qb, kb, nc, wr + (long long)l * DMODEL);

    // ---- scores = (q @ k^T) * iscale via split-bf16 MFMA
    split_f32_bf16<<<2048, blk, 0, stream>>>(qb, Qhi, Qlo, (int)SZ);
    split_f32_bf16<<<2048, blk, 0, stream>>>(kb, Khi, Klo, (int)SZ);
    mfma_gemm3<3><<<dim3(8, 8, BATCH), blk, 0, stream>>>(
        Qhi, Qlo, Khi, Klo, nullptr, scores, LSEQ, DMODEL, iscale, sQ, sQ, sS);

    attn_softmax<<<BATCH * LSEQ, 256, 0, stream>>>(scores, pad);

    // ---- attn @ v via split-bf16 MFMA (v transposed to [D][L] per batch)
    split_f32_bf16<<<4096, blk, 0, stream>>>(scores, Phi, Plo, (int)(4 * sS / 4 * 4));
    transpose_split<<<dim3(16, 32, BATCH), blk, 0, stream>>>(vb2, VThi, VTlo, LSEQ, DMODEL);
    mfma_gemm3<3><<<dim3(4, 8, BATCH), blk, 0, stream>>>(
        Phi, Plo, VThi, VTlo, nullptr, qb, DMODEL, LSEQ, 1.f, sS, sQ, sQ);

    ln_add<<<TOK, 128, 0, stream>>>(xl, qb, ln1g + l * DMODEL, ln1b + l * DMODEL, xcur);

    // ---- router + dispatch
    zero_i32<<<1, 64, 0, stream>>>(counts, 16);
    router_topk2<<<TOK / 16, blk, 0, stream>>>(
        xcur, rtw + l * DMODEL * NEXP, rtb + l * NEXP, nzw + l * DMODEL * NEXP,
        nzb + l * NEXP, gate, counts, selmask, l);
    moe_plan<<<1, 64, 0, stream>>>(counts, startE, blockExp, blockBase, blockValid);
    moe_build<<<TOK / 256, 256, 0, stream>>>(selmask, startE, cursor, list, gate, rowGate);
    zero_f32<<<(int)(SZ / 4 / 256), 256, 0, stream>>>(moe, (int)(SZ / 4));

    // ---- experts (3-pass split-bf16, grouped, chunked H)
    split_f32_bf16<<<2048, blk, 0, stream>>>(xcur, Xhi, Xlo, (int)SZ);
    transpose_split<<<dim3(64, 16, 8), blk, 0, stream>>>(
        ew1 + (long long)l * NEXP * DMODEL * HDIM, W1Thi, W1Tlo, DMODEL, HDIM);
    transpose_split<<<dim3(16, 64, 8), blk, 0, stream>>>(
        ew2 + (long long)l * NEXP * HDIM * DMODEL, W2Thi, W2Tlo, HDIM, DMODEL);

    const float* b1l = eb1 + (long long)l * NEXP * HDIM;
    const float* b2l = eb2 + (long long)l * NEXP * DMODEL;
    for (int ch = 0; ch < 2; ++ch) {
      const int byOff = ch * CHBLK;
      mfma_moe1<3><<<dim3(HDIM / 128, CHBLK), blk, 0, stream>>>(
          Xhi, Xlo, W1Thi, W1Tlo, b1l, list, blockExp, blockBase, blockValid,
          byOff, Hhi, Hlo);
      mfma_moe2<3><<<dim3(DMODEL / 128, CHBLK), blk, 0, stream>>>(
          Hhi, Hlo, W2Thi, W2Tlo, b2l, list, blockExp, blockBase, blockValid,
          byOff, rowGate, moe);
    }

    float* outp = (l == NLAYER - 1) ? (float*)d_out : xcur;
    ln_add<<<TOK, 128, 0, stream>>>(xcur, moe, ln2g + l * DMODEL, ln2b + l * DMODEL, outp);
  }
}

// Round 9
// 1708.187 us; speedup vs baseline: 2.0525x; 1.0854x over previous
//
#include <hip/hip_runtime.h>
#include <math.h>

#define TOK 4096      // B*L
#define DMODEL 512
#define LSEQ 1024
#define BATCH 4
#define NLAYER 2
#define NEXP 8
#define TOPK 4
#define HDIM 2048
#define NBLK 136
#define CHBLK 68
#define KSPLIT2 4     // K-split factor for moe2 (K=2048 -> 4x512)

typedef unsigned short u16;
typedef __attribute__((ext_vector_type(8))) short bf16x8;
typedef __attribute__((ext_vector_type(4))) float f32x4;

// ---------------------------------------------------------------- bf16 split
__device__ __forceinline__ u16 f2bf(float x) {
  const unsigned u = __float_as_uint(x);
  return (u16)((u + 0x7FFFu + ((u >> 16) & 1u)) >> 16);
}
__device__ __forceinline__ float bf2f(u16 h) {
  return __uint_as_float(((unsigned)h) << 16);
}

// ---------------------------------------------------------------- reductions
__device__ __forceinline__ float waveAllSum(float v) {
#pragma unroll
  for (int off = 1; off < 64; off <<= 1) v += __shfl_xor(v, off, 64);
  return v;
}
__device__ __forceinline__ float waveAllMax(float v) {
#pragma unroll
  for (int off = 1; off < 64; off <<= 1) v = fmaxf(v, __shfl_xor(v, off, 64));
  return v;
}

// ---------------------------------------------------------------- threefry
__device__ __forceinline__ unsigned rotl32(unsigned x, int r) {
  return (x << r) | (x >> (32 - r));
}
__device__ __forceinline__ void tf2x32(unsigned k0, unsigned k1,
                                       unsigned& x0, unsigned& x1) {
  const unsigned ks0 = k0, ks1 = k1, ks2 = k0 ^ k1 ^ 0x1BD11BDAu;
  x0 += ks0; x1 += ks1;
#define TF_R4(a, b, c, d)                                   \
  x0 += x1; x1 = rotl32(x1, a); x1 ^= x0;                   \
  x0 += x1; x1 = rotl32(x1, b); x1 ^= x0;                   \
  x0 += x1; x1 = rotl32(x1, c); x1 ^= x0;                   \
  x0 += x1; x1 = rotl32(x1, d); x1 ^= x0;
  TF_R4(13, 15, 26, 6)  x0 += ks1; x1 += ks2 + 1u;
  TF_R4(17, 29, 16, 24) x0 += ks2; x1 += ks0 + 2u;
  TF_R4(13, 15, 26, 6)  x0 += ks0; x1 += ks1 + 3u;
  TF_R4(17, 29, 16, 24) x0 += ks1; x1 += ks2 + 4u;
  TF_R4(13, 15, 26, 6)  x0 += ks2; x1 += ks0 + 5u;
#undef TF_R4
}

__device__ __forceinline__ float xla_erfinv(float u) {
  float w = -log1pf(-__fmul_rn(u, u));
  float p;
  if (w < 5.0f) {
    w = __fadd_rn(w, -2.5f);
    p = 2.81022636e-08f;
    p = __fadd_rn(3.43273939e-07f, __fmul_rn(p, w));
    p = __fadd_rn(-3.5233877e-06f, __fmul_rn(p, w));
    p = __fadd_rn(-4.39150654e-06f, __fmul_rn(p, w));
    p = __fadd_rn(0.00021858087f, __fmul_rn(p, w));
    p = __fadd_rn(-0.00125372503f, __fmul_rn(p, w));
    p = __fadd_rn(-0.00417768164f, __fmul_rn(p, w));
    p = __fadd_rn(0.246640727f, __fmul_rn(p, w));
    p = __fadd_rn(1.50140941f, __fmul_rn(p, w));
  } else {
    w = __fadd_rn(sqrtf(w), -3.0f);
    p = -0.000200214257f;
    p = __fadd_rn(0.000100950558f, __fmul_rn(p, w));
    p = __fadd_rn(0.00134934322f, __fmul_rn(p, w));
    p = __fadd_rn(-0.00367342844f, __fmul_rn(p, w));
    p = __fadd_rn(0.00573950773f, __fmul_rn(p, w));
    p = __fadd_rn(-0.0076224613f, __fmul_rn(p, w));
    p = __fadd_rn(0.00943887047f, __fmul_rn(p, w));
    p = __fadd_rn(1.00167406f, __fmul_rn(p, w));
    p = __fadd_rn(2.83297682f, __fmul_rn(p, w));
  }
  return __fmul_rn(p, u);
}

__device__ __forceinline__ float bits_to_normal(unsigned bits) {
  const unsigned fb = (bits >> 9) | 0x3f800000u;
  const float u01 = __fadd_rn(__uint_as_float(fb), -1.0f);
  const float lo = -0.99999994f;
  float u = __fadd_rn(__fmul_rn(u01, 2.0f), lo);
  u = fmaxf(u, lo);
  return __fmul_rn(1.41421356237309515f, xla_erfinv(u));
}

__device__ __forceinline__ float eps_normal(unsigned i, unsigned layer) {
  unsigned f0 = 0u, f1 = layer;
  tf2x32(0u, 42u, f0, f1);
  unsigned x0 = 0u, x1 = i;
  tf2x32(f0, f1, x0, x1);
  return bits_to_normal(x0 ^ x1);
}

// ------------------------------------------------- split / transpose-split
__global__ __launch_bounds__(256) void split_f32_bf16(
    const float* __restrict__ in, u16* __restrict__ hi, u16* __restrict__ lo,
    int n) {
  const int i = (blockIdx.x * 256 + threadIdx.x) * 4;
  if (i >= n) return;
  const float4 v = *(const float4*)(in + i);
  ushort4 h, l;
  h.x = f2bf(v.x); l.x = f2bf(v.x - bf2f(h.x));
  h.y = f2bf(v.y); l.y = f2bf(v.y - bf2f(h.y));
  h.z = f2bf(v.z); l.z = f2bf(v.z - bf2f(h.z));
  h.w = f2bf(v.w); l.w = f2bf(v.w - bf2f(h.w));
  *(ushort4*)(hi + i) = h;
  *(ushort4*)(lo + i) = l;
}

// in [Z][R][C] f32 -> hi/lo [Z][C][R] bf16
__global__ __launch_bounds__(256) void transpose_split(
    const float* __restrict__ in, u16* __restrict__ hi, u16* __restrict__ lo,
    int R, int C) {
  __shared__ float tile[32][33];
  const size_t eoff = (size_t)blockIdx.z * R * C;
  const float* src = in + eoff;
  const int r0 = blockIdx.y * 32, c0 = blockIdx.x * 32;
  const int tx = threadIdx.x & 31, ty = threadIdx.x >> 5;
#pragma unroll
  for (int j = 0; j < 4; ++j)
    tile[ty + 8 * j][tx] = src[(size_t)(r0 + ty + 8 * j) * C + c0 + tx];
  __syncthreads();
  u16* dh = hi + eoff;
  u16* dl = lo + eoff;
#pragma unroll
  for (int j = 0; j < 4; ++j) {
    const float v = tile[tx][ty + 8 * j];
    const u16 h = f2bf(v);
    const size_t idx = (size_t)(c0 + ty + 8 * j) * R + r0 + tx;
    dh[idx] = h;
    dl[idx] = f2bf(v - bf2f(h));
  }
}

#define SWZC(lane) ((((lane) >> 4) ^ ((lane) & 3)) * 8)

// ------------------------------------------------- generic 3-pass MFMA GEMM
template <int PASSES>
__global__ __launch_bounds__(256) void mfma_gemm3(
    const u16* __restrict__ Ahi, const u16* __restrict__ Alo,
    const u16* __restrict__ Bhi, const u16* __restrict__ Blo,
    const float* __restrict__ bias, float* __restrict__ Cg,
    int N, int K, float alpha,
    long long sA, long long sB, long long sC) {
  constexpr int NT = 128 * 40;
  __shared__ u16 lds[(PASSES == 3 ? 4 : 2) * NT];
  u16(*As)[40] = (u16(*)[40])lds;
  u16(*Bs)[40] = (u16(*)[40])(lds + NT);
  u16(*Als)[40] = (u16(*)[40])(lds + 2 * NT);
  u16(*Bls)[40] = (u16(*)[40])(lds + 3 * NT);
  const int m0 = blockIdx.y * 128, n0 = blockIdx.x * 128;
  const int t = threadIdx.x;
  const int sr = t >> 1, c0 = (t & 1) * 2;
  const int w0 = ((c0) ^ (sr & 3)) * 8, w1 = ((c0 + 1) ^ (sr & 3)) * 8;
  const u16* aH = Ahi + (long long)blockIdx.z * sA + (size_t)(m0 + sr) * K;
  const u16* aL = Alo + (long long)blockIdx.z * sA + (size_t)(m0 + sr) * K;
  const u16* bH = Bhi + (long long)blockIdx.z * sB + (size_t)(n0 + sr) * K;
  const u16* bL = Blo + (long long)blockIdx.z * sB + (size_t)(n0 + sr) * K;
  float* C = Cg + (long long)blockIdx.z * sC;
  const int lane = t & 63, w = t >> 6;
  const int wm = (w >> 1) * 64, wn = (w & 1) * 64;
  const int lr = lane & 15;
  const int kcol = SWZC(lane);

  f32x4 acc[4][4] = {};
  for (int k0 = 0; k0 < K; k0 += 32) {
    __syncthreads();
    *(uint4*)&As[sr][w0] = *(const uint4*)(aH + k0 + c0 * 8);
    *(uint4*)&As[sr][w1] = *(const uint4*)(aH + k0 + c0 * 8 + 8);
    *(uint4*)&Bs[sr][w0] = *(const uint4*)(bH + k0 + c0 * 8);
    *(uint4*)&Bs[sr][w1] = *(const uint4*)(bH + k0 + c0 * 8 + 8);
    if constexpr (PASSES == 3) {
      *(uint4*)&Als[sr][w0] = *(const uint4*)(aL + k0 + c0 * 8);
      *(uint4*)&Als[sr][w1] = *(const uint4*)(aL + k0 + c0 * 8 + 8);
      *(uint4*)&Bls[sr][w0] = *(const uint4*)(bL + k0 + c0 * 8);
      *(uint4*)&Bls[sr][w1] = *(const uint4*)(bL + k0 + c0 * 8 + 8);
    }
    __syncthreads();
    bf16x8 ah[4], bh[4];
#pragma unroll
    for (int i = 0; i < 4; ++i) {
      ah[i] = *(const bf16x8*)&As[wm + i * 16 + lr][kcol];
      bh[i] = *(const bf16x8*)&Bs[wn + i * 16 + lr][kcol];
    }
    if constexpr (PASSES == 3) {
      bf16x8 al[4], bl[4];
#pragma unroll
      for (int i = 0; i < 4; ++i) {
        al[i] = *(const bf16x8*)&Als[wm + i * 16 + lr][kcol];
        bl[i] = *(const bf16x8*)&Bls[wn + i * 16 + lr][kcol];
      }
#pragma unroll
      for (int i = 0; i < 4; ++i)
#pragma unroll
        for (int j = 0; j < 4; ++j) {
          acc[i][j] = __builtin_amdgcn_mfma_f32_16x16x32_bf16(ah[i], bh[j], acc[i][j], 0, 0, 0);
          acc[i][j] = __builtin_amdgcn_mfma_f32_16x16x32_bf16(al[i], bh[j], acc[i][j], 0, 0, 0);
          acc[i][j] = __builtin_amdgcn_mfma_f32_16x16x32_bf16(ah[i], bl[j], acc[i][j], 0, 0, 0);
        }
    } else {
#pragma unroll
      for (int i = 0; i < 4; ++i)
#pragma unroll
        for (int j = 0; j < 4; ++j)
          acc[i][j] = __builtin_amdgcn_mfma_f32_16x16x32_bf16(ah[i], bh[j], acc[i][j], 0, 0, 0);
    }
  }
#pragma unroll
  for (int i = 0; i < 4; ++i) {
#pragma unroll
    for (int j = 0; j < 4; ++j) {
      const int n = n0 + wn + j * 16 + lr;
      const float bv = bias ? bias[n] : 0.f;
#pragma unroll
      for (int r = 0; r < 4; ++r) {
        const int m = m0 + wm + i * 16 + (lane >> 4) * 4 + r;
        C[(size_t)m * N + n] = acc[i][j][r] * alpha + bv;
      }
    }
  }
}

// ------------------------------------------------- fused QKV 3-pass MFMA
// grid.x: 12 = 3 mats x 4 n-blocks; grid.y: TOK/128. One launch = 384 blocks
// (was 3 launches x 128 blocks at ~0.5 block/CU each).
__global__ __launch_bounds__(256) void mfma_qkv3(
    const u16* __restrict__ Ahi, const u16* __restrict__ Alo,
    const u16* __restrict__ Wq_h, const u16* __restrict__ Wq_l,
    const u16* __restrict__ Wk_h, const u16* __restrict__ Wk_l,
    const u16* __restrict__ Wv_h, const u16* __restrict__ Wv_l,
    const float* __restrict__ bq, const float* __restrict__ bk,
    const float* __restrict__ bv,
    float* __restrict__ qo, float* __restrict__ ko, float* __restrict__ vo) {
  constexpr int K = DMODEL;
  constexpr int NT = 128 * 40;
  __shared__ u16 lds[4 * NT];
  u16(*As)[40] = (u16(*)[40])lds;
  u16(*Bs)[40] = (u16(*)[40])(lds + NT);
  u16(*Als)[40] = (u16(*)[40])(lds + 2 * NT);
  u16(*Bls)[40] = (u16(*)[40])(lds + 3 * NT);
  const int mat = blockIdx.x >> 2;
  const u16* Bhi = (mat == 0) ? Wq_h : (mat == 1) ? Wk_h : Wv_h;
  const u16* Blo = (mat == 0) ? Wq_l : (mat == 1) ? Wk_l : Wv_l;
  const float* bias = (mat == 0) ? bq : (mat == 1) ? bk : bv;
  float* C = (mat == 0) ? qo : (mat == 1) ? ko : vo;
  const int m0 = blockIdx.y * 128, n0 = (blockIdx.x & 3) * 128;
  const int t = threadIdx.x;
  const int sr = t >> 1, c0 = (t & 1) * 2;
  const int w0 = ((c0) ^ (sr & 3)) * 8, w1 = ((c0 + 1) ^ (sr & 3)) * 8;
  const u16* aH = Ahi + (size_t)(m0 + sr) * K;
  const u16* aL = Alo + (size_t)(m0 + sr) * K;
  const u16* bH = Bhi + (size_t)(n0 + sr) * K;
  const u16* bL = Blo + (size_t)(n0 + sr) * K;
  const int lane = t & 63, w = t >> 6;
  const int wm = (w >> 1) * 64, wn = (w & 1) * 64;
  const int lr = lane & 15;
  const int kcol = SWZC(lane);

  f32x4 acc[4][4] = {};
  for (int k0 = 0; k0 < K; k0 += 32) {
    __syncthreads();
    *(uint4*)&As[sr][w0] = *(const uint4*)(aH + k0 + c0 * 8);
    *(uint4*)&As[sr][w1] = *(const uint4*)(aH + k0 + c0 * 8 + 8);
    *(uint4*)&Bs[sr][w0] = *(const uint4*)(bH + k0 + c0 * 8);
    *(uint4*)&Bs[sr][w1] = *(const uint4*)(bH + k0 + c0 * 8 + 8);
    *(uint4*)&Als[sr][w0] = *(const uint4*)(aL + k0 + c0 * 8);
    *(uint4*)&Als[sr][w1] = *(const uint4*)(aL + k0 + c0 * 8 + 8);
    *(uint4*)&Bls[sr][w0] = *(const uint4*)(bL + k0 + c0 * 8);
    *(uint4*)&Bls[sr][w1] = *(const uint4*)(bL + k0 + c0 * 8 + 8);
    __syncthreads();
    bf16x8 ah[4], bh[4], al[4], bl[4];
#pragma unroll
    for (int i = 0; i < 4; ++i) {
      ah[i] = *(const bf16x8*)&As[wm + i * 16 + lr][kcol];
      bh[i] = *(const bf16x8*)&Bs[wn + i * 16 + lr][kcol];
      al[i] = *(const bf16x8*)&Als[wm + i * 16 + lr][kcol];
      bl[i] = *(const bf16x8*)&Bls[wn + i * 16 + lr][kcol];
    }
#pragma unroll
    for (int i = 0; i < 4; ++i)
#pragma unroll
      for (int j = 0; j < 4; ++j) {
        acc[i][j] = __builtin_amdgcn_mfma_f32_16x16x32_bf16(ah[i], bh[j], acc[i][j], 0, 0, 0);
        acc[i][j] = __builtin_amdgcn_mfma_f32_16x16x32_bf16(al[i], bh[j], acc[i][j], 0, 0, 0);
        acc[i][j] = __builtin_amdgcn_mfma_f32_16x16x32_bf16(ah[i], bl[j], acc[i][j], 0, 0, 0);
      }
  }
#pragma unroll
  for (int i = 0; i < 4; ++i) {
#pragma unroll
    for (int j = 0; j < 4; ++j) {
      const int n = n0 + wn + j * 16 + lr;
      const float bv2 = bias[n];
#pragma unroll
      for (int r = 0; r < 4; ++r) {
        const int m = m0 + wm + i * 16 + (lane >> 4) * 4 + r;
        C[(size_t)m * DMODEL + n] = acc[i][j][r] + bv2;
      }
    }
  }
}

// ------------------------------------------------- MFMA expert GEMM 1
template <int PASSES>
__global__ __launch_bounds__(256) void mfma_moe1(
    const u16* __restrict__ Ahi, const u16* __restrict__ Alo,
    const u16* __restrict__ Bhi, const u16* __restrict__ Blo,
    const float* __restrict__ b1l, const int* __restrict__ list,
    const int* __restrict__ blockExp, const int* __restrict__ blockBase,
    const int* __restrict__ blockValid, int byOff,
    u16* __restrict__ Hhi, u16* __restrict__ Hlo) {
  constexpr int K = DMODEL;
  constexpr int NT = 128 * 40;
  __shared__ u16 lds[(PASSES == 3 ? 4 : 2) * NT];
  u16(*As)[40] = (u16(*)[40])lds;
  u16(*Bs)[40] = (u16(*)[40])(lds + NT);
  u16(*Als)[40] = (u16(*)[40])(lds + 2 * NT);
  u16(*Bls)[40] = (u16(*)[40])(lds + 3 * NT);
  const int by = byOff + blockIdx.y;
  const int e = blockExp[by];
  if (e < 0) return;
  const int row0 = blockBase[by], valid = blockValid[by];
  const int hbase = blockBase[byOff];
  const int n0 = blockIdx.x * 128;
  const int t = threadIdx.x;
  const int sr = t >> 1, c0 = (t & 1) * 2;
  const int w0 = ((c0) ^ (sr & 3)) * 8, w1 = ((c0 + 1) ^ (sr & 3)) * 8;
  const int atok = list[row0 + ((sr < valid) ? sr : 0)];
  const u16* aH = Ahi + (size_t)atok * K;
  const u16* aL = Alo + (size_t)atok * K;
  const u16* bH = Bhi + ((size_t)e * HDIM + n0 + sr) * K;
  const u16* bL = Blo + ((size_t)e * HDIM + n0 + sr) * K;
  const int lane = t & 63, w = t >> 6;
  const int wm = (w >> 1) * 64, wn = (w & 1) * 64;
  const int lr = lane & 15;
  const int kcol = SWZC(lane);

  f32x4 acc[4][4] = {};
  for (int k0 = 0; k0 < K; k0 += 32) {
    __syncthreads();
    *(uint4*)&As[sr][w0] = *(const uint4*)(aH + k0 + c0 * 8);
    *(uint4*)&As[sr][w1] = *(const uint4*)(aH + k0 + c0 * 8 + 8);
    *(uint4*)&Bs[sr][w0] = *(const uint4*)(bH + k0 + c0 * 8);
    *(uint4*)&Bs[sr][w1] = *(const uint4*)(bH + k0 + c0 * 8 + 8);
    if constexpr (PASSES == 3) {
      *(uint4*)&Als[sr][w0] = *(const uint4*)(aL + k0 + c0 * 8);
      *(uint4*)&Als[sr][w1] = *(const uint4*)(aL + k0 + c0 * 8 + 8);
      *(uint4*)&Bls[sr][w0] = *(const uint4*)(bL + k0 + c0 * 8);
      *(uint4*)&Bls[sr][w1] = *(const uint4*)(bL + k0 + c0 * 8 + 8);
    }
    __syncthreads();
    bf16x8 ah[4], bh[4];
#pragma unroll
    for (int i = 0; i < 4; ++i) {
      ah[i] = *(const bf16x8*)&As[wm + i * 16 + lr][kcol];
      bh[i] = *(const bf16x8*)&Bs[wn + i * 16 + lr][kcol];
    }
    if constexpr (PASSES == 3) {
      bf16x8 al[4], bl[4];
#pragma unroll
      for (int i = 0; i < 4; ++i) {
        al[i] = *(const bf16x8*)&Als[wm + i * 16 + lr][kcol];
        bl[i] = *(const bf16x8*)&Bls[wn + i * 16 + lr][kcol];
      }
#pragma unroll
      for (int i = 0; i < 4; ++i)
#pragma unroll
        for (int j = 0; j < 4; ++j) {
          acc[i][j] = __builtin_amdgcn_mfma_f32_16x16x32_bf16(ah[i], bh[j], acc[i][j], 0, 0, 0);
          acc[i][j] = __builtin_amdgcn_mfma_f32_16x16x32_bf16(al[i], bh[j], acc[i][j], 0, 0, 0);
          acc[i][j] = __builtin_amdgcn_mfma_f32_16x16x32_bf16(ah[i], bl[j], acc[i][j], 0, 0, 0);
        }
    } else {
#pragma unroll
      for (int i = 0; i < 4; ++i)
#pragma unroll
        for (int j = 0; j < 4; ++j)
          acc[i][j] = __builtin_amdgcn_mfma_f32_16x16x32_bf16(ah[i], bh[j], acc[i][j], 0, 0, 0);
    }
  }
#pragma unroll
  for (int i = 0; i < 4; ++i) {
#pragma unroll
    for (int j = 0; j < 4; ++j) {
      const int n = n0 + wn + j * 16 + lr;
      const float bv = b1l[(size_t)e * HDIM + n];
#pragma unroll
      for (int r = 0; r < 4; ++r) {
        const int m = wm + i * 16 + (lane >> 4) * 4 + r;
        if (m < valid) {
          const float h = fmaxf(acc[i][j][r] + bv, 0.f);
          const u16 hh = f2bf(h);
          const size_t idx = (size_t)(row0 + m - hbase) * HDIM + n;
          Hhi[idx] = hh;
          if constexpr (PASSES == 3) Hlo[idx] = f2bf(h - bf2f(hh));
        }
      }
    }
  }
}

// ------------------------------------------------- MFMA expert GEMM 2
// K-split over blockIdx.z (KSPLIT2 slices); partial sums combine via the
// existing atomicAdd epilogue. Bias added only by slice z==0.
template <int PASSES>
__global__ __launch_bounds__(256) void mfma_moe2(
    const u16* __restrict__ Hhi, const u16* __restrict__ Hlo,
    const u16* __restrict__ Bhi, const u16* __restrict__ Blo,
    const float* __restrict__ b2l, const int* __restrict__ list,
    const int* __restrict__ blockExp, const int* __restrict__ blockBase,
    const int* __restrict__ blockValid, int byOff,
    const float* __restrict__ rowGate, float* __restrict__ moe) {
  constexpr int K = HDIM;
  constexpr int KC = K / KSPLIT2;
  constexpr int NT = 128 * 40;
  __shared__ u16 lds[(PASSES == 3 ? 4 : 2) * NT];
  u16(*As)[40] = (u16(*)[40])lds;
  u16(*Bs)[40] = (u16(*)[40])(lds + NT);
  u16(*Als)[40] = (u16(*)[40])(lds + 2 * NT);
  u16(*Bls)[40] = (u16(*)[40])(lds + 3 * NT);
  const int by = byOff + blockIdx.y;
  const int e = blockExp[by];
  if (e < 0) return;
  const int row0 = blockBase[by], valid = blockValid[by];
  const int hbase = blockBase[byOff];
  const int n0 = blockIdx.x * 128;
  const int kb = blockIdx.z * KC;
  const int t = threadIdx.x;
  const int sr = t >> 1, c0 = (t & 1) * 2;
  const int w0 = ((c0) ^ (sr & 3)) * 8, w1 = ((c0 + 1) ^ (sr & 3)) * 8;
  const u16* aH = Hhi + (size_t)(row0 + sr - hbase) * K;
  const u16* aL = Hlo + (size_t)(row0 + sr - hbase) * K;
  const u16* bH = Bhi + ((size_t)e * DMODEL + n0 + sr) * K;
  const u16* bL = Blo + ((size_t)e * DMODEL + n0 + sr) * K;
  const int lane = t & 63, w = t >> 6;
  const int wm = (w >> 1) * 64, wn = (w & 1) * 64;
  const int lr = lane & 15;
  const int kcol = SWZC(lane);

  f32x4 acc[4][4] = {};
  for (int k0 = kb; k0 < kb + KC; k0 += 32) {
    __syncthreads();
    *(uint4*)&As[sr][w0] = *(const uint4*)(aH + k0 + c0 * 8);
    *(uint4*)&As[sr][w1] = *(const uint4*)(aH + k0 + c0 * 8 + 8);
    *(uint4*)&Bs[sr][w0] = *(const uint4*)(bH + k0 + c0 * 8);
    *(uint4*)&Bs[sr][w1] = *(const uint4*)(bH + k0 + c0 * 8 + 8);
    if constexpr (PASSES == 3) {
      *(uint4*)&Als[sr][w0] = *(const uint4*)(aL + k0 + c0 * 8);
      *(uint4*)&Als[sr][w1] = *(const uint4*)(aL + k0 + c0 * 8 + 8);
      *(uint4*)&Bls[sr][w0] = *(const uint4*)(bL + k0 + c0 * 8);
      *(uint4*)&Bls[sr][w1] = *(const uint4*)(bL + k0 + c0 * 8 + 8);
    }
    __syncthreads();
    bf16x8 ah[4], bh[4];
#pragma unroll
    for (int i = 0; i < 4; ++i) {
      ah[i] = *(const bf16x8*)&As[wm + i * 16 + lr][kcol];
      bh[i] = *(const bf16x8*)&Bs[wn + i * 16 + lr][kcol];
    }
    if constexpr (PASSES == 3) {
      bf16x8 al[4], bl[4];
#pragma unroll
      for (int i = 0; i < 4; ++i) {
        al[i] = *(const bf16x8*)&Als[wm + i * 16 + lr][kcol];
        bl[i] = *(const bf16x8*)&Bls[wn + i * 16 + lr][kcol];
      }
#pragma unroll
      for (int i = 0; i < 4; ++i)
#pragma unroll
        for (int j = 0; j < 4; ++j) {
          acc[i][j] = __builtin_amdgcn_mfma_f32_16x16x32_bf16(ah[i], bh[j], acc[i][j], 0, 0, 0);
          acc[i][j] = __builtin_amdgcn_mfma_f32_16x16x32_bf16(al[i], bh[j], acc[i][j], 0, 0, 0);
          acc[i][j] = __builtin_amdgcn_mfma_f32_16x16x32_bf16(ah[i], bl[j], acc[i][j], 0, 0, 0);
        }
    } else {
#pragma unroll
      for (int i = 0; i < 4; ++i)
#pragma unroll
        for (int j = 0; j < 4; ++j)
          acc[i][j] = __builtin_amdgcn_mfma_f32_16x16x32_bf16(ah[i], bh[j], acc[i][j], 0, 0, 0);
    }
  }
  const bool addBias = (blockIdx.z == 0);
#pragma unroll
  for (int i = 0; i < 4; ++i) {
#pragma unroll
    for (int r = 0; r < 4; ++r) {
      const int m = wm + i * 16 + (lane >> 4) * 4 + r;
      if (m >= valid) continue;
      const int tok = list[row0 + m];
      const float g = rowGate[row0 + m];
      float* orow = moe + (size_t)tok * DMODEL;
#pragma unroll
      for (int j = 0; j < 4; ++j) {
        const int n = n0 + wn + j * 16 + lr;
        float v = acc[i][j][r];
        if (addBias) v += b2l[(size_t)e * DMODEL + n];
        atomicAdd(orow + n, v * g);
      }
    }
  }
}

// ---------------------------------------------------------------- RoPE
__global__ __launch_bounds__(256) void rope_rot(
    float* __restrict__ q, float* __restrict__ k,
    const float* __restrict__ nc, const float* __restrict__ wr) {
  const int tok = blockIdx.x, j = threadIdx.x;
  const float c0 = nc[tok * 2 + 0], c1 = nc[tok * 2 + 1];
  const float f = c0 * wr[j] + c1 * wr[256 + j];
  const float cf = cosf(f), sf = sinf(f);
  float2* q2 = (float2*)(q + (long long)tok * DMODEL);
  float2* k2 = (float2*)(k + (long long)tok * DMODEL);
  const float2 qq = q2[j];
  const float2 kk = k2[j];
  q2[j] = make_float2(qq.x * cf - qq.y * sf, qq.x * sf + qq.y * cf);
  k2[j] = make_float2(kk.x * cf - kk.y * sf, kk.x * sf + kk.y * cf);
}

// ---------------------------------------------------------------- softmax
__global__ __launch_bounds__(256) void attn_softmax(
    float* __restrict__ S, const unsigned char* __restrict__ pad) {
  const int q = blockIdx.x & (LSEQ - 1);
  const int b = blockIdx.x >> 10;
  float* row = S + (long long)blockIdx.x * LSEQ;
  const int t = threadIdx.x;
  const float4 v = ((const float4*)row)[t];
  float vals[4] = {v.x, v.y, v.z, v.w};
  const int k0 = t * 4;
#pragma unroll
  for (int j = 0; j < 4; ++j) {
    const int k = k0 + j;
    if (k > q || pad[b * LSEQ + k]) vals[j] = -INFINITY;
  }
  __shared__ float red[4];
  const int wid = t >> 6, lane = t & 63;
  float m = waveAllMax(fmaxf(fmaxf(vals[0], vals[1]), fmaxf(vals[2], vals[3])));
  if (lane == 0) red[wid] = m;
  __syncthreads();
  m = fmaxf(fmaxf(red[0], red[1]), fmaxf(red[2], red[3]));
  const float e0 = expf(vals[0] - m), e1 = expf(vals[1] - m);
  const float e2 = expf(vals[2] - m), e3 = expf(vals[3] - m);
  const float ps = waveAllSum(e0 + e1 + e2 + e3);
  __syncthreads();
  if (lane == 0) red[wid] = ps;
  __syncthreads();
  const float tot = red[0] + red[1] + red[2] + red[3];
  float4 o;
  o.x = e0 / tot; o.y = e1 / tot; o.z = e2 / tot; o.w = e3 / tot;
  ((float4*)row)[t] = o;
}

// ---------------------------------------------------------------- add + LN
__global__ __launch_bounds__(128) void ln_add(
    const float* __restrict__ Aa, const float* __restrict__ Bb,
    const float* __restrict__ gg, const float* __restrict__ bb,
    float* __restrict__ out) {
  const int row = blockIdx.x, t = threadIdx.x;
  const float4 va = ((const float4*)(Aa + (long long)row * DMODEL))[t];
  const float4 vb = ((const float4*)(Bb + (long long)row * DMODEL))[t];
  const float x0 = va.x + vb.x, x1 = va.y + vb.y;
  const float x2 = va.z + vb.z, x3 = va.w + vb.w;
  __shared__ float r1[2], r2[2];
  const int wid = t >> 6, lane = t & 63;
  const float s = waveAllSum(x0 + x1 + x2 + x3);
  if (lane == 0) r1[wid] = s;
  __syncthreads();
  const float mean = (r1[0] + r1[1]) * (1.0f / DMODEL);
  const float d0 = x0 - mean, d1 = x1 - mean, d2 = x2 - mean, d3 = x3 - mean;
  const float vs = waveAllSum(d0 * d0 + d1 * d1 + d2 * d2 + d3 * d3);
  if (lane == 0) r2[wid] = vs;
  __syncthreads();
  const float var = (r2[0] + r2[1]) * (1.0f / DMODEL);
  const float rs = rsqrtf(var + 1e-5f);
  const float4 g4 = ((const float4*)gg)[t];
  const float4 b4 = ((const float4*)bb)[t];
  float4 o;
  o.x = d0 * rs * g4.x + b4.x;
  o.y = d1 * rs * g4.y + b4.y;
  o.z = d2 * rs * g4.z + b4.z;
  o.w = d3 * rs * g4.w + b4.w;
  ((float4*)(out + (long long)row * DMODEL))[t] = o;
}

// ------------------------------------------------- router v2 (LDS-staged W)
__global__ __launch_bounds__(256) void router_topk2(
    const float* __restrict__ x, const float* __restrict__ rtw,
    const float* __restrict__ rtb, const float* __restrict__ nzw,
    const float* __restrict__ nzb, float* __restrict__ gate,
    int* __restrict__ counts, unsigned char* __restrict__ selmask, int layer) {
  __shared__ float Wl[16][524];
  __shared__ float noisyS[16][8];
  const int t = threadIdx.x;
  for (int i = t; i < DMODEL * NEXP; i += 256) {
    const int d = i >> 3, e = i & 7;
    Wl[e][d] = rtw[i];
    Wl[8 + e][d] = nzw[i];
  }
  __syncthreads();
  const int tt = t >> 4, o = t & 15;
  const int tok = blockIdx.x * 16 + tt;
  const float4* x4 = (const float4*)(x + (size_t)tok * DMODEL);
  float s = 0.f;
#pragma unroll 4
  for (int dd = 0; dd < DMODEL / 4; ++dd) {
    const float4 xv = x4[dd];
    const float4 wv = *(const float4*)&Wl[o][dd * 4];
    s = fmaf(xv.x, wv.x, s);
    s = fmaf(xv.y, wv.y, s);
    s = fmaf(xv.z, wv.z, s);
    s = fmaf(xv.w, wv.w, s);
  }
  const float other = __shfl_xor(s, 8, 64);  // pair logit<->noise lanes
  if (o < 8) {
    const float logit = s + rtb[o];
    const float nl = other + nzb[o];
    const float eps = eps_normal((unsigned)(tok * NEXP + o), (unsigned)layer);
    const float sp = fmaxf(nl, 0.f) + log1pf(expf(-fabsf(nl)));  // logaddexp(x,0)
    noisyS[tt][o] = logit + eps * sp;
  }
  __syncthreads();
  if (t < 16) {
    const int tk = blockIdx.x * 16 + t;
    float v[8]; bool sel[8];
#pragma unroll
    for (int i = 0; i < 8; ++i) { v[i] = noisyS[t][i]; sel[i] = false; }
    for (int r = 0; r < TOPK; ++r) {  // strict '>' => lowest index wins ties
      int bi = 0; float best = -INFINITY;
      for (int i = 0; i < 8; ++i)
        if (!sel[i] && v[i] > best) { best = v[i]; bi = i; }
      sel[bi] = true;
    }
    float m = -INFINITY;
    for (int i = 0; i < 8; ++i) if (sel[i]) m = fmaxf(m, v[i]);
    float ex[8]; float den = 0.f;
    unsigned char mbits = 0;
    for (int i = 0; i < 8; ++i) {
      ex[i] = sel[i] ? expf(v[i] - m) : 0.f;
      den += ex[i];
      if (sel[i]) { mbits |= (unsigned char)(1u << i); atomicAdd(&counts[i], 1); }
    }
    for (int i = 0; i < 8; ++i) gate[tk * NEXP + i] = ex[i] / den;
    selmask[tk] = mbits;
  }
}

// ------------------------------------------------- dispatch plan/build/zero
__global__ void moe_plan(const int* __restrict__ counts, int* __restrict__ start,
                         int* __restrict__ blockExp, int* __restrict__ blockBase,
                         int* __restrict__ blockValid) {
  if (threadIdx.x != 0) return;
  int s = 0, by = 0;
  for (int e = 0; e < NEXP; ++e) {
    start[e] = s;
    const int c = counts[e];
    const int nb = (c + 127) >> 7;
    for (int b = 0; b < nb; ++b) {
      blockExp[by] = e;
      blockBase[by] = s + b * 128;
      blockValid[by] = min(128, c - b * 128);
      ++by;
    }
    s += nb * 128;
  }
  for (; by < NBLK; ++by) { blockExp[by] = -1; blockBase[by] = s; blockValid[by] = 0; }
}

__global__ __launch_bounds__(256) void moe_build(
    const unsigned char* __restrict__ selmask, const int* __restrict__ start,
    int* __restrict__ cursor, int* __restrict__ list,
    const float* __restrict__ gate, float* __restrict__ rowGate) {
  const int tok = blockIdx.x * 256 + threadIdx.x;
  if (tok >= TOK) return;
  unsigned m = selmask[tok];
  while (m) {
    const int e = __ffs(m) - 1;
    m &= m - 1;
    const int slot = atomicAdd(&cursor[e], 1);
    list[start[e] + slot] = tok;
    rowGate[start[e] + slot] = gate[tok * NEXP + e];
  }
}

__global__ __launch_bounds__(256) void zero_f32(float* __restrict__ p, int n4) {
  const int i = blockIdx.x * 256 + threadIdx.x;
  if (i < n4) ((float4*)p)[i] = make_float4(0.f, 0.f, 0.f, 0.f);
}
__global__ void zero_i32(int* __restrict__ p, int n) {
  const int i = threadIdx.x;
  if (i < n) p[i] = 0;
}

// ---------------------------------------------------------------- launch
extern "C" void kernel_launch(void* const* d_in, const int* in_sizes, int n_in,
                              void* d_out, int out_size, void* d_ws,
                              size_t ws_size, hipStream_t stream) {
  const float* x_in = (const float*)d_in[0];
  const float* nc = (const float*)d_in[1];
  const unsigned char* pad = (const unsigned char*)d_in[3];
  const float* wq = (const float*)d_in[4];
  const float* bq = (const float*)d_in[5];
  const float* wk = (const float*)d_in[6];
  const float* bk = (const float*)d_in[7];
  const float* wv = (const float*)d_in[8];
  const float* bv = (const float*)d_in[9];
  const float* wr = (const float*)d_in[10];
  const float* ln1g = (const float*)d_in[11];
  const float* ln1b = (const float*)d_in[12];
  const float* rtw = (const float*)d_in[13];
  const float* rtb = (const float*)d_in[14];
  const float* nzw = (const float*)d_in[15];
  const float* nzb = (const float*)d_in[16];
  const float* ew1 = (const float*)d_in[17];
  const float* eb1 = (const float*)d_in[18];
  const float* ew2 = (const float*)d_in[19];
  const float* eb2 = (const float*)d_in[20];
  const float* ln2g = (const float*)d_in[21];
  const float* ln2b = (const float*)d_in[22];

  float* ws = (float*)d_ws;
  const long long SZ = (long long)TOK * DMODEL;  // 2,097,152
  float* qb = ws;                        // also attn output
  float* kb = ws + SZ;
  float* vb2 = ws + 2 * SZ;
  float* xcur = ws + 3 * SZ;
  float* moe = ws + 4 * SZ;
  float* gate = ws + 5 * SZ;
  int* meta = (int*)(ws + 10518528);
  int* counts = meta;
  int* cursor = meta + 8;
  int* startE = meta + 16;
  int* blockExp = meta + 24;
  int* blockBase = meta + 160;
  int* blockValid = meta + 296;
  int* list = meta + 432;
  unsigned char* selmask = (unsigned char*)(meta + 17840);
  float* rowGate = ws + 10537408;
  u16* Xhi = (u16*)(ws + 10554816);      // expert split of xcur
  u16* Xlo = (u16*)(ws + 11603392);

  // ---- attention region (aliases expert W1T/W2T/H region; disjoint lifetime)
  float* scores = ws + 12651968;         // 4,194,304 f32
  u16* ub = (u16*)(ws + 16846272);
  u16* XAhi = ub;                        // 2,097,152 each
  u16* XAlo = ub + 2097152;
  u16* Qhi = ub + 4194304;
  u16* Qlo = ub + 6291456;
  u16* Khi = ub + 8388608;
  u16* Klo = ub + 10485760;
  u16* Phi = ub + 12582912;              // 4,194,304 each
  u16* Plo = ub + 16777216;
  u16* VThi = ub + 20971520;             // 2,097,152 each
  u16* VTlo = ub + 23068672;
  u16* WqThi = ub + 25165824;            // 262,144 each
  u16* WqTlo = ub + 25427968;
  u16* WkThi = ub + 25690112;
  u16* WkTlo = ub + 25952256;
  u16* WvThi = ub + 26214400;
  u16* WvTlo = ub + 26476544;            // region ends 30,215,616 floats

  // ---- expert region (written after attention each layer)
  u16* W1Thi = (u16*)(ws + 12651968);
  u16* W1Tlo = (u16*)(ws + 16846272);
  u16* W2Thi = (u16*)(ws + 21040576);
  u16* W2Tlo = (u16*)(ws + 25234880);
  u16* Hhi = (u16*)(ws + 29429184);
  u16* Hlo = (u16*)(ws + 38342080);      // high-water 47,254,976 f = 189 MB

  const float iscale = 1.0f / sqrtf((float)DMODEL);
  const dim3 blk(256);
  const long long sQ = (long long)LSEQ * DMODEL;   // per-batch q/k/v stride
  const long long sS = (long long)LSEQ * LSEQ;     // per-batch scores stride

  for (int l = 0; l < NLAYER; ++l) {
    const float* xl = (l == 0) ? x_in : xcur;
    const long long wOff = (long long)l * DMODEL * DMODEL;

    // ---- QKV via fused split-bf16 MFMA (one 384-block launch)
    split_f32_bf16<<<2048, blk, 0, stream>>>(xl, XAhi, XAlo, (int)SZ);
    transpose_split<<<dim3(16, 16, 1), blk, 0, stream>>>(wq + wOff, WqThi, WqTlo, DMODEL, DMODEL);
    transpose_split<<<dim3(16, 16, 1), blk, 0, stream>>>(wk + wOff, WkThi, WkTlo, DMODEL, DMODEL);
    transpose_split<<<dim3(16, 16, 1), blk, 0, stream>>>(wv + wOff, WvThi, WvTlo, DMODEL, DMODEL);
    mfma_qkv3<<<dim3(12, TOK / 128), blk, 0, stream>>>(
        XAhi, XAlo, WqThi, WqTlo, WkThi, WkTlo, WvThi, WvTlo,
        bq + l * DMODEL, bk + l * DMODEL, bv + l * DMODEL, qb, kb, vb2);

    rope_rot<<<TOK, 256, 0, stream>>>(qb, kb, nc, wr + (long long)l * DMODEL);

    // ---- scores = (q @ k^T) * iscale via split-bf16 MFMA
    split_f32_bf16<<<2048, blk, 0, stream>>>(qb, Qhi, Qlo, (int)SZ);
    split_f32_bf16<<<2048, blk, 0, stream>>>(kb, Khi, Klo, (int)SZ);
    mfma_gemm3<3><<<dim3(8, 8, BATCH), blk, 0, stream>>>(
        Qhi, Qlo, Khi, Klo, nullptr, scores, LSEQ, DMODEL, iscale, sQ, sQ, sS);

    attn_softmax<<<BATCH * LSEQ, 256, 0, stream>>>(scores, pad);

    // ---- attn @ v via split-bf16 MFMA (v transposed to [D][L] per batch)
    split_f32_bf16<<<4096, blk, 0, stream>>>(scores, Phi, Plo, (int)(4 * sS / 4 * 4));
    transpose_split<<<dim3(16, 32, BATCH), blk, 0, stream>>>(vb2, VThi, VTlo, LSEQ, DMODEL);
    mfma_gemm3<3><<<dim3(4, 8, BATCH), blk, 0, stream>>>(
        Phi, Plo, VThi, VTlo, nullptr, qb, DMODEL, LSEQ, 1.f, sS, sQ, sQ);

    ln_add<<<TOK, 128, 0, stream>>>(xl, qb, ln1g + l * DMODEL, ln1b + l * DMODEL, xcur);

    // ---- router + dispatch
    zero_i32<<<1, 64, 0, stream>>>(counts, 16);
    router_topk2<<<TOK / 16, blk, 0, stream>>>(
        xcur, rtw + l * DMODEL * NEXP, rtb + l * NEXP, nzw + l * DMODEL * NEXP,
        nzb + l * NEXP, gate, counts, selmask, l);
    moe_plan<<<1, 64, 0, stream>>>(counts, startE, blockExp, blockBase, blockValid);
    moe_build<<<TOK / 256, 256, 0, stream>>>(selmask, startE, cursor, list, gate, rowGate);
    zero_f32<<<(int)(SZ / 4 / 256), 256, 0, stream>>>(moe, (int)(SZ / 4));

    // ---- experts (3-pass split-bf16, grouped, chunked H, K-split moe2)
    split_f32_bf16<<<2048, blk, 0, stream>>>(xcur, Xhi, Xlo, (int)SZ);
    transpose_split<<<dim3(64, 16, 8), blk, 0, stream>>>(
        ew1 + (long long)l * NEXP * DMODEL * HDIM, W1Thi, W1Tlo, DMODEL, HDIM);
    transpose_split<<<dim3(16, 64, 8), blk, 0, stream>>>(
        ew2 + (long long)l * NEXP * HDIM * DMODEL, W2Thi, W2Tlo, HDIM, DMODEL);

    const float* b1l = eb1 + (long long)l * NEXP * HDIM;
    const float* b2l = eb2 + (long long)l * NEXP * DMODEL;
    for (int ch = 0; ch < 2; ++ch) {
      const int byOff = ch * CHBLK;
      mfma_moe1<3><<<dim3(HDIM / 128, CHBLK), blk, 0, stream>>>(
          Xhi, Xlo, W1Thi, W1Tlo, b1l, list, blockExp, blockBase, blockValid,
          byOff, Hhi, Hlo);
      mfma_moe2<3><<<dim3(DMODEL / 128, CHBLK, KSPLIT2), blk, 0, stream>>>(
          Hhi, Hlo, W2Thi, W2Tlo, b2l, list, blockExp, blockBase, blockValid,
          byOff, rowGate, moe);
    }

    float* outp = (l == NLAYER - 1) ? (float*)d_out : xcur;
    ln_add<<<TOK, 128, 0, stream>>>(xcur, moe, ln2g + l * DMODEL, ln2b + l * DMODEL, outp);
  }
}

// Round 11
// 1408.325 us; speedup vs baseline: 2.4895x; 1.2129x over previous
//
#include <hip/hip_runtime.h>
#include <math.h>

#define TOK 4096      // B*L
#define DMODEL 512
#define LSEQ 1024
#define BATCH 4
#define NLAYER 2
#define NEXP 8
#define TOPK 4
#define HDIM 2048
#define NBLK 136
#define CHBLK 68
#define KSPLIT2 4     // K-split factor for moe2 (K=2048 -> 4x512)

typedef unsigned short u16;
typedef __attribute__((ext_vector_type(8))) short bf16x8;
typedef __attribute__((ext_vector_type(4))) float f32x4;

// ---------------------------------------------------------------- bf16 split
__device__ __forceinline__ u16 f2bf(float x) {
  const unsigned u = __float_as_uint(x);
  return (u16)((u + 0x7FFFu + ((u >> 16) & 1u)) >> 16);
}
__device__ __forceinline__ float bf2f(u16 h) {
  return __uint_as_float(((unsigned)h) << 16);
}

// ---------------------------------------------------------------- reductions
__device__ __forceinline__ float waveAllSum(float v) {
#pragma unroll
  for (int off = 1; off < 64; off <<= 1) v += __shfl_xor(v, off, 64);
  return v;
}
__device__ __forceinline__ float waveAllMax(float v) {
#pragma unroll
  for (int off = 1; off < 64; off <<= 1) v = fmaxf(v, __shfl_xor(v, off, 64));
  return v;
}

// ---------------------------------------------------------------- threefry
__device__ __forceinline__ unsigned rotl32(unsigned x, int r) {
  return (x << r) | (x >> (32 - r));
}
__device__ __forceinline__ void tf2x32(unsigned k0, unsigned k1,
                                       unsigned& x0, unsigned& x1) {
  const unsigned ks0 = k0, ks1 = k1, ks2 = k0 ^ k1 ^ 0x1BD11BDAu;
  x0 += ks0; x1 += ks1;
#define TF_R4(a, b, c, d)                                   \
  x0 += x1; x1 = rotl32(x1, a); x1 ^= x0;                   \
  x0 += x1; x1 = rotl32(x1, b); x1 ^= x0;                   \
  x0 += x1; x1 = rotl32(x1, c); x1 ^= x0;                   \
  x0 += x1; x1 = rotl32(x1, d); x1 ^= x0;
  TF_R4(13, 15, 26, 6)  x0 += ks1; x1 += ks2 + 1u;
  TF_R4(17, 29, 16, 24) x0 += ks2; x1 += ks0 + 2u;
  TF_R4(13, 15, 26, 6)  x0 += ks0; x1 += ks1 + 3u;
  TF_R4(17, 29, 16, 24) x0 += ks1; x1 += ks2 + 4u;
  TF_R4(13, 15, 26, 6)  x0 += ks2; x1 += ks0 + 5u;
#undef TF_R4
}

__device__ __forceinline__ float xla_erfinv(float u) {
  float w = -log1pf(-__fmul_rn(u, u));
  float p;
  if (w < 5.0f) {
    w = __fadd_rn(w, -2.5f);
    p = 2.81022636e-08f;
    p = __fadd_rn(3.43273939e-07f, __fmul_rn(p, w));
    p = __fadd_rn(-3.5233877e-06f, __fmul_rn(p, w));
    p = __fadd_rn(-4.39150654e-06f, __fmul_rn(p, w));
    p = __fadd_rn(0.00021858087f, __fmul_rn(p, w));
    p = __fadd_rn(-0.00125372503f, __fmul_rn(p, w));
    p = __fadd_rn(-0.00417768164f, __fmul_rn(p, w));
    p = __fadd_rn(0.246640727f, __fmul_rn(p, w));
    p = __fadd_rn(1.50140941f, __fmul_rn(p, w));
  } else {
    w = __fadd_rn(sqrtf(w), -3.0f);
    p = -0.000200214257f;
    p = __fadd_rn(0.000100950558f, __fmul_rn(p, w));
    p = __fadd_rn(0.00134934322f, __fmul_rn(p, w));
    p = __fadd_rn(-0.00367342844f, __fmul_rn(p, w));
    p = __fadd_rn(0.00573950773f, __fmul_rn(p, w));
    p = __fadd_rn(-0.0076224613f, __fmul_rn(p, w));
    p = __fadd_rn(0.00943887047f, __fmul_rn(p, w));
    p = __fadd_rn(1.00167406f, __fmul_rn(p, w));
    p = __fadd_rn(2.83297682f, __fmul_rn(p, w));
  }
  return __fmul_rn(p, u);
}

__device__ __forceinline__ float bits_to_normal(unsigned bits) {
  const unsigned fb = (bits >> 9) | 0x3f800000u;
  const float u01 = __fadd_rn(__uint_as_float(fb), -1.0f);
  const float lo = -0.99999994f;
  float u = __fadd_rn(__fmul_rn(u01, 2.0f), lo);
  u = fmaxf(u, lo);
  return __fmul_rn(1.41421356237309515f, xla_erfinv(u));
}

__device__ __forceinline__ float eps_normal(unsigned i, unsigned layer) {
  unsigned f0 = 0u, f1 = layer;
  tf2x32(0u, 42u, f0, f1);
  unsigned x0 = 0u, x1 = i;
  tf2x32(f0, f1, x0, x1);
  return bits_to_normal(x0 ^ x1);
}

// ------------------------------------------------- split / transpose-split
__global__ __launch_bounds__(256) void split_f32_bf16(
    const float* __restrict__ in, u16* __restrict__ hi, u16* __restrict__ lo,
    int n) {
  const int i = (blockIdx.x * 256 + threadIdx.x) * 4;
  if (i >= n) return;
  const float4 v = *(const float4*)(in + i);
  ushort4 h, l;
  h.x = f2bf(v.x); l.x = f2bf(v.x - bf2f(h.x));
  h.y = f2bf(v.y); l.y = f2bf(v.y - bf2f(h.y));
  h.z = f2bf(v.z); l.z = f2bf(v.z - bf2f(h.z));
  h.w = f2bf(v.w); l.w = f2bf(v.w - bf2f(h.w));
  *(ushort4*)(hi + i) = h;
  *(ushort4*)(lo + i) = l;
}

// in [Z][R][C] f32 -> hi/lo [Z][C][R] bf16
__global__ __launch_bounds__(256) void transpose_split(
    const float* __restrict__ in, u16* __restrict__ hi, u16* __restrict__ lo,
    int R, int C) {
  __shared__ float tile[32][33];
  const size_t eoff = (size_t)blockIdx.z * R * C;
  const float* src = in + eoff;
  const int r0 = blockIdx.y * 32, c0 = blockIdx.x * 32;
  const int tx = threadIdx.x & 31, ty = threadIdx.x >> 5;
#pragma unroll
  for (int j = 0; j < 4; ++j)
    tile[ty + 8 * j][tx] = src[(size_t)(r0 + ty + 8 * j) * C + c0 + tx];
  __syncthreads();
  u16* dh = hi + eoff;
  u16* dl = lo + eoff;
#pragma unroll
  for (int j = 0; j < 4; ++j) {
    const float v = tile[tx][ty + 8 * j];
    const u16 h = f2bf(v);
    const size_t idx = (size_t)(c0 + ty + 8 * j) * R + r0 + tx;
    dh[idx] = h;
    dl[idx] = f2bf(v - bf2f(h));
  }
}

#define SWZC(lane) ((((lane) >> 4) ^ ((lane) & 3)) * 8)

// ------------------------------------------------- generic 3-pass MFMA GEMM
template <int PASSES>
__global__ __launch_bounds__(256) void mfma_gemm3(
    const u16* __restrict__ Ahi, const u16* __restrict__ Alo,
    const u16* __restrict__ Bhi, const u16* __restrict__ Blo,
    const float* __restrict__ bias, float* __restrict__ Cg,
    int N, int K, float alpha,
    long long sA, long long sB, long long sC) {
  constexpr int NT = 128 * 40;
  __shared__ u16 lds[(PASSES == 3 ? 4 : 2) * NT];
  u16(*As)[40] = (u16(*)[40])lds;
  u16(*Bs)[40] = (u16(*)[40])(lds + NT);
  u16(*Als)[40] = (u16(*)[40])(lds + 2 * NT);
  u16(*Bls)[40] = (u16(*)[40])(lds + 3 * NT);
  const int m0 = blockIdx.y * 128, n0 = blockIdx.x * 128;
  const int t = threadIdx.x;
  const int sr = t >> 1, c0 = (t & 1) * 2;
  const int w0 = ((c0) ^ (sr & 3)) * 8, w1 = ((c0 + 1) ^ (sr & 3)) * 8;
  const u16* aH = Ahi + (long long)blockIdx.z * sA + (size_t)(m0 + sr) * K;
  const u16* aL = Alo + (long long)blockIdx.z * sA + (size_t)(m0 + sr) * K;
  const u16* bH = Bhi + (long long)blockIdx.z * sB + (size_t)(n0 + sr) * K;
  const u16* bL = Blo + (long long)blockIdx.z * sB + (size_t)(n0 + sr) * K;
  float* C = Cg + (long long)blockIdx.z * sC;
  const int lane = t & 63, w = t >> 6;
  const int wm = (w >> 1) * 64, wn = (w & 1) * 64;
  const int lr = lane & 15;
  const int kcol = SWZC(lane);

  f32x4 acc[4][4] = {};
  for (int k0 = 0; k0 < K; k0 += 32) {
    __syncthreads();
    *(uint4*)&As[sr][w0] = *(const uint4*)(aH + k0 + c0 * 8);
    *(uint4*)&As[sr][w1] = *(const uint4*)(aH + k0 + c0 * 8 + 8);
    *(uint4*)&Bs[sr][w0] = *(const uint4*)(bH + k0 + c0 * 8);
    *(uint4*)&Bs[sr][w1] = *(const uint4*)(bH + k0 + c0 * 8 + 8);
    if constexpr (PASSES == 3) {
      *(uint4*)&Als[sr][w0] = *(const uint4*)(aL + k0 + c0 * 8);
      *(uint4*)&Als[sr][w1] = *(const uint4*)(aL + k0 + c0 * 8 + 8);
      *(uint4*)&Bls[sr][w0] = *(const uint4*)(bL + k0 + c0 * 8);
      *(uint4*)&Bls[sr][w1] = *(const uint4*)(bL + k0 + c0 * 8 + 8);
    }
    __syncthreads();
    bf16x8 ah[4], bh[4];
#pragma unroll
    for (int i = 0; i < 4; ++i) {
      ah[i] = *(const bf16x8*)&As[wm + i * 16 + lr][kcol];
      bh[i] = *(const bf16x8*)&Bs[wn + i * 16 + lr][kcol];
    }
    if constexpr (PASSES == 3) {
      bf16x8 al[4], bl[4];
#pragma unroll
      for (int i = 0; i < 4; ++i) {
        al[i] = *(const bf16x8*)&Als[wm + i * 16 + lr][kcol];
        bl[i] = *(const bf16x8*)&Bls[wn + i * 16 + lr][kcol];
      }
#pragma unroll
      for (int i = 0; i < 4; ++i)
#pragma unroll
        for (int j = 0; j < 4; ++j) {
          acc[i][j] = __builtin_amdgcn_mfma_f32_16x16x32_bf16(ah[i], bh[j], acc[i][j], 0, 0, 0);
          acc[i][j] = __builtin_amdgcn_mfma_f32_16x16x32_bf16(al[i], bh[j], acc[i][j], 0, 0, 0);
          acc[i][j] = __builtin_amdgcn_mfma_f32_16x16x32_bf16(ah[i], bl[j], acc[i][j], 0, 0, 0);
        }
    } else {
#pragma unroll
      for (int i = 0; i < 4; ++i)
#pragma unroll
        for (int j = 0; j < 4; ++j)
          acc[i][j] = __builtin_amdgcn_mfma_f32_16x16x32_bf16(ah[i], bh[j], acc[i][j], 0, 0, 0);
    }
  }
#pragma unroll
  for (int i = 0; i < 4; ++i) {
#pragma unroll
    for (int j = 0; j < 4; ++j) {
      const int n = n0 + wn + j * 16 + lr;
      const float bv = bias ? bias[n] : 0.f;
#pragma unroll
      for (int r = 0; r < 4; ++r) {
        const int m = m0 + wm + i * 16 + (lane >> 4) * 4 + r;
        C[(size_t)m * N + n] = acc[i][j][r] * alpha + bv;
      }
    }
  }
}

// ------------------------------------------------- fused QKV 3-pass MFMA
__global__ __launch_bounds__(256) void mfma_qkv3(
    const u16* __restrict__ Ahi, const u16* __restrict__ Alo,
    const u16* __restrict__ Wq_h, const u16* __restrict__ Wq_l,
    const u16* __restrict__ Wk_h, const u16* __restrict__ Wk_l,
    const u16* __restrict__ Wv_h, const u16* __restrict__ Wv_l,
    const float* __restrict__ bq, const float* __restrict__ bk,
    const float* __restrict__ bv,
    float* __restrict__ qo, float* __restrict__ ko, float* __restrict__ vo) {
  constexpr int K = DMODEL;
  constexpr int NT = 128 * 40;
  __shared__ u16 lds[4 * NT];
  u16(*As)[40] = (u16(*)[40])lds;
  u16(*Bs)[40] = (u16(*)[40])(lds + NT);
  u16(*Als)[40] = (u16(*)[40])(lds + 2 * NT);
  u16(*Bls)[40] = (u16(*)[40])(lds + 3 * NT);
  const int mat = blockIdx.x >> 2;
  const u16* Bhi = (mat == 0) ? Wq_h : (mat == 1) ? Wk_h : Wv_h;
  const u16* Blo = (mat == 0) ? Wq_l : (mat == 1) ? Wk_l : Wv_l;
  const float* bias = (mat == 0) ? bq : (mat == 1) ? bk : bv;
  float* C = (mat == 0) ? qo : (mat == 1) ? ko : vo;
  const int m0 = blockIdx.y * 128, n0 = (blockIdx.x & 3) * 128;
  const int t = threadIdx.x;
  const int sr = t >> 1, c0 = (t & 1) * 2;
  const int w0 = ((c0) ^ (sr & 3)) * 8, w1 = ((c0 + 1) ^ (sr & 3)) * 8;
  const u16* aH = Ahi + (size_t)(m0 + sr) * K;
  const u16* aL = Alo + (size_t)(m0 + sr) * K;
  const u16* bH = Bhi + (size_t)(n0 + sr) * K;
  const u16* bL = Blo + (size_t)(n0 + sr) * K;
  const int lane = t & 63, w = t >> 6;
  const int wm = (w >> 1) * 64, wn = (w & 1) * 64;
  const int lr = lane & 15;
  const int kcol = SWZC(lane);

  f32x4 acc[4][4] = {};
  for (int k0 = 0; k0 < K; k0 += 32) {
    __syncthreads();
    *(uint4*)&As[sr][w0] = *(const uint4*)(aH + k0 + c0 * 8);
    *(uint4*)&As[sr][w1] = *(const uint4*)(aH + k0 + c0 * 8 + 8);
    *(uint4*)&Bs[sr][w0] = *(const uint4*)(bH + k0 + c0 * 8);
    *(uint4*)&Bs[sr][w1] = *(const uint4*)(bH + k0 + c0 * 8 + 8);
    *(uint4*)&Als[sr][w0] = *(const uint4*)(aL + k0 + c0 * 8);
    *(uint4*)&Als[sr][w1] = *(const uint4*)(aL + k0 + c0 * 8 + 8);
    *(uint4*)&Bls[sr][w0] = *(const uint4*)(bL + k0 + c0 * 8);
    *(uint4*)&Bls[sr][w1] = *(const uint4*)(bL + k0 + c0 * 8 + 8);
    __syncthreads();
    bf16x8 ah[4], bh[4], al[4], bl[4];
#pragma unroll
    for (int i = 0; i < 4; ++i) {
      ah[i] = *(const bf16x8*)&As[wm + i * 16 + lr][kcol];
      bh[i] = *(const bf16x8*)&Bs[wn + i * 16 + lr][kcol];
      al[i] = *(const bf16x8*)&Als[wm + i * 16 + lr][kcol];
      bl[i] = *(const bf16x8*)&Bls[wn + i * 16 + lr][kcol];
    }
#pragma unroll
    for (int i = 0; i < 4; ++i)
#pragma unroll
      for (int j = 0; j < 4; ++j) {
        acc[i][j] = __builtin_amdgcn_mfma_f32_16x16x32_bf16(ah[i], bh[j], acc[i][j], 0, 0, 0);
        acc[i][j] = __builtin_amdgcn_mfma_f32_16x16x32_bf16(al[i], bh[j], acc[i][j], 0, 0, 0);
        acc[i][j] = __builtin_amdgcn_mfma_f32_16x16x32_bf16(ah[i], bl[j], acc[i][j], 0, 0, 0);
      }
  }
#pragma unroll
  for (int i = 0; i < 4; ++i) {
#pragma unroll
    for (int j = 0; j < 4; ++j) {
      const int n = n0 + wn + j * 16 + lr;
      const float bv2 = bias[n];
#pragma unroll
      for (int r = 0; r < 4; ++r) {
        const int m = m0 + wm + i * 16 + (lane >> 4) * 4 + r;
        C[(size_t)m * DMODEL + n] = acc[i][j][r] + bv2;
      }
    }
  }
}

// ------------------------------------------------- MFMA expert GEMM 1
template <int PASSES>
__global__ __launch_bounds__(256) void mfma_moe1(
    const u16* __restrict__ Ahi, const u16* __restrict__ Alo,
    const u16* __restrict__ Bhi, const u16* __restrict__ Blo,
    const float* __restrict__ b1l, const int* __restrict__ list,
    const int* __restrict__ blockExp, const int* __restrict__ blockBase,
    const int* __restrict__ blockValid, int byOff,
    u16* __restrict__ Hhi, u16* __restrict__ Hlo) {
  constexpr int K = DMODEL;
  constexpr int NT = 128 * 40;
  __shared__ u16 lds[(PASSES == 3 ? 4 : 2) * NT];
  u16(*As)[40] = (u16(*)[40])lds;
  u16(*Bs)[40] = (u16(*)[40])(lds + NT);
  u16(*Als)[40] = (u16(*)[40])(lds + 2 * NT);
  u16(*Bls)[40] = (u16(*)[40])(lds + 3 * NT);
  const int by = byOff + blockIdx.y;
  const int e = blockExp[by];
  if (e < 0) return;
  const int row0 = blockBase[by], valid = blockValid[by];
  const int hbase = blockBase[byOff];
  const int n0 = blockIdx.x * 128;
  const int t = threadIdx.x;
  const int sr = t >> 1, c0 = (t & 1) * 2;
  const int w0 = ((c0) ^ (sr & 3)) * 8, w1 = ((c0 + 1) ^ (sr & 3)) * 8;
  const int atok = list[row0 + ((sr < valid) ? sr : 0)];
  const u16* aH = Ahi + (size_t)atok * K;
  const u16* aL = Alo + (size_t)atok * K;
  const u16* bH = Bhi + ((size_t)e * HDIM + n0 + sr) * K;
  const u16* bL = Blo + ((size_t)e * HDIM + n0 + sr) * K;
  const int lane = t & 63, w = t >> 6;
  const int wm = (w >> 1) * 64, wn = (w & 1) * 64;
  const int lr = lane & 15;
  const int kcol = SWZC(lane);

  f32x4 acc[4][4] = {};
  for (int k0 = 0; k0 < K; k0 += 32) {
    __syncthreads();
    *(uint4*)&As[sr][w0] = *(const uint4*)(aH + k0 + c0 * 8);
    *(uint4*)&As[sr][w1] = *(const uint4*)(aH + k0 + c0 * 8 + 8);
    *(uint4*)&Bs[sr][w0] = *(const uint4*)(bH + k0 + c0 * 8);
    *(uint4*)&Bs[sr][w1] = *(const uint4*)(bH + k0 + c0 * 8 + 8);
    if constexpr (PASSES == 3) {
      *(uint4*)&Als[sr][w0] = *(const uint4*)(aL + k0 + c0 * 8);
      *(uint4*)&Als[sr][w1] = *(const uint4*)(aL + k0 + c0 * 8 + 8);
      *(uint4*)&Bls[sr][w0] = *(const uint4*)(bL + k0 + c0 * 8);
      *(uint4*)&Bls[sr][w1] = *(const uint4*)(bL + k0 + c0 * 8 + 8);
    }
    __syncthreads();
    bf16x8 ah[4], bh[4];
#pragma unroll
    for (int i = 0; i < 4; ++i) {
      ah[i] = *(const bf16x8*)&As[wm + i * 16 + lr][kcol];
      bh[i] = *(const bf16x8*)&Bs[wn + i * 16 + lr][kcol];
    }
    if constexpr (PASSES == 3) {
      bf16x8 al[4], bl[4];
#pragma unroll
      for (int i = 0; i < 4; ++i) {
        al[i] = *(const bf16x8*)&Als[wm + i * 16 + lr][kcol];
        bl[i] = *(const bf16x8*)&Bls[wn + i * 16 + lr][kcol];
      }
#pragma unroll
      for (int i = 0; i < 4; ++i)
#pragma unroll
        for (int j = 0; j < 4; ++j) {
          acc[i][j] = __builtin_amdgcn_mfma_f32_16x16x32_bf16(ah[i], bh[j], acc[i][j], 0, 0, 0);
          acc[i][j] = __builtin_amdgcn_mfma_f32_16x16x32_bf16(al[i], bh[j], acc[i][j], 0, 0, 0);
          acc[i][j] = __builtin_amdgcn_mfma_f32_16x16x32_bf16(ah[i], bl[j], acc[i][j], 0, 0, 0);
        }
    } else {
#pragma unroll
      for (int i = 0; i < 4; ++i)
#pragma unroll
        for (int j = 0; j < 4; ++j)
          acc[i][j] = __builtin_amdgcn_mfma_f32_16x16x32_bf16(ah[i], bh[j], acc[i][j], 0, 0, 0);
    }
  }
#pragma unroll
  for (int i = 0; i < 4; ++i) {
#pragma unroll
    for (int j = 0; j < 4; ++j) {
      const int n = n0 + wn + j * 16 + lr;
      const float bv = b1l[(size_t)e * HDIM + n];
#pragma unroll
      for (int r = 0; r < 4; ++r) {
        const int m = wm + i * 16 + (lane >> 4) * 4 + r;
        if (m < valid) {
          const float h = fmaxf(acc[i][j][r] + bv, 0.f);
          const u16 hh = f2bf(h);
          const size_t idx = (size_t)(row0 + m - hbase) * HDIM + n;
          Hhi[idx] = hh;
          if constexpr (PASSES == 3) Hlo[idx] = f2bf(h - bf2f(hh));
        }
      }
    }
  }
}

// ------------------------------------------------- MFMA expert GEMM 2
template <int PASSES>
__global__ __launch_bounds__(256) void mfma_moe2(
    const u16* __restrict__ Hhi, const u16* __restrict__ Hlo,
    const u16* __restrict__ Bhi, const u16* __restrict__ Blo,
    const float* __restrict__ b2l, const int* __restrict__ list,
    const int* __restrict__ blockExp, const int* __restrict__ blockBase,
    const int* __restrict__ blockValid, int byOff,
    const float* __restrict__ rowGate, float* __restrict__ moe) {
  constexpr int K = HDIM;
  constexpr int KC = K / KSPLIT2;
  constexpr int NT = 128 * 40;
  __shared__ u16 lds[(PASSES == 3 ? 4 : 2) * NT];
  u16(*As)[40] = (u16(*)[40])lds;
  u16(*Bs)[40] = (u16(*)[40])(lds + NT);
  u16(*Als)[40] = (u16(*)[40])(lds + 2 * NT);
  u16(*Bls)[40] = (u16(*)[40])(lds + 3 * NT);
  const int by = byOff + blockIdx.y;
  const int e = blockExp[by];
  if (e < 0) return;
  const int row0 = blockBase[by], valid = blockValid[by];
  const int hbase = blockBase[byOff];
  const int n0 = blockIdx.x * 128;
  const int kb = blockIdx.z * KC;
  const int t = threadIdx.x;
  const int sr = t >> 1, c0 = (t & 1) * 2;
  const int w0 = ((c0) ^ (sr & 3)) * 8, w1 = ((c0 + 1) ^ (sr & 3)) * 8;
  const u16* aH = Hhi + (size_t)(row0 + sr - hbase) * K;
  const u16* aL = Hlo + (size_t)(row0 + sr - hbase) * K;
  const u16* bH = Bhi + ((size_t)e * DMODEL + n0 + sr) * K;
  const u16* bL = Blo + ((size_t)e * DMODEL + n0 + sr) * K;
  const int lane = t & 63, w = t >> 6;
  const int wm = (w >> 1) * 64, wn = (w & 1) * 64;
  const int lr = lane & 15;
  const int kcol = SWZC(lane);

  f32x4 acc[4][4] = {};
  for (int k0 = kb; k0 < kb + KC; k0 += 32) {
    __syncthreads();
    *(uint4*)&As[sr][w0] = *(const uint4*)(aH + k0 + c0 * 8);
    *(uint4*)&As[sr][w1] = *(const uint4*)(aH + k0 + c0 * 8 + 8);
    *(uint4*)&Bs[sr][w0] = *(const uint4*)(bH + k0 + c0 * 8);
    *(uint4*)&Bs[sr][w1] = *(const uint4*)(bH + k0 + c0 * 8 + 8);
    if constexpr (PASSES == 3) {
      *(uint4*)&Als[sr][w0] = *(const uint4*)(aL + k0 + c0 * 8);
      *(uint4*)&Als[sr][w1] = *(const uint4*)(aL + k0 + c0 * 8 + 8);
      *(uint4*)&Bls[sr][w0] = *(const uint4*)(bL + k0 + c0 * 8);
      *(uint4*)&Bls[sr][w1] = *(const uint4*)(bL + k0 + c0 * 8 + 8);
    }
    __syncthreads();
    bf16x8 ah[4], bh[4];
#pragma unroll
    for (int i = 0; i < 4; ++i) {
      ah[i] = *(const bf16x8*)&As[wm + i * 16 + lr][kcol];
      bh[i] = *(const bf16x8*)&Bs[wn + i * 16 + lr][kcol];
    }
    if constexpr (PASSES == 3) {
      bf16x8 al[4], bl[4];
#pragma unroll
      for (int i = 0; i < 4; ++i) {
        al[i] = *(const bf16x8*)&Als[wm + i * 16 + lr][kcol];
        bl[i] = *(const bf16x8*)&Bls[wn + i * 16 + lr][kcol];
      }
#pragma unroll
      for (int i = 0; i < 4; ++i)
#pragma unroll
        for (int j = 0; j < 4; ++j) {
          acc[i][j] = __builtin_amdgcn_mfma_f32_16x16x32_bf16(ah[i], bh[j], acc[i][j], 0, 0, 0);
          acc[i][j] = __builtin_amdgcn_mfma_f32_16x16x32_bf16(al[i], bh[j], acc[i][j], 0, 0, 0);
          acc[i][j] = __builtin_amdgcn_mfma_f32_16x16x32_bf16(ah[i], bl[j], acc[i][j], 0, 0, 0);
        }
    } else {
#pragma unroll
      for (int i = 0; i < 4; ++i)
#pragma unroll
        for (int j = 0; j < 4; ++j)
          acc[i][j] = __builtin_amdgcn_mfma_f32_16x16x32_bf16(ah[i], bh[j], acc[i][j], 0, 0, 0);
    }
  }
  const bool addBias = (blockIdx.z == 0);
#pragma unroll
  for (int i = 0; i < 4; ++i) {
#pragma unroll
    for (int r = 0; r < 4; ++r) {
      const int m = wm + i * 16 + (lane >> 4) * 4 + r;
      if (m >= valid) continue;
      const int tok = list[row0 + m];
      const float g = rowGate[row0 + m];
      float* orow = moe + (size_t)tok * DMODEL;
#pragma unroll
      for (int j = 0; j < 4; ++j) {
        const int n = n0 + wn + j * 16 + lr;
        float v = acc[i][j][r];
        if (addBias) v += b2l[(size_t)e * DMODEL + n];
        atomicAdd(orow + n, v * g);
      }
    }
  }
}

// ---------------------------------------------------------------- RoPE
__global__ __launch_bounds__(256) void rope_rot(
    float* __restrict__ q, float* __restrict__ k,
    const float* __restrict__ nc, const float* __restrict__ wr) {
  const int tok = blockIdx.x, j = threadIdx.x;
  const float c0 = nc[tok * 2 + 0], c1 = nc[tok * 2 + 1];
  const float f = c0 * wr[j] + c1 * wr[256 + j];
  const float cf = cosf(f), sf = sinf(f);
  float2* q2 = (float2*)(q + (long long)tok * DMODEL);
  float2* k2 = (float2*)(k + (long long)tok * DMODEL);
  const float2 qq = q2[j];
  const float2 kk = k2[j];
  q2[j] = make_float2(qq.x * cf - qq.y * sf, qq.x * sf + qq.y * cf);
  k2[j] = make_float2(kk.x * cf - kk.y * sf, kk.x * sf + kk.y * cf);
}

// ---------------------------------------------------------------- softmax
__global__ __launch_bounds__(256) void attn_softmax(
    float* __restrict__ S, const unsigned char* __restrict__ pad) {
  const int q = blockIdx.x & (LSEQ - 1);
  const int b = blockIdx.x >> 10;
  float* row = S + (long long)blockIdx.x * LSEQ;
  const int t = threadIdx.x;
  const float4 v = ((const float4*)row)[t];
  float vals[4] = {v.x, v.y, v.z, v.w};
  const int k0 = t * 4;
#pragma unroll
  for (int j = 0; j < 4; ++j) {
    const int k = k0 + j;
    if (k > q || pad[b * LSEQ + k]) vals[j] = -INFINITY;
  }
  __shared__ float red[4];
  const int wid = t >> 6, lane = t & 63;
  float m = waveAllMax(fmaxf(fmaxf(vals[0], vals[1]), fmaxf(vals[2], vals[3])));
  if (lane == 0) red[wid] = m;
  __syncthreads();
  m = fmaxf(fmaxf(red[0], red[1]), fmaxf(red[2], red[3]));
  const float e0 = expf(vals[0] - m), e1 = expf(vals[1] - m);
  const float e2 = expf(vals[2] - m), e3 = expf(vals[3] - m);
  const float ps = waveAllSum(e0 + e1 + e2 + e3);
  __syncthreads();
  if (lane == 0) red[wid] = ps;
  __syncthreads();
  const float tot = red[0] + red[1] + red[2] + red[3];
  float4 o;
  o.x = e0 / tot; o.y = e1 / tot; o.z = e2 / tot; o.w = e3 / tot;
  ((float4*)row)[t] = o;
}

// ---------------------------------------------------------------- add + LN
__global__ __launch_bounds__(128) void ln_add(
    const float* __restrict__ Aa, const float* __restrict__ Bb,
    const float* __restrict__ gg, const float* __restrict__ bb,
    float* __restrict__ out) {
  const int row = blockIdx.x, t = threadIdx.x;
  const float4 va = ((const float4*)(Aa + (long long)row * DMODEL))[t];
  const float4 vb = ((const float4*)(Bb + (long long)row * DMODEL))[t];
  const float x0 = va.x + vb.x, x1 = va.y + vb.y;
  const float x2 = va.z + vb.z, x3 = va.w + vb.w;
  __shared__ float r1[2], r2[2];
  const int wid = t >> 6, lane = t & 63;
  const float s = waveAllSum(x0 + x1 + x2 + x3);
  if (lane == 0) r1[wid] = s;
  __syncthreads();
  const float mean = (r1[0] + r1[1]) * (1.0f / DMODEL);
  const float d0 = x0 - mean, d1 = x1 - mean, d2 = x2 - mean, d3 = x3 - mean;
  const float vs = waveAllSum(d0 * d0 + d1 * d1 + d2 * d2 + d3 * d3);
  if (lane == 0) r2[wid] = vs;
  __syncthreads();
  const float var = (r2[0] + r2[1]) * (1.0f / DMODEL);
  const float rs = rsqrtf(var + 1e-5f);
  const float4 g4 = ((const float4*)gg)[t];
  const float4 b4 = ((const float4*)bb)[t];
  float4 o;
  o.x = d0 * rs * g4.x + b4.x;
  o.y = d1 * rs * g4.y + b4.y;
  o.z = d2 * rs * g4.z + b4.z;
  o.w = d3 * rs * g4.w + b4.w;
  ((float4*)(out + (long long)row * DMODEL))[t] = o;
}

// ------------------------------------------------- router v3: no global atomics
__global__ __launch_bounds__(256) void router_topk2(
    const float* __restrict__ x, const float* __restrict__ rtw,
    const float* __restrict__ rtb, const float* __restrict__ nzw,
    const float* __restrict__ nzb, float* __restrict__ gate,
    unsigned char* __restrict__ selmask, int layer) {
  __shared__ float Wl[16][524];
  __shared__ float noisyS[16][8];
  const int t = threadIdx.x;
  for (int i = t; i < DMODEL * NEXP; i += 256) {
    const int d = i >> 3, e = i & 7;
    Wl[e][d] = rtw[i];
    Wl[8 + e][d] = nzw[i];
  }
  __syncthreads();
  const int tt = t >> 4, o = t & 15;
  const int tok = blockIdx.x * 16 + tt;
  const float4* x4 = (const float4*)(x + (size_t)tok * DMODEL);
  float s = 0.f;
#pragma unroll 4
  for (int dd = 0; dd < DMODEL / 4; ++dd) {
    const float4 xv = x4[dd];
    const float4 wv = *(const float4*)&Wl[o][dd * 4];
    s = fmaf(xv.x, wv.x, s);
    s = fmaf(xv.y, wv.y, s);
    s = fmaf(xv.z, wv.z, s);
    s = fmaf(xv.w, wv.w, s);
  }
  const float other = __shfl_xor(s, 8, 64);  // pair logit<->noise lanes
  if (o < 8) {
    const float logit = s + rtb[o];
    const float nl = other + nzb[o];
    const float eps = eps_normal((unsigned)(tok * NEXP + o), (unsigned)layer);
    const float sp = fmaxf(nl, 0.f) + log1pf(expf(-fabsf(nl)));  // logaddexp(x,0)
    noisyS[tt][o] = logit + eps * sp;
  }
  __syncthreads();
  if (t < 16) {
    const int tk = blockIdx.x * 16 + t;
    float v[8]; bool sel[8];
#pragma unroll
    for (int i = 0; i < 8; ++i) { v[i] = noisyS[t][i]; sel[i] = false; }
    for (int r = 0; r < TOPK; ++r) {  // strict '>' => lowest index wins ties
      int bi = 0; float best = -INFINITY;
      for (int i = 0; i < 8; ++i)
        if (!sel[i] && v[i] > best) { best = v[i]; bi = i; }
      sel[bi] = true;
    }
    float m = -INFINITY;
    for (int i = 0; i < 8; ++i) if (sel[i]) m = fmaxf(m, v[i]);
    float ex[8]; float den = 0.f;
    unsigned char mbits = 0;
    for (int i = 0; i < 8; ++i) {
      ex[i] = sel[i] ? expf(v[i] - m) : 0.f;
      den += ex[i];
      if (sel[i]) mbits |= (unsigned char)(1u << i);
    }
    for (int i = 0; i < 8; ++i) gate[tk * NEXP + i] = ex[i] / den;
    selmask[tk] = mbits;
  }
}

// ------------------------------------------------- atomic-free dispatch
// Phase 1: per-block histograms via 64-lane ballots (no atomics; each
// block owns its blockCnt row). Old moe_build: 16384 atomicAdds on 8
// addresses = 132 us of serialized HBM round-trips.
__global__ __launch_bounds__(256) void moe_count(
    const unsigned char* __restrict__ selmask, int* __restrict__ blockCnt) {
  __shared__ int wcnt[4][8];
  const int t = threadIdx.x, lane = t & 63, w = t >> 6;
  const unsigned m = selmask[blockIdx.x * 256 + t];
#pragma unroll
  for (int e = 0; e < 8; ++e) {
    const unsigned long long bal = __ballot((m >> e) & 1u);
    if (lane == 0) wcnt[w][e] = __popcll(bal);
  }
  __syncthreads();
  if (t < 8)
    blockCnt[blockIdx.x * 8 + t] =
        wcnt[0][t] + wcnt[1][t] + wcnt[2][t] + wcnt[3][t];
}

// Phase 2: serial scan (~300 ops) -> expert starts, per-(block,expert)
// offsets, and the 128-row tile plan.
__global__ void moe_scan(const int* __restrict__ blockCnt,
                         int* __restrict__ start, int* __restrict__ blockExp,
                         int* __restrict__ blockBase, int* __restrict__ blockValid,
                         int* __restrict__ blockOff) {
  if (threadIdx.x != 0) return;
  int s = 0, by = 0;
  for (int e = 0; e < NEXP; ++e) {
    start[e] = s;
    int off = s;
    for (int b = 0; b < TOK / 256; ++b) {
      blockOff[b * 8 + e] = off;
      off += blockCnt[b * 8 + e];
    }
    const int c = off - s;
    const int nb = (c + 127) >> 7;
    for (int b2 = 0; b2 < nb; ++b2) {
      blockExp[by] = e;
      blockBase[by] = s + b2 * 128;
      blockValid[by] = min(128, c - b2 * 128);
      ++by;
    }
    s += nb * 128;
  }
  for (; by < NBLK; ++by) { blockExp[by] = -1; blockBase[by] = s; blockValid[by] = 0; }
}

// Phase 3: each token computes its slot via ballot-rank (no atomics;
// deterministic token-ascending order within each expert).
__global__ __launch_bounds__(256) void moe_fill(
    const unsigned char* __restrict__ selmask, const int* __restrict__ blockOff,
    const float* __restrict__ gate, int* __restrict__ list,
    float* __restrict__ rowGate) {
  __shared__ int wbase[4][8];
  const int t = threadIdx.x, lane = t & 63, w = t >> 6;
  const int tok = blockIdx.x * 256 + t;
  const unsigned m = selmask[tok];
  unsigned long long bal[8];
#pragma unroll
  for (int e = 0; e < 8; ++e) {
    bal[e] = __ballot((m >> e) & 1u);
    if (lane == 0) wbase[w][e] = __popcll(bal[e]);
  }
  __syncthreads();
  if (t < 8) {
    int base = blockOff[blockIdx.x * 8 + t];
    for (int ww = 0; ww < 4; ++ww) {
      const int c = wbase[ww][t];
      wbase[ww][t] = base;
      base += c;
    }
  }
  __syncthreads();
  const unsigned long long ltm = (1ull << lane) - 1ull;
#pragma unroll
  for (int e = 0; e < 8; ++e) {
    if ((m >> e) & 1u) {
      const int slot = wbase[w][e] + __popcll(bal[e] & ltm);
      list[slot] = tok;
      rowGate[slot] = gate[tok * NEXP + e];
    }
  }
}

__global__ __launch_bounds__(256) void zero_f32(float* __restrict__ p, int n4) {
  const int i = blockIdx.x * 256 + threadIdx.x;
  if (i < n4) ((float4*)p)[i] = make_float4(0.f, 0.f, 0.f, 0.f);
}

// ---------------------------------------------------------------- launch
extern "C" void kernel_launch(void* const* d_in, const int* in_sizes, int n_in,
                              void* d_out, int out_size, void* d_ws,
                              size_t ws_size, hipStream_t stream) {
  const float* x_in = (const float*)d_in[0];
  const float* nc = (const float*)d_in[1];
  const unsigned char* pad = (const unsigned char*)d_in[3];
  const float* wq = (const float*)d_in[4];
  const float* bq = (const float*)d_in[5];
  const float* wk = (const float*)d_in[6];
  const float* bk = (const float*)d_in[7];
  const float* wv = (const float*)d_in[8];
  const float* bv = (const float*)d_in[9];
  const float* wr = (const float*)d_in[10];
  const float* ln1g = (const float*)d_in[11];
  const float* ln1b = (const float*)d_in[12];
  const float* rtw = (const float*)d_in[13];
  const float* rtb = (const float*)d_in[14];
  const float* nzw = (const float*)d_in[15];
  const float* nzb = (const float*)d_in[16];
  const float* ew1 = (const float*)d_in[17];
  const float* eb1 = (const float*)d_in[18];
  const float* ew2 = (const float*)d_in[19];
  const float* eb2 = (const float*)d_in[20];
  const float* ln2g = (const float*)d_in[21];
  const float* ln2b = (const float*)d_in[22];

  float* ws = (float*)d_ws;
  const long long SZ = (long long)TOK * DMODEL;  // 2,097,152
  float* qb = ws;                        // also attn output
  float* kb = ws + SZ;
  float* vb2 = ws + 2 * SZ;
  float* xcur = ws + 3 * SZ;
  float* moe = ws + 4 * SZ;
  float* gate = ws + 5 * SZ;
  int* meta = (int*)(ws + 10518528);
  int* startE = meta + 16;
  int* blockExp = meta + 24;
  int* blockBase = meta + 160;
  int* blockValid = meta + 296;
  int* list = meta + 432;
  unsigned char* selmask = (unsigned char*)(meta + 17840);
  float* rowGate = ws + 10537408;
  u16* Xhi = (u16*)(ws + 10554816);      // expert split of xcur
  u16* Xlo = (u16*)(ws + 11603392);

  // ---- attention region (aliases expert W1T/W2T/H region; disjoint lifetime)
  float* scores = ws + 12651968;         // 4,194,304 f32
  u16* ub = (u16*)(ws + 16846272);
  u16* XAhi = ub;                        // 2,097,152 each
  u16* XAlo = ub + 2097152;
  u16* Qhi = ub + 4194304;
  u16* Qlo = ub + 6291456;
  u16* Khi = ub + 8388608;
  u16* Klo = ub + 10485760;
  u16* Phi = ub + 12582912;              // 4,194,304 each
  u16* Plo = ub + 16777216;
  u16* VThi = ub + 20971520;             // 2,097,152 each
  u16* VTlo = ub + 23068672;
  u16* WqThi = ub + 25165824;            // 262,144 each
  u16* WqTlo = ub + 25427968;
  u16* WkThi = ub + 25690112;
  u16* WkTlo = ub + 25952256;
  u16* WvThi = ub + 26214400;
  u16* WvTlo = ub + 26476544;            // region ends 30,215,616 floats

  // ---- expert region (written after attention each layer)
  u16* W1Thi = (u16*)(ws + 12651968);
  u16* W1Tlo = (u16*)(ws + 16846272);
  u16* W2Thi = (u16*)(ws + 21040576);
  u16* W2Tlo = (u16*)(ws + 25234880);
  u16* Hhi = (u16*)(ws + 29429184);
  u16* Hlo = (u16*)(ws + 38342080);      // ends 47,254,976 f
  int* blockCnt = (int*)(ws + 47254976); // [16][8]
  int* blockOff = (int*)(ws + 47255104); // [16][8]; high-water 47,255,232 f

  const float iscale = 1.0f / sqrtf((float)DMODEL);
  const dim3 blk(256);
  const long long sQ = (long long)LSEQ * DMODEL;   // per-batch q/k/v stride
  const long long sS = (long long)LSEQ * LSEQ;     // per-batch scores stride

  for (int l = 0; l < NLAYER; ++l) {
    const float* xl = (l == 0) ? x_in : xcur;
    const long long wOff = (long long)l * DMODEL * DMODEL;

    // ---- QKV via fused split-bf16 MFMA (one 384-block launch)
    split_f32_bf16<<<2048, blk, 0, stream>>>(xl, XAhi, XAlo, (int)SZ);
    transpose_split<<<dim3(16, 16, 1), blk, 0, stream>>>(wq + wOff, WqThi, WqTlo, DMODEL, DMODEL);
    transpose_split<<<dim3(16, 16, 1), blk, 0, stream>>>(wk + wOff, WkThi, WkTlo, DMODEL, DMODEL);
    transpose_split<<<dim3(16, 16, 1), blk, 0, stream>>>(wv + wOff, WvThi, WvTlo, DMODEL, DMODEL);
    mfma_qkv3<<<dim3(12, TOK / 128), blk, 0, stream>>>(
        XAhi, XAlo, WqThi, WqTlo, WkThi, WkTlo, WvThi, WvTlo,
        bq + l * DMODEL, bk + l * DMODEL, bv + l * DMODEL, qb, kb, vb2);

    rope_rot<<<TOK, 256, 0, stream>>>(qb, kb, nc, wr + (long long)l * DMODEL);

    // ---- scores = (q @ k^T) * iscale via split-bf16 MFMA
    split_f32_bf16<<<2048, blk, 0, stream>>>(qb, Qhi, Qlo, (int)SZ);
    split_f32_bf16<<<2048, blk, 0, stream>>>(kb, Khi, Klo, (int)SZ);
    mfma_gemm3<3><<<dim3(8, 8, BATCH), blk, 0, stream>>>(
        Qhi, Qlo, Khi, Klo, nullptr, scores, LSEQ, DMODEL, iscale, sQ, sQ, sS);

    attn_softmax<<<BATCH * LSEQ, 256, 0, stream>>>(scores, pad);

    // ---- attn @ v via split-bf16 MFMA (v transposed to [D][L] per batch)
    split_f32_bf16<<<4096, blk, 0, stream>>>(scores, Phi, Plo, (int)(4 * sS / 4 * 4));
    transpose_split<<<dim3(16, 32, BATCH), blk, 0, stream>>>(vb2, VThi, VTlo, LSEQ, DMODEL);
    mfma_gemm3<3><<<dim3(4, 8, BATCH), blk, 0, stream>>>(
        Phi, Plo, VThi, VTlo, nullptr, qb, DMODEL, LSEQ, 1.f, sS, sQ, sQ);

    ln_add<<<TOK, 128, 0, stream>>>(xl, qb, ln1g + l * DMODEL, ln1b + l * DMODEL, xcur);

    // ---- router + atomic-free dispatch
    router_topk2<<<TOK / 16, blk, 0, stream>>>(
        xcur, rtw + l * DMODEL * NEXP, rtb + l * NEXP, nzw + l * DMODEL * NEXP,
        nzb + l * NEXP, gate, selmask, l);
    moe_count<<<TOK / 256, blk, 0, stream>>>(selmask, blockCnt);
    moe_scan<<<1, 64, 0, stream>>>(blockCnt, startE, blockExp, blockBase,
                                   blockValid, blockOff);
    moe_fill<<<TOK / 256, blk, 0, stream>>>(selmask, blockOff, gate, list, rowGate);
    zero_f32<<<(int)(SZ / 4 / 256), 256, 0, stream>>>(moe, (int)(SZ / 4));

    // ---- experts (3-pass split-bf16, grouped, chunked H, K-split moe2)
    split_f32_bf16<<<2048, blk, 0, stream>>>(xcur, Xhi, Xlo, (int)SZ);
    transpose_split<<<dim3(64, 16, 8), blk, 0, stream>>>(
        ew1 + (long long)l * NEXP * DMODEL * HDIM, W1Thi, W1Tlo, DMODEL, HDIM);
    transpose_split<<<dim3(16, 64, 8), blk, 0, stream>>>(
        ew2 + (long long)l * NEXP * HDIM * DMODEL, W2Thi, W2Tlo, HDIM, DMODEL);

    const float* b1l = eb1 + (long long)l * NEXP * HDIM;
    const float* b2l = eb2 + (long long)l * NEXP * DMODEL;
    for (int ch = 0; ch < 2; ++ch) {
      const int byOff = ch * CHBLK;
      mfma_moe1<3><<<dim3(HDIM / 128, CHBLK), blk, 0, stream>>>(
          Xhi, Xlo, W1Thi, W1Tlo, b1l, list, blockExp, blockBase, blockValid,
          byOff, Hhi, Hlo);
      mfma_moe2<3><<<dim3(DMODEL / 128, CHBLK, KSPLIT2), blk, 0, stream>>>(
          Hhi, Hlo, W2Thi, W2Tlo, b2l, list, blockExp, blockBase, blockValid,
          byOff, rowGate, moe);
    }

    float* outp = (l == NLAYER - 1) ? (float*)d_out : xcur;
    ln_add<<<TOK, 128, 0, stream>>>(xcur, moe, ln2g + l * DMODEL, ln2b + l * DMODEL, outp);
  }
}